// Round 2
// baseline (1447.380 us; speedup 1.0000x reference)
//
#include <hip/hip_runtime.h>
#include <hip/hip_bf16.h>
#include <stdint.h>

typedef __hip_bfloat16 bf16;

#define BB 4
#define LL 2048
#define DMM 256
#define HH 8
#define EE 32
#define NLL 3
#define ITR 16
#define UU 40
#define ROWS (BB*LL)          // 8192
#define NELEM (ROWS*DMM)      // 2097152

// ---------------- threefry2x32 (exact JAX semantics) ----------------
__host__ __device__ inline void threefry2x32(uint32_t k0, uint32_t k1,
                                             uint32_t x0, uint32_t x1,
                                             uint32_t* o0, uint32_t* o1) {
  uint32_t ks2 = k0 ^ k1 ^ 0x1BD11BDAu;
  x0 += k0; x1 += k1;
#define TFR(r) { x0 += x1; x1 = (x1 << (r)) | (x1 >> (32 - (r))); x1 ^= x0; }
  TFR(13) TFR(15) TFR(26) TFR(6)
  x0 += k1;  x1 += ks2 + 1u;
  TFR(17) TFR(29) TFR(16) TFR(24)
  x0 += ks2; x1 += k0 + 2u;
  TFR(13) TFR(15) TFR(26) TFR(6)
  x0 += k0;  x1 += k1 + 3u;
  TFR(17) TFR(29) TFR(16) TFR(24)
  x0 += k1;  x1 += ks2 + 4u;
  TFR(13) TFR(15) TFR(26) TFR(6)
  x0 += ks2; x1 += k0 + 5u;
#undef TFR
  *o0 = x0; *o1 = x1;
}

__device__ __forceinline__ float wave_sum(float v) {
#pragma unroll
  for (int off = 32; off > 0; off >>= 1) v += __shfl_xor(v, off);
  return v;
}

__device__ __forceinline__ float bfbits(unsigned short u) {
  return __uint_as_float(((uint32_t)u) << 16);
}

// ---------------- dtype probe: flag=1 if input is float32, 0 if bf16 ----------------
__global__ __launch_bounds__(256) void probe_dtype(const void* __restrict__ x,
                                                   int* __restrict__ flag) {
  __shared__ int cnt;
  if (threadIdx.x == 0) cnt = 0;
  __syncthreads();
  const unsigned short* u = (const unsigned short*)x;
  int bad = 0;
  for (int j = threadIdx.x; j < 2048; j += 256) {
    float v = bfbits(u[j]);
    float a = fabsf(v);
    bool ok = (v == 0.0f) || (a > 1e-4f && a < 100.0f);
    if (!ok) bad++;
  }
  atomicAdd(&cnt, bad);
  __syncthreads();
  if (threadIdx.x == 0) *flag = (cnt > 100) ? 1 : 0;
}

// ---------------- flag-driven convert to f32 ----------------
__global__ __launch_bounds__(256) void cvt(const void* __restrict__ src,
                                           float* __restrict__ dst, int n,
                                           const int* __restrict__ flag) {
  int gid = blockIdx.x * 256 + threadIdx.x;
  if (gid >= n) return;
  if (*flag) dst[gid] = ((const float*)src)[gid];
  else       dst[gid] = bfbits(((const unsigned short*)src)[gid]);
}

// ---------------- idx generation: lower_bits & 2047 ----------------
__global__ __launch_bounds__(256) void idx_kernel(uint32_t k20, uint32_t k21,
                                                  int* __restrict__ idx) {
  int j = blockIdx.x * 256 + threadIdx.x;
  if (j >= LL * UU) return;
  uint32_t o0, o1;
  const int half = (LL * UU) / 2;  // 40960
  if (j < half) {
    threefry2x32(k20, k21, (uint32_t)j, (uint32_t)(j + half), &o0, &o1);
    idx[j] = (int)(o0 & (LL - 1));
  } else {
    threefry2x32(k20, k21, (uint32_t)(j - half), (uint32_t)j, &o0, &o1);
    idx[j] = (int)(o1 & (LL - 1));
  }
}

// ---------------- generic f32 GEMM: C[M=8192,N=256] = A(8192x256) @ W^T ----------------
#define GBM 64
#define GBN 64
#define GBK 16
__global__ __launch_bounds__(256) void gemm_bt(const float* __restrict__ A,
                                               const float* __restrict__ W,
                                               const float* __restrict__ bias,
                                               float* __restrict__ C,
                                               int wRow, int wK, int accumulate, int lshift) {
  __shared__ float As[GBK][GBM + 4];
  __shared__ float Bs[GBK][GBN + 4];
  int bm = blockIdx.x * GBM;
  int bn = blockIdx.y * GBN;
  int tid = threadIdx.x;
  int kk = tid & 15, rr = tid >> 4;
  int tx = tid & 15, ty = tid >> 4;
  float acc[4][4] = {};
  for (int k0 = 0; k0 < DMM; k0 += GBK) {
#pragma unroll
    for (int p = 0; p < 4; ++p) {
      int row = bm + rr + 16 * p;
      int arow = row;
      if (lshift != 0) {
        int b = row >> 11, l = row & (LL - 1);
        arow = (b << 11) | ((l + lshift + LL) & (LL - 1));
      }
      As[kk][rr + 16 * p] = A[(size_t)arow * DMM + k0 + kk];
      Bs[kk][rr + 16 * p] = W[(size_t)(bn + rr + 16 * p) * wRow + (size_t)(k0 + kk) * wK];
    }
    __syncthreads();
#pragma unroll
    for (int kq = 0; kq < GBK; ++kq) {
      float av[4], bv[4];
#pragma unroll
      for (int i = 0; i < 4; ++i) av[i] = As[kq][ty * 4 + i];
#pragma unroll
      for (int j = 0; j < 4; ++j) bv[j] = Bs[kq][tx * 4 + j];
#pragma unroll
      for (int i = 0; i < 4; ++i)
#pragma unroll
        for (int j = 0; j < 4; ++j) acc[i][j] = fmaf(av[i], bv[j], acc[i][j]);
    }
    __syncthreads();
  }
#pragma unroll
  for (int i = 0; i < 4; ++i) {
    int row = bm + ty * 4 + i;
    float* crow = C + (size_t)row * DMM + bn + tx * 4;
    if (accumulate) {
#pragma unroll
      for (int j = 0; j < 4; ++j) crow[j] += acc[i][j];
    } else {
#pragma unroll
      for (int j = 0; j < 4; ++j) crow[j] = acc[i][j] + bias[bn + tx * 4 + j];
    }
  }
}

// ---------------- M scores ----------------
__global__ __launch_bounds__(256) void m_kernel(const float* __restrict__ Q,
                                                const float* __restrict__ K,
                                                const int* __restrict__ idx,
                                                float* __restrict__ M) {
  int gid = blockIdx.x * 256 + threadIdx.x;  // (b*H+h)*L + l
  int l = gid & (LL - 1);
  int bh = gid >> 11;
  int h = bh & (HH - 1);
  int b = bh >> 3;
  const float4* q4 =
      reinterpret_cast<const float4*>(Q + ((size_t)(b * LL + l)) * DMM + h * EE);
  float4 qr[8];
#pragma unroll
  for (int i = 0; i < 8; ++i) qr[i] = q4[i];
  float mx = -1e30f, sm = 0.f;
  const int* ip = idx + l * UU;
  for (int u = 0; u < UU; ++u) {
    int j = ip[u];
    const float4* k4 =
        reinterpret_cast<const float4*>(K + ((size_t)(b * LL + j)) * DMM + h * EE);
    float s = 0.f;
#pragma unroll
    for (int i = 0; i < 8; ++i) {
      float4 kv = k4[i];
      s += qr[i].x * kv.x + qr[i].y * kv.y + qr[i].z * kv.z + qr[i].w * kv.w;
    }
    mx = fmaxf(mx, s);
    sm += s;
  }
  M[gid] = mx - sm * (1.0f / (float)LL);
}

// ---------------- top-k (u=40) per (b,h) ----------------
__global__ __launch_bounds__(256) void topk_kernel(const float* __restrict__ M,
                                                   int* __restrict__ top) {
  int bh = blockIdx.x;
  int tid = threadIdx.x;
  __shared__ float vals[LL];
  __shared__ float rv[256];
  __shared__ int ri[256];
  const float* m = M + (size_t)bh * LL;
  for (int j = tid; j < LL; j += 256) vals[j] = m[j];
  __syncthreads();
  for (int t = 0; t < UU; ++t) {
    float bv = -1e38f;
    int bi = LL;
    for (int j = tid; j < LL; j += 256) {
      float v = vals[j];
      if (v > bv || (v == bv && j < bi)) { bv = v; bi = j; }
    }
    rv[tid] = bv; ri[tid] = bi;
    __syncthreads();
    for (int s = 128; s > 0; s >>= 1) {
      if (tid < s) {
        float ov = rv[tid + s]; int oi = ri[tid + s];
        if (ov > rv[tid] || (ov == rv[tid] && oi < ri[tid])) { rv[tid] = ov; ri[tid] = oi; }
      }
      __syncthreads();
    }
    if (tid == 0) { top[bh * UU + t] = ri[0]; vals[ri[0]] = -1e38f; }
    __syncthreads();
  }
}

// ---------------- v mean over L ----------------
__global__ __launch_bounds__(256) void vmean_part(const float* __restrict__ V,
                                                  float* __restrict__ pv) {
  int blk = blockIdx.x;  // b*8 + c
  int b = blk >> 3, c = blk & 7;
  int d = threadIdx.x;
  float s = 0.f;
  int base = b * LL + c * 256;
  for (int r = 0; r < 256; ++r) s += V[(size_t)(base + r) * DMM + d];
  pv[(size_t)blk * DMM + d] = s;
}
__global__ __launch_bounds__(256) void vmean_fin(const float* __restrict__ pv,
                                                 float* __restrict__ vm) {
  int gid = blockIdx.x * 256 + threadIdx.x;  // B*DM
  int b = gid >> 8, d = gid & 255;
  float s = 0.f;
#pragma unroll
  for (int c = 0; c < 8; ++c) s += pv[(size_t)(b * 8 + c) * DMM + d];
  vm[gid] = s * (1.0f / (float)LL);
}

__global__ __launch_bounds__(256) void ctx_init(const float* __restrict__ vm,
                                                float* __restrict__ ctx) {
  int gid = blockIdx.x * 256 + threadIdx.x;
  int d = gid & 255;
  int b = gid >> 19;
  ctx[gid] = vm[b * DMM + d];
}

// ---------------- full attention for selected rows ----------------
__global__ __launch_bounds__(256) void attn_sel(const float* __restrict__ Q,
                                                const float* __restrict__ K,
                                                const float* __restrict__ V,
                                                const int* __restrict__ top,
                                                float* __restrict__ ctx) {
  int bid = blockIdx.x;
  int t = bid % UU;
  int bh = bid / UU;
  int h = bh & (HH - 1), b = bh >> 3;
  int tid = threadIdx.x;
  __shared__ float p[LL];
  __shared__ float red[256];
  __shared__ float gacc[8][EE];
  int qrow = top[bh * UU + t];
  const float4* q4 =
      reinterpret_cast<const float4*>(Q + ((size_t)(b * LL + qrow)) * DMM + h * EE);
  float4 qr[8];
#pragma unroll
  for (int i = 0; i < 8; ++i) qr[i] = q4[i];
  const float scale = 0.17677669529663687f;  // 1/sqrt(32)
  float lmax = -1e30f;
  for (int j = tid; j < LL; j += 256) {
    const float4* k4 =
        reinterpret_cast<const float4*>(K + ((size_t)(b * LL + j)) * DMM + h * EE);
    float s = 0.f;
#pragma unroll
    for (int i = 0; i < 8; ++i) {
      float4 kv = k4[i];
      s += qr[i].x * kv.x + qr[i].y * kv.y + qr[i].z * kv.z + qr[i].w * kv.w;
    }
    s *= scale;
    p[j] = s;
    lmax = fmaxf(lmax, s);
  }
  red[tid] = lmax;
  __syncthreads();
  for (int s = 128; s > 0; s >>= 1) {
    if (tid < s) red[tid] = fmaxf(red[tid], red[tid + s]);
    __syncthreads();
  }
  float mx = red[0];
  __syncthreads();
  float lsum = 0.f;
  for (int j = tid; j < LL; j += 256) {
    float e = expf(p[j] - mx);
    p[j] = e;
    lsum += e;
  }
  red[tid] = lsum;
  __syncthreads();
  for (int s = 128; s > 0; s >>= 1) {
    if (tid < s) red[tid] += red[tid + s];
    __syncthreads();
  }
  float inv = 1.0f / red[0];
  int e = tid & (EE - 1), g = tid >> 5;
  float acc = 0.f;
  for (int j = g; j < LL; j += 8)
    acc += p[j] * V[((size_t)(b * LL + j)) * DMM + h * EE + e];
  gacc[g][e] = acc;
  __syncthreads();
  if (tid < EE) {
    float o = 0.f;
#pragma unroll
    for (int gg = 0; gg < 8; ++gg) o += gacc[gg][tid];
    ctx[((size_t)(b * LL + qrow)) * DMM + h * EE + tid] = o * inv;
  }
}

// ---------------- LayerNorm(x + t) * g + b, wave per row ----------------
__global__ __launch_bounds__(256) void ln_res(const float* __restrict__ X,
                                              const float* __restrict__ T,
                                              const float* __restrict__ g,
                                              const float* __restrict__ bb,
                                              float* __restrict__ Out) {
  int wave = threadIdx.x >> 6, lane = threadIdx.x & 63;
  size_t row = (size_t)blockIdx.x * 4 + wave;
  const float* xr = X + row * DMM;
  const float* tr = T + row * DMM;
  float v[4];
#pragma unroll
  for (int i = 0; i < 4; ++i) v[i] = xr[lane + 64 * i] + tr[lane + 64 * i];
  float s = wave_sum(v[0] + v[1] + v[2] + v[3]);
  float m = s * (1.0f / (float)DMM);
  float sq = 0.f;
#pragma unroll
  for (int i = 0; i < 4; ++i) { float d = v[i] - m; sq += d * d; }
  sq = wave_sum(sq);
  float rstd = rsqrtf(sq * (1.0f / (float)DMM) + 1e-5f);
#pragma unroll
  for (int i = 0; i < 4; ++i) {
    int d = lane + 64 * i;
    Out[row * DMM + d] = (v[i] - m) * rstd * g[d] + bb[d];
  }
}

// ---------------- fused FFN (INTER=16) + residual + LN ----------------
__global__ __launch_bounds__(256) void ffn_ln(const float* __restrict__ X,
                                              const float* __restrict__ w1,
                                              const float* __restrict__ b1,
                                              const float* __restrict__ w2,
                                              const float* __restrict__ b2,
                                              const float* __restrict__ g,
                                              const float* __restrict__ bb,
                                              float* __restrict__ Out) {
  int wave = threadIdx.x >> 6, lane = threadIdx.x & 63;
  size_t row = (size_t)blockIdx.x * 4 + wave;
  __shared__ float xs[4][DMM];
  const float* xr = X + row * DMM;
  float xv[4];
#pragma unroll
  for (int i = 0; i < 4; ++i) {
    xv[i] = xr[lane + 64 * i];
    xs[wave][lane + 64 * i] = xv[i];
  }
  __syncthreads();
  int f = lane & 15, qtr = lane >> 4;
  const float* w1p = w1 + f * DMM + qtr * 64;
  const float* xq = &xs[wave][qtr * 64];
  float pacc = 0.f;
#pragma unroll 8
  for (int d = 0; d < 64; ++d) pacc += xq[d] * w1p[d];
  pacc += __shfl_xor(pacc, 16);
  pacc += __shfl_xor(pacc, 32);
  float y1 = fmaxf(pacc + b1[f], 0.0f);
  float y1v[16];
#pragma unroll
  for (int ff = 0; ff < 16; ++ff) y1v[ff] = __shfl(y1, ff);
  float v[4];
#pragma unroll
  for (int i = 0; i < 4; ++i) {
    int d = lane + 64 * i;
    const float* w2p = w2 + d * ITR;
    float a = b2[d];
#pragma unroll
    for (int ff = 0; ff < 16; ++ff) a += y1v[ff] * w2p[ff];
    v[i] = xv[i] + a;
  }
  float s = wave_sum(v[0] + v[1] + v[2] + v[3]);
  float m = s * (1.0f / (float)DMM);
  float sq = 0.f;
#pragma unroll
  for (int i = 0; i < 4; ++i) { float d = v[i] - m; sq += d * d; }
  sq = wave_sum(sq);
  float rstd = rsqrtf(sq * (1.0f / (float)DMM) + 1e-5f);
#pragma unroll
  for (int i = 0; i < 4; ++i) {
    int d = lane + 64 * i;
    Out[row * DMM + d] = (v[i] - m) * rstd * g[d] + bb[d];
  }
}

// ---------------- batchnorm stats ----------------
__global__ __launch_bounds__(256) void stat_part(const float* __restrict__ Y,
                                                 float* __restrict__ ps,
                                                 float* __restrict__ ps2) {
  int c = blockIdx.x;
  int d = threadIdx.x;
  float s = 0.f, s2 = 0.f;
  int base = c * 256;
  for (int r = 0; r < 256; ++r) {
    float v = Y[(size_t)(base + r) * DMM + d];
    s += v;
    s2 += v * v;
  }
  ps[(size_t)c * DMM + d] = s;
  ps2[(size_t)c * DMM + d] = s2;
}
__global__ __launch_bounds__(256) void stat_fin(const float* __restrict__ ps,
                                                const float* __restrict__ ps2,
                                                float* __restrict__ mean,
                                                float* __restrict__ rstd) {
  int d = threadIdx.x;
  float s = 0.f, s2 = 0.f;
  for (int c = 0; c < 32; ++c) {
    s += ps[(size_t)c * DMM + d];
    s2 += ps2[(size_t)c * DMM + d];
  }
  float m = s * (1.0f / (float)ROWS);
  float var = s2 * (1.0f / (float)ROWS) - m * m;
  mean[d] = m;
  rstd[d] = rsqrtf(var + 1e-5f);
}

__global__ __launch_bounds__(256) void bn_elu(const float* __restrict__ Y,
                                              const float* __restrict__ mean,
                                              const float* __restrict__ rstd,
                                              const float* __restrict__ g,
                                              const float* __restrict__ bb,
                                              float* __restrict__ X) {
  int gid = blockIdx.x * 256 + threadIdx.x;
  int d = gid & 255;
  float v = (Y[gid] - mean[d]) * rstd[d] * g[d] + bb[d];
  X[gid] = v > 0.f ? v : expm1f(v);
}

// ---------------- final LN -> out (dtype per flag) ----------------
__global__ __launch_bounds__(256) void ln_final(const float* __restrict__ X,
                                                const float* __restrict__ g,
                                                const float* __restrict__ bb,
                                                void* __restrict__ Out,
                                                const int* __restrict__ flag) {
  int wave = threadIdx.x >> 6, lane = threadIdx.x & 63;
  size_t row = (size_t)blockIdx.x * 4 + wave;
  const float* xr = X + row * DMM;
  float v[4];
#pragma unroll
  for (int i = 0; i < 4; ++i) v[i] = xr[lane + 64 * i];
  float s = wave_sum(v[0] + v[1] + v[2] + v[3]);
  float m = s * (1.0f / (float)DMM);
  float sq = 0.f;
#pragma unroll
  for (int i = 0; i < 4; ++i) { float d = v[i] - m; sq += d * d; }
  sq = wave_sum(sq);
  float rstd = rsqrtf(sq * (1.0f / (float)DMM) + 1e-5f);
  int isf32 = *flag;
#pragma unroll
  for (int i = 0; i < 4; ++i) {
    int d = lane + 64 * i;
    float val = (v[i] - m) * rstd * g[d] + bb[d];
    if (isf32) ((float*)Out)[row * DMM + d] = val;
    else       ((bf16*)Out)[row * DMM + d] = __float2bfloat16(val);
  }
}

extern "C" void kernel_launch(void* const* d_in, const int* in_sizes, int n_in,
                              void* d_out, int out_size, void* d_ws, size_t ws_size,
                              hipStream_t stream) {
  (void)in_sizes; (void)n_in; (void)out_size; (void)ws_size;

  // ---- workspace layout (floats) ----
  float* xbuf  = (float*)d_ws;
  float* qb    = xbuf + NELEM;
  float* kb    = qb + NELEM;
  float* vb    = kb + NELEM;
  float* ctx   = vb + NELEM;
  float* tmp   = ctx + NELEM;
  float* Mbuf  = tmp + NELEM;            // B*H*L
  float* vmp   = Mbuf + BB * HH * LL;
  float* vmean = vmp + BB * 8 * DMM;
  float* stp   = vmean + BB * DMM;
  float* stp2  = stp + 32 * DMM;
  float* smean = stp2 + 32 * DMM;
  float* srstd = smean + DMM;
  float* wbase = srstd + DMM;            // converted weights region
  float* wp = wbase;
  // sizes of inputs 1..22 in elements
  const int wsz[23] = {
      NELEM,
      NLL * DMM * DMM, NLL * DMM,   // wq bq
      NLL * DMM * DMM, NLL * DMM,   // wk bk
      NLL * DMM * DMM, NLL * DMM,   // wv bv
      NLL * DMM * DMM, NLL * DMM,   // wo bo
      NLL * ITR * DMM, NLL * ITR,   // c1w c1b
      NLL * DMM * ITR, NLL * DMM,   // c2w c2b
      NLL * DMM, NLL * DMM,         // ln1g ln1b
      NLL * DMM, NLL * DMM,         // ln2g ln2b
      (NLL - 1) * DMM * DMM * 3, (NLL - 1) * DMM,  // dcw dcb
      (NLL - 1) * DMM, (NLL - 1) * DMM,            // bng bnb
      DMM, DMM                       // fng fnb  (fnb ptr computed below)
  };
  float* fptr[23];
  for (int i = 1; i < 23; ++i) { fptr[i] = wp; wp += wsz[i]; }
  int* idxb = (int*)wp;                  // L*U
  int* topb = idxb + LL * UU;            // B*H*U
  int* flag = topb + BB * HH * UU;       // 1

  // ---- dtype probe + convert all inputs to f32 ----
  probe_dtype<<<1, 256, 0, stream>>>(d_in[0], flag);
  cvt<<<(NELEM + 255) / 256, 256, 0, stream>>>(d_in[0], xbuf, NELEM, flag);
  for (int i = 1; i < 23; ++i)
    cvt<<<(wsz[i] + 255) / 256, 256, 0, stream>>>(d_in[i], fptr[i], wsz[i], flag);

  const float* wq_all  = fptr[1];
  const float* bq_all  = fptr[2];
  const float* wk_all  = fptr[3];
  const float* bk_all  = fptr[4];
  const float* wv_all  = fptr[5];
  const float* bv_all  = fptr[6];
  const float* wo_all  = fptr[7];
  const float* bo_all  = fptr[8];
  const float* c1w_all = fptr[9];
  const float* c1b_all = fptr[10];
  const float* c2w_all = fptr[11];
  const float* c2b_all = fptr[12];
  const float* ln1g_all= fptr[13];
  const float* ln1b_all= fptr[14];
  const float* ln2g_all= fptr[15];
  const float* ln2b_all= fptr[16];
  const float* dcw_all = fptr[17];
  const float* dcb_all = fptr[18];
  const float* bng_all = fptr[19];
  const float* bnb_all = fptr[20];
  const float* fng     = fptr[21];
  const float* fnb     = fptr[22];

  dim3 gg(ROWS / GBM, DMM / GBN);

  for (int i = 0; i < NLL; ++i) {
    gemm_bt<<<gg, 256, 0, stream>>>(xbuf, wq_all + (size_t)i * DMM * DMM,
                                    bq_all + i * DMM, qb, DMM, 1, 0, 0);
    gemm_bt<<<gg, 256, 0, stream>>>(xbuf, wk_all + (size_t)i * DMM * DMM,
                                    bk_all + i * DMM, kb, DMM, 1, 0, 0);
    gemm_bt<<<gg, 256, 0, stream>>>(xbuf, wv_all + (size_t)i * DMM * DMM,
                                    bv_all + i * DMM, vb, DMM, 1, 0, 0);

    // JAX PRNG: key(42) -> fold_in(i) -> split -> k2 (lower-bits key)
    uint32_t ki0, ki1, a0, a1, b0, b1;
    threefry2x32(0u, 42u, 0u, (uint32_t)i, &ki0, &ki1);
    threefry2x32(ki0, ki1, 0u, 2u, &a0, &a1);
    threefry2x32(ki0, ki1, 1u, 3u, &b0, &b1);
    (void)a0; (void)b0;
    idx_kernel<<<(LL * UU) / 256, 256, 0, stream>>>(a1, b1, idxb);

    m_kernel<<<(BB * HH * LL) / 256, 256, 0, stream>>>(qb, kb, idxb, Mbuf);
    topk_kernel<<<BB * HH, 256, 0, stream>>>(Mbuf, topb);
    vmean_part<<<BB * 8, 256, 0, stream>>>(vb, vmp);
    vmean_fin<<<(BB * DMM) / 256, 256, 0, stream>>>(vmp, vmean);
    ctx_init<<<NELEM / 256, 256, 0, stream>>>(vmean, ctx);
    attn_sel<<<BB * HH * UU, 256, 0, stream>>>(qb, kb, vb, topb, ctx);

    gemm_bt<<<gg, 256, 0, stream>>>(ctx, wo_all + (size_t)i * DMM * DMM,
                                    bo_all + i * DMM, tmp, DMM, 1, 0, 0);
    ln_res<<<ROWS / 4, 256, 0, stream>>>(xbuf, tmp, ln1g_all + i * DMM,
                                         ln1b_all + i * DMM, xbuf);
    ffn_ln<<<ROWS / 4, 256, 0, stream>>>(xbuf, c1w_all + (size_t)i * ITR * DMM,
                                         c1b_all + i * ITR,
                                         c2w_all + (size_t)i * DMM * ITR,
                                         c2b_all + i * DMM, ln2g_all + i * DMM,
                                         ln2b_all + i * DMM, xbuf);

    if (i < NLL - 1) {
      const float* wconv = dcw_all + (size_t)i * DMM * DMM * 3;
      for (int t = 0; t < 3; ++t) {
        gemm_bt<<<gg, 256, 0, stream>>>(xbuf, wconv + t, dcb_all + i * DMM, tmp,
                                        3 * DMM, 3, t > 0 ? 1 : 0, t - 1);
      }
      stat_part<<<32, 256, 0, stream>>>(tmp, stp, stp2);
      stat_fin<<<1, 256, 0, stream>>>(stp, stp2, smean, srstd);
      bn_elu<<<NELEM / 256, 256, 0, stream>>>(tmp, smean, srstd, bng_all + i * DMM,
                                              bnb_all + i * DMM, xbuf);
    }
  }

  ln_final<<<ROWS / 4, 256, 0, stream>>>(xbuf, fng, fnb, d_out, flag);
}

// Round 3
// 1175.552 us; speedup vs baseline: 1.2312x; 1.2312x over previous
//
#include <hip/hip_runtime.h>
#include <stdint.h>

#define BB 4
#define LL 2048
#define DMM 256
#define HH 8
#define EE 32
#define NLL 3
#define ITR 16
#define UU 40
#define ROWS (BB*LL)          // 8192
#define NELEM (ROWS*DMM)      // 2097152

typedef __attribute__((ext_vector_type(8))) short short8;
typedef __attribute__((ext_vector_type(4))) float f32x4;

// ---------------- bf16 bit helpers (RNE) ----------------
__device__ __forceinline__ float bfbits(unsigned short u) {
  return __uint_as_float(((uint32_t)u) << 16);
}
__device__ __forceinline__ unsigned short f2b(float f) {
  uint32_t u = __float_as_uint(f);
  uint32_t r = (u + 0x7FFFu + ((u >> 16) & 1u)) >> 16;
  return (unsigned short)r;
}

// ---------------- threefry2x32 (exact JAX semantics) ----------------
__host__ __device__ inline void threefry2x32(uint32_t k0, uint32_t k1,
                                             uint32_t x0, uint32_t x1,
                                             uint32_t* o0, uint32_t* o1) {
  uint32_t ks2 = k0 ^ k1 ^ 0x1BD11BDAu;
  x0 += k0; x1 += k1;
#define TFR(r) { x0 += x1; x1 = (x1 << (r)) | (x1 >> (32 - (r))); x1 ^= x0; }
  TFR(13) TFR(15) TFR(26) TFR(6)
  x0 += k1;  x1 += ks2 + 1u;
  TFR(17) TFR(29) TFR(16) TFR(24)
  x0 += ks2; x1 += k0 + 2u;
  TFR(13) TFR(15) TFR(26) TFR(6)
  x0 += k0;  x1 += k1 + 3u;
  TFR(17) TFR(29) TFR(16) TFR(24)
  x0 += k1;  x1 += ks2 + 4u;
  TFR(13) TFR(15) TFR(26) TFR(6)
  x0 += ks2; x1 += k0 + 5u;
#undef TFR
  *o0 = x0; *o1 = x1;
}

__device__ __forceinline__ float wave_sum(float v) {
#pragma unroll
  for (int off = 32; off > 0; off >>= 1) v += __shfl_xor(v, off);
  return v;
}

// ---------------- dtype probe: flag=1 if input is float32, 0 if bf16 ----------------
__global__ __launch_bounds__(256) void probe_dtype(const void* __restrict__ x,
                                                   int* __restrict__ flag) {
  __shared__ int cnt;
  if (threadIdx.x == 0) cnt = 0;
  __syncthreads();
  const unsigned short* u = (const unsigned short*)x;
  int bad = 0;
  for (int j = threadIdx.x; j < 2048; j += 256) {
    float v = bfbits(u[j]);
    float a = fabsf(v);
    bool ok = (v == 0.0f) || (a > 1e-4f && a < 100.0f);
    if (!ok) bad++;
  }
  atomicAdd(&cnt, bad);
  __syncthreads();
  if (threadIdx.x == 0) *flag = (cnt > 100) ? 1 : 0;
}

// ---------------- mega convert: all inputs -> f32 (+optional bf16 copy) ----------------
struct CvtArgs {
  const void* src[23];
  float* dstF[23];
  unsigned short* dstB[23];
  int n[23];
  int blkStart[24];
};
__global__ __launch_bounds__(256) void mega_cvt(CvtArgs a, const int* __restrict__ flag) {
  int bid = blockIdx.x;
  int i = 0;
  while (i < 22 && bid >= a.blkStart[i + 1]) ++i;
  int e = (bid - a.blkStart[i]) * 256 + (int)threadIdx.x;
  if (e >= a.n[i]) return;
  float v; unsigned short rw;
  if (*flag) { v = ((const float*)a.src[i])[e]; rw = f2b(v); }
  else       { rw = ((const unsigned short*)a.src[i])[e]; v = bfbits(rw); }
  a.dstF[i][e] = v;
  if (a.dstB[i]) a.dstB[i][e] = rw;
}

// ---------------- conv weight repack: [ly][n][k][t] f32 -> [ly][t][n][k] bf16 ----------------
__global__ __launch_bounds__(256) void dcw_repack(const float* __restrict__ dcwF,
                                                  unsigned short* __restrict__ dcwT) {
  int gid = blockIdx.x * 256 + threadIdx.x;  // 393216 total
  if (gid >= (NLL - 1) * 3 * 65536) return;
  int ly = gid / 196608;
  int r = gid - ly * 196608;
  int t = r >> 16;
  int r2 = r & 65535;
  int n = r2 >> 8, k = r2 & 255;
  dcwT[gid] = f2b(dcwF[ly * 196608 + n * 768 + k * 3 + t]);
}

// ---------------- idx generation: lower_bits & 2047 ----------------
__global__ __launch_bounds__(256) void idx_kernel(uint32_t k20, uint32_t k21,
                                                  int* __restrict__ idx) {
  int j = blockIdx.x * 256 + threadIdx.x;
  if (j >= LL * UU) return;
  uint32_t o0, o1;
  const int half = (LL * UU) / 2;  // 40960
  if (j < half) {
    threefry2x32(k20, k21, (uint32_t)j, (uint32_t)(j + half), &o0, &o1);
    idx[j] = (int)(o0 & (LL - 1));
  } else {
    threefry2x32(k20, k21, (uint32_t)(j - half), (uint32_t)j, &o0, &o1);
    idx[j] = (int)(o1 & (LL - 1));
  }
}

// ---------------- f32 GEMM (Q,K only — top-k needs f32-exact scores) ----------------
#define GBM 64
#define GBN 64
#define GBK 16
__global__ __launch_bounds__(256) void gemm_bt(const float* __restrict__ A,
                                               const float* __restrict__ W,
                                               const float* __restrict__ bias,
                                               float* __restrict__ C) {
  __shared__ float As[GBK][GBM + 4];
  __shared__ float Bs[GBK][GBN + 4];
  int bm = blockIdx.x * GBM;
  int bn = blockIdx.y * GBN;
  int tid = threadIdx.x;
  int kk = tid & 15, rr = tid >> 4;
  int tx = tid & 15, ty = tid >> 4;
  float acc[4][4] = {};
  for (int k0 = 0; k0 < DMM; k0 += GBK) {
#pragma unroll
    for (int p = 0; p < 4; ++p) {
      int row = bm + rr + 16 * p;
      As[kk][rr + 16 * p] = A[(size_t)row * DMM + k0 + kk];
      Bs[kk][rr + 16 * p] = W[(size_t)(bn + rr + 16 * p) * DMM + k0 + kk];
    }
    __syncthreads();
#pragma unroll
    for (int kq = 0; kq < GBK; ++kq) {
      float av[4], bv[4];
#pragma unroll
      for (int i = 0; i < 4; ++i) av[i] = As[kq][ty * 4 + i];
#pragma unroll
      for (int j = 0; j < 4; ++j) bv[j] = Bs[kq][tx * 4 + j];
#pragma unroll
      for (int i = 0; i < 4; ++i)
#pragma unroll
        for (int j = 0; j < 4; ++j) acc[i][j] = fmaf(av[i], bv[j], acc[i][j]);
    }
    __syncthreads();
  }
#pragma unroll
  for (int i = 0; i < 4; ++i) {
    int row = bm + ty * 4 + i;
    float* crow = C + (size_t)row * DMM + bn + tx * 4;
#pragma unroll
    for (int j = 0; j < 4; ++j) crow[j] = acc[i][j] + bias[bn + tx * 4 + j];
  }
}

// ---------------- bf16 MFMA GEMM: C[8192,256] = A @ W^T (+bias), ntaps for conv ----------------
__global__ __launch_bounds__(256) void gemm_mfma(const unsigned short* __restrict__ A,
                                                 const unsigned short* __restrict__ W,
                                                 const float* __restrict__ bias,
                                                 float* __restrict__ C, int ntaps) {
  __shared__ unsigned short As[128][40];  // pad to 40 shorts (80B): 2-way max conflicts
  __shared__ unsigned short Bs[64][40];
  int bm = blockIdx.x * 128, bn = blockIdx.y * 64;
  int tid = threadIdx.x;
  int wave = tid >> 6, lane = tid & 63;
  int wm = wave >> 1, wn = wave & 1;
  int l15 = lane & 15, quad = lane >> 4;
  f32x4 acc[4][2];
#pragma unroll
  for (int i = 0; i < 4; ++i)
#pragma unroll
    for (int j = 0; j < 2; ++j) acc[i][j] = (f32x4){0.f, 0.f, 0.f, 0.f};
  for (int tap = 0; tap < ntaps; ++tap) {
    int lshift = (ntaps == 3) ? (tap - 1) : 0;
    const unsigned short* Wt = W + (size_t)tap * 65536;
    for (int k0 = 0; k0 < 256; k0 += 32) {
      __syncthreads();
      for (int c = tid; c < 512; c += 256) {
        int row = c >> 2, seg = c & 3;
        int grow = bm + row;
        if (lshift != 0) {
          int bidx = grow >> 11, l = grow & 2047;
          grow = (bidx << 11) | ((l + lshift + 2048) & 2047);
        }
        *(uint4*)(&As[row][seg * 8]) =
            *(const uint4*)(A + (size_t)grow * 256 + k0 + seg * 8);
      }
      {
        int row = tid >> 2, seg = tid & 3;
        *(uint4*)(&Bs[row][seg * 8]) =
            *(const uint4*)(Wt + (size_t)(bn + row) * 256 + k0 + seg * 8);
      }
      __syncthreads();
      short8 af[4], bfr[2];
#pragma unroll
      for (int mt = 0; mt < 4; ++mt)
        af[mt] = *(const short8*)(&As[wm * 64 + mt * 16 + l15][quad * 8]);
#pragma unroll
      for (int nt = 0; nt < 2; ++nt)
        bfr[nt] = *(const short8*)(&Bs[wn * 32 + nt * 16 + l15][quad * 8]);
#pragma unroll
      for (int mt = 0; mt < 4; ++mt)
#pragma unroll
        for (int nt = 0; nt < 2; ++nt)
          acc[mt][nt] = __builtin_amdgcn_mfma_f32_16x16x32_bf16(af[mt], bfr[nt],
                                                                acc[mt][nt], 0, 0, 0);
    }
  }
  // C/D layout: col = lane&15, row = quad*4 + r  [guide §3, m89-verified]
#pragma unroll
  for (int nt = 0; nt < 2; ++nt) {
    int n = bn + wn * 32 + nt * 16 + l15;
    float bv = bias[n];
#pragma unroll
    for (int mt = 0; mt < 4; ++mt)
#pragma unroll
      for (int r = 0; r < 4; ++r) {
        int m = bm + wm * 64 + mt * 16 + quad * 4 + r;
        C[(size_t)m * 256 + n] = acc[mt][nt][r] + bv;
      }
  }
}

// ---------------- M scores ----------------
__global__ __launch_bounds__(256) void m_kernel(const float* __restrict__ Q,
                                                const float* __restrict__ K,
                                                const int* __restrict__ idx,
                                                float* __restrict__ M) {
  int gid = blockIdx.x * 256 + threadIdx.x;  // (b*H+h)*L + l
  int l = gid & (LL - 1);
  int bh = gid >> 11;
  int h = bh & (HH - 1);
  int b = bh >> 3;
  const float4* q4 =
      reinterpret_cast<const float4*>(Q + ((size_t)(b * LL + l)) * DMM + h * EE);
  float4 qr[8];
#pragma unroll
  for (int i = 0; i < 8; ++i) qr[i] = q4[i];
  float mx = -1e30f, sm = 0.f;
  const int* ip = idx + l * UU;
  for (int u = 0; u < UU; ++u) {
    int j = ip[u];
    const float4* k4 =
        reinterpret_cast<const float4*>(K + ((size_t)(b * LL + j)) * DMM + h * EE);
    float s = 0.f;
#pragma unroll
    for (int i = 0; i < 8; ++i) {
      float4 kv = k4[i];
      s += qr[i].x * kv.x + qr[i].y * kv.y + qr[i].z * kv.z + qr[i].w * kv.w;
    }
    mx = fmaxf(mx, s);
    sm += s;
  }
  M[gid] = mx - sm * (1.0f / (float)LL);
}

// ---------------- top-k (u=40) per (b,h) ----------------
__global__ __launch_bounds__(256) void topk_kernel(const float* __restrict__ M,
                                                   int* __restrict__ top) {
  int bh = blockIdx.x;
  int tid = threadIdx.x;
  __shared__ float vals[LL];
  __shared__ float rv[256];
  __shared__ int ri[256];
  const float* m = M + (size_t)bh * LL;
  for (int j = tid; j < LL; j += 256) vals[j] = m[j];
  __syncthreads();
  for (int t = 0; t < UU; ++t) {
    float bv = -1e38f;
    int bi = LL;
    for (int j = tid; j < LL; j += 256) {
      float v = vals[j];
      if (v > bv || (v == bv && j < bi)) { bv = v; bi = j; }
    }
    rv[tid] = bv; ri[tid] = bi;
    __syncthreads();
    for (int s = 128; s > 0; s >>= 1) {
      if (tid < s) {
        float ov = rv[tid + s]; int oi = ri[tid + s];
        if (ov > rv[tid] || (ov == rv[tid] && oi < ri[tid])) { rv[tid] = ov; ri[tid] = oi; }
      }
      __syncthreads();
    }
    if (tid == 0) { top[bh * UU + t] = ri[0]; vals[ri[0]] = -1e38f; }
    __syncthreads();
  }
}

// ---------------- v mean over L ----------------
__global__ __launch_bounds__(256) void vmean_part(const float* __restrict__ V,
                                                  float* __restrict__ pv) {
  int blk = blockIdx.x;  // b*8 + c
  int b = blk >> 3, c = blk & 7;
  int d = threadIdx.x;
  float s = 0.f;
  int base = b * LL + c * 256;
  for (int r = 0; r < 256; ++r) s += V[(size_t)(base + r) * DMM + d];
  pv[(size_t)blk * DMM + d] = s;
}
__global__ __launch_bounds__(256) void vmean_fin(const float* __restrict__ pv,
                                                 float* __restrict__ vm) {
  int gid = blockIdx.x * 256 + threadIdx.x;  // B*DM
  int b = gid >> 8, d = gid & 255;
  float s = 0.f;
#pragma unroll
  for (int c = 0; c < 8; ++c) s += pv[(size_t)(b * 8 + c) * DMM + d];
  vm[gid] = s * (1.0f / (float)LL);
}

__global__ __launch_bounds__(256) void ctx_init2(const float* __restrict__ vm,
                                                 unsigned short* __restrict__ ctxbf) {
  int gid = blockIdx.x * 256 + threadIdx.x;
  int d = gid & 255;
  int b = gid >> 19;
  ctxbf[gid] = f2b(vm[b * DMM + d]);
}

// ---------------- flash attention for 8 selected queries per block ----------------
// grid (5, 32): x = query-group (8 each), y = b*H+h
__global__ __launch_bounds__(256) void attn_sel2(const float* __restrict__ Q,
                                                 const float* __restrict__ K,
                                                 const float* __restrict__ V,
                                                 const int* __restrict__ top,
                                                 unsigned short* __restrict__ ctxbf) {
  __shared__ float Qs[8][32];
  __shared__ unsigned short ps[8][2048];  // 32KB (scores/probs bf16)
  __shared__ float Vt[128][36];           // 18KB, padded
  __shared__ int qrows[8];
  int qg = blockIdx.x, bh = blockIdx.y;
  int h = bh & 7, b = bh >> 3;
  int tid = threadIdx.x;
  int wave = tid >> 6, lane = tid & 63;
  if (tid < 8) qrows[tid] = top[bh * UU + qg * 8 + tid];
  __syncthreads();
  {
    int q = tid >> 5, d = tid & 31;
    Qs[q][d] = Q[((size_t)(b * LL + qrows[q])) * DMM + h * EE + d];
  }
  __syncthreads();
  const float scale = 0.17677669529663687f;  // 1/sqrt(32)
  for (int i = 0; i < 8; ++i) {
    int k = tid + 256 * i;
    const float4* kp = (const float4*)(K + ((size_t)(b * LL + k)) * DMM + h * EE);
    float4 kr[8];
#pragma unroll
    for (int j = 0; j < 8; ++j) kr[j] = kp[j];
#pragma unroll
    for (int q = 0; q < 8; ++q) {
      const float4* qp = (const float4*)Qs[q];
      float s = 0.f;
#pragma unroll
      for (int j = 0; j < 8; ++j) {
        float4 qv = qp[j];
        s += qv.x * kr[j].x + qv.y * kr[j].y + qv.z * kr[j].z + qv.w * kr[j].w;
      }
      ps[q][k] = f2b(s * scale);
    }
  }
  __syncthreads();
  // softmax: wave w owns query w
  float mx = -1e30f;
#pragma unroll
  for (int j = 0; j < 32; ++j) mx = fmaxf(mx, bfbits(ps[wave][lane + 64 * j]));
#pragma unroll
  for (int off = 32; off > 0; off >>= 1) mx = fmaxf(mx, __shfl_xor(mx, off));
  float sum = 0.f;
#pragma unroll
  for (int j = 0; j < 32; ++j) {
    int idx = lane + 64 * j;
    float e = expf(bfbits(ps[wave][idx]) - mx);
    sum += e;
    ps[wave][idx] = f2b(e);
  }
  sum = wave_sum(sum);
  float inv = 1.0f / sum;
  // PV: lane = (kg 0..7, dq 0..7): accumulates dims dq*4..dq*4+3 over keys kg+8j
  int kg = lane & 7, dq = lane >> 3;
  float o0 = 0.f, o1 = 0.f, o2 = 0.f, o3 = 0.f;
  for (int t8 = 0; t8 < 16; ++t8) {
    __syncthreads();
    for (int c = tid; c < 1024; c += 256) {
      int row = c >> 3, seg = c & 7;
      *(float4*)(&Vt[row][seg * 4]) =
          *(const float4*)(V + ((size_t)(b * LL + t8 * 128 + row)) * DMM + h * EE + seg * 4);
    }
    __syncthreads();
    const unsigned short* pw = &ps[wave][t8 * 128];
#pragma unroll
    for (int j = 0; j < 16; ++j) {
      int r = kg + 8 * j;
      float pv = bfbits(pw[r]);
      const float4 vv = *(const float4*)(&Vt[r][dq * 4]);
      o0 += pv * vv.x; o1 += pv * vv.y; o2 += pv * vv.z; o3 += pv * vv.w;
    }
  }
#pragma unroll
  for (int mm = 1; mm <= 4; mm <<= 1) {
    o0 += __shfl_xor(o0, mm); o1 += __shfl_xor(o1, mm);
    o2 += __shfl_xor(o2, mm); o3 += __shfl_xor(o3, mm);
  }
  if (kg == 0) {
    size_t base = ((size_t)(b * LL + qrows[wave])) * DMM + h * EE + dq * 4;
    ctxbf[base + 0] = f2b(o0 * inv);
    ctxbf[base + 1] = f2b(o1 * inv);
    ctxbf[base + 2] = f2b(o2 * inv);
    ctxbf[base + 3] = f2b(o3 * inv);
  }
}

// ---------------- LayerNorm(x + t) ----------------
__global__ __launch_bounds__(256) void ln_res(const float* __restrict__ X,
                                              const float* __restrict__ T,
                                              const float* __restrict__ g,
                                              const float* __restrict__ bb,
                                              float* __restrict__ Out) {
  int wave = threadIdx.x >> 6, lane = threadIdx.x & 63;
  size_t row = (size_t)blockIdx.x * 4 + wave;
  const float* xr = X + row * DMM;
  const float* tr = T + row * DMM;
  float v[4];
#pragma unroll
  for (int i = 0; i < 4; ++i) v[i] = xr[lane + 64 * i] + tr[lane + 64 * i];
  float s = wave_sum(v[0] + v[1] + v[2] + v[3]);
  float m = s * (1.0f / (float)DMM);
  float sq = 0.f;
#pragma unroll
  for (int i = 0; i < 4; ++i) { float d = v[i] - m; sq += d * d; }
  sq = wave_sum(sq);
  float rstd = rsqrtf(sq * (1.0f / (float)DMM) + 1e-5f);
#pragma unroll
  for (int i = 0; i < 4; ++i) {
    int d = lane + 64 * i;
    Out[row * DMM + d] = (v[i] - m) * rstd * g[d] + bb[d];
  }
}

// ---------------- fused FFN (INTER=16) + residual + LN (+bf16 copy out) ----------------
__global__ __launch_bounds__(256) void ffn_ln(const float* __restrict__ X,
                                              const float* __restrict__ w1,
                                              const float* __restrict__ b1,
                                              const float* __restrict__ w2,
                                              const float* __restrict__ b2,
                                              const float* __restrict__ g,
                                              const float* __restrict__ bb,
                                              float* __restrict__ Out,
                                              unsigned short* __restrict__ OutB) {
  int wave = threadIdx.x >> 6, lane = threadIdx.x & 63;
  size_t row = (size_t)blockIdx.x * 4 + wave;
  __shared__ float xs[4][DMM];
  const float* xr = X + row * DMM;
  float xv[4];
#pragma unroll
  for (int i = 0; i < 4; ++i) {
    xv[i] = xr[lane + 64 * i];
    xs[wave][lane + 64 * i] = xv[i];
  }
  __syncthreads();
  int f = lane & 15, qtr = lane >> 4;
  const float* w1p = w1 + f * DMM + qtr * 64;
  const float* xq = &xs[wave][qtr * 64];
  float pacc = 0.f;
#pragma unroll 8
  for (int d = 0; d < 64; ++d) pacc += xq[d] * w1p[d];
  pacc += __shfl_xor(pacc, 16);
  pacc += __shfl_xor(pacc, 32);
  float y1 = fmaxf(pacc + b1[f], 0.0f);
  float y1v[16];
#pragma unroll
  for (int ff = 0; ff < 16; ++ff) y1v[ff] = __shfl(y1, ff);
  float v[4];
#pragma unroll
  for (int i = 0; i < 4; ++i) {
    int d = lane + 64 * i;
    const float* w2p = w2 + d * ITR;
    float a = b2[d];
#pragma unroll
    for (int ff = 0; ff < 16; ++ff) a += y1v[ff] * w2p[ff];
    v[i] = xv[i] + a;
  }
  float s = wave_sum(v[0] + v[1] + v[2] + v[3]);
  float m = s * (1.0f / (float)DMM);
  float sq = 0.f;
#pragma unroll
  for (int i = 0; i < 4; ++i) { float d = v[i] - m; sq += d * d; }
  sq = wave_sum(sq);
  float rstd = rsqrtf(sq * (1.0f / (float)DMM) + 1e-5f);
#pragma unroll
  for (int i = 0; i < 4; ++i) {
    int d = lane + 64 * i;
    float val = (v[i] - m) * rstd * g[d] + bb[d];
    Out[row * DMM + d] = val;
    OutB[row * DMM + d] = f2b(val);
  }
}

// ---------------- batchnorm stats ----------------
__global__ __launch_bounds__(256) void stat_part(const float* __restrict__ Y,
                                                 float* __restrict__ ps,
                                                 float* __restrict__ ps2) {
  int c = blockIdx.x;
  int d = threadIdx.x;
  float s = 0.f, s2 = 0.f;
  int base = c * 256;
  for (int r = 0; r < 256; ++r) {
    float v = Y[(size_t)(base + r) * DMM + d];
    s += v;
    s2 += v * v;
  }
  ps[(size_t)c * DMM + d] = s;
  ps2[(size_t)c * DMM + d] = s2;
}
__global__ __launch_bounds__(256) void stat_fin(const float* __restrict__ ps,
                                                const float* __restrict__ ps2,
                                                float* __restrict__ mean,
                                                float* __restrict__ rstd) {
  int d = threadIdx.x;
  float s = 0.f, s2 = 0.f;
  for (int c = 0; c < 32; ++c) {
    s += ps[(size_t)c * DMM + d];
    s2 += ps2[(size_t)c * DMM + d];
  }
  float m = s * (1.0f / (float)ROWS);
  float var = s2 * (1.0f / (float)ROWS) - m * m;
  mean[d] = m;
  rstd[d] = rsqrtf(var + 1e-5f);
}

__global__ __launch_bounds__(256) void bn_elu(const float* __restrict__ Y,
                                              const float* __restrict__ mean,
                                              const float* __restrict__ rstd,
                                              const float* __restrict__ g,
                                              const float* __restrict__ bb,
                                              float* __restrict__ X,
                                              unsigned short* __restrict__ XB) {
  int gid = blockIdx.x * 256 + threadIdx.x;
  int d = gid & 255;
  float v = (Y[gid] - mean[d]) * rstd[d] * g[d] + bb[d];
  float r = v > 0.f ? v : expm1f(v);
  X[gid] = r;
  XB[gid] = f2b(r);
}

// ---------------- final LN -> out (dtype per flag) ----------------
__global__ __launch_bounds__(256) void ln_final(const float* __restrict__ X,
                                                const float* __restrict__ g,
                                                const float* __restrict__ bb,
                                                void* __restrict__ Out,
                                                const int* __restrict__ flag) {
  int wave = threadIdx.x >> 6, lane = threadIdx.x & 63;
  size_t row = (size_t)blockIdx.x * 4 + wave;
  const float* xr = X + row * DMM;
  float v[4];
#pragma unroll
  for (int i = 0; i < 4; ++i) v[i] = xr[lane + 64 * i];
  float s = wave_sum(v[0] + v[1] + v[2] + v[3]);
  float m = s * (1.0f / (float)DMM);
  float sq = 0.f;
#pragma unroll
  for (int i = 0; i < 4; ++i) { float d = v[i] - m; sq += d * d; }
  sq = wave_sum(sq);
  float rstd = rsqrtf(sq * (1.0f / (float)DMM) + 1e-5f);
  int isf32 = *flag;
#pragma unroll
  for (int i = 0; i < 4; ++i) {
    int d = lane + 64 * i;
    float val = (v[i] - m) * rstd * g[d] + bb[d];
    if (isf32) ((float*)Out)[row * DMM + d] = val;
    else       ((unsigned short*)Out)[row * DMM + d] = f2b(val);
  }
}

extern "C" void kernel_launch(void* const* d_in, const int* in_sizes, int n_in,
                              void* d_out, int out_size, void* d_ws, size_t ws_size,
                              hipStream_t stream) {
  (void)in_sizes; (void)n_in; (void)out_size; (void)ws_size;

  // ---- workspace layout ----
  float* xbuf = (float*)d_ws;
  float* kb   = xbuf + NELEM;
  float* vb   = kb + NELEM;
  float* qb   = vb + NELEM;   // qb aliases tmp (Q dead after attn_sel2)
  float* tmp  = qb;
  float* Mbuf = qb + NELEM;
  float* vmp  = Mbuf + BB * HH * LL;
  float* vmean= vmp + BB * 8 * DMM;
  float* stp  = vmean + BB * DMM;
  float* stp2 = stp + 32 * DMM;
  float* smean= stp2 + 32 * DMM;
  float* srstd= smean + DMM;
  float* wp   = srstd + DMM;
  const int wsz[23] = {
      NELEM,
      NLL * DMM * DMM, NLL * DMM,    // wq bq
      NLL * DMM * DMM, NLL * DMM,    // wk bk
      NLL * DMM * DMM, NLL * DMM,    // wv bv
      NLL * DMM * DMM, NLL * DMM,    // wo bo
      NLL * ITR * DMM, NLL * ITR,    // c1w c1b
      NLL * DMM * ITR, NLL * DMM,    // c2w c2b
      NLL * DMM, NLL * DMM,          // ln1g ln1b
      NLL * DMM, NLL * DMM,          // ln2g ln2b
      (NLL - 1) * DMM * DMM * 3, (NLL - 1) * DMM,  // dcw dcb
      (NLL - 1) * DMM, (NLL - 1) * DMM,            // bng bnb
      DMM, DMM                       // fng fnb
  };
  float* fptr[23];
  fptr[0] = xbuf;
  for (int i = 1; i < 23; ++i) { fptr[i] = wp; wp += wsz[i]; }
  unsigned short* xbf   = (unsigned short*)wp;
  unsigned short* ctxbf = xbf + NELEM;
  unsigned short* wvbf  = ctxbf + NELEM;
  unsigned short* wobf  = wvbf + NLL * DMM * DMM;
  unsigned short* dcwT  = wobf + NLL * DMM * DMM;
  int* idxb = (int*)(dcwT + (NLL - 1) * 3 * DMM * DMM);
  int* topb = idxb + LL * UU;
  int* flag = topb + BB * HH * UU;

  // ---- probe + convert everything in one pass ----
  probe_dtype<<<1, 256, 0, stream>>>(d_in[0], flag);
  CvtArgs ca;
  int totalBlk = 0;
  for (int i = 0; i < 23; ++i) {
    ca.src[i] = d_in[i];
    ca.dstF[i] = fptr[i];
    ca.dstB[i] = nullptr;
    ca.n[i] = wsz[i];
    ca.blkStart[i] = totalBlk;
    totalBlk += (wsz[i] + 255) / 256;
  }
  ca.blkStart[23] = totalBlk;
  ca.dstB[0] = xbf;
  ca.dstB[5] = wvbf;
  ca.dstB[7] = wobf;
  mega_cvt<<<totalBlk, 256, 0, stream>>>(ca, flag);
  dcw_repack<<<((NLL - 1) * 3 * 65536 + 255) / 256, 256, 0, stream>>>(fptr[17], dcwT);

  dim3 gg(ROWS / GBM, DMM / GBN);
  dim3 gm(ROWS / 128, DMM / 64);

  for (int i = 0; i < NLL; ++i) {
    gemm_bt<<<gg, 256, 0, stream>>>(xbuf, fptr[1] + (size_t)i * DMM * DMM,
                                    fptr[2] + i * DMM, qb);
    gemm_bt<<<gg, 256, 0, stream>>>(xbuf, fptr[3] + (size_t)i * DMM * DMM,
                                    fptr[4] + i * DMM, kb);
    gemm_mfma<<<gm, 256, 0, stream>>>(xbf, wvbf + (size_t)i * DMM * DMM,
                                      fptr[6] + i * DMM, vb, 1);

    // JAX PRNG: key(42) -> fold_in(i) -> split -> k2 (lower-bits key)
    uint32_t ki0, ki1, a0, a1, b0, b1;
    threefry2x32(0u, 42u, 0u, (uint32_t)i, &ki0, &ki1);
    threefry2x32(ki0, ki1, 0u, 2u, &a0, &a1);
    threefry2x32(ki0, ki1, 1u, 3u, &b0, &b1);
    (void)a0; (void)b0;
    idx_kernel<<<(LL * UU) / 256, 256, 0, stream>>>(a1, b1, idxb);

    m_kernel<<<(BB * HH * LL) / 256, 256, 0, stream>>>(qb, kb, idxb, Mbuf);
    topk_kernel<<<BB * HH, 256, 0, stream>>>(Mbuf, topb);
    vmean_part<<<BB * 8, 256, 0, stream>>>(vb, vmp);
    vmean_fin<<<(BB * DMM) / 256, 256, 0, stream>>>(vmp, vmean);
    ctx_init2<<<NELEM / 256, 256, 0, stream>>>(vmean, ctxbf);
    attn_sel2<<<dim3(5, BB * HH), 256, 0, stream>>>(qb, kb, vb, topb, ctxbf);

    gemm_mfma<<<gm, 256, 0, stream>>>(ctxbf, wobf + (size_t)i * DMM * DMM,
                                      fptr[8] + i * DMM, tmp, 1);
    ln_res<<<ROWS / 4, 256, 0, stream>>>(xbuf, tmp, fptr[13] + i * DMM,
                                         fptr[14] + i * DMM, xbuf);
    ffn_ln<<<ROWS / 4, 256, 0, stream>>>(xbuf, fptr[9] + (size_t)i * ITR * DMM,
                                         fptr[10] + i * ITR,
                                         fptr[11] + (size_t)i * DMM * ITR,
                                         fptr[12] + i * DMM, fptr[15] + i * DMM,
                                         fptr[16] + i * DMM, xbuf, xbf);

    if (i < NLL - 1) {
      gemm_mfma<<<gm, 256, 0, stream>>>(xbf, dcwT + (size_t)i * 3 * DMM * DMM,
                                        fptr[18] + i * DMM, tmp, 3);
      stat_part<<<32, 256, 0, stream>>>(tmp, stp, stp2);
      stat_fin<<<1, 256, 0, stream>>>(stp, stp2, smean, srstd);
      bn_elu<<<NELEM / 256, 256, 0, stream>>>(tmp, smean, srstd, fptr[19] + i * DMM,
                                              fptr[20] + i * DMM, xbuf, xbf);
    }
  }

  ln_final<<<ROWS / 4, 256, 0, stream>>>(xbuf, fptr[21], fptr[22], d_out, flag);
}

// Round 4
// 883.283 us; speedup vs baseline: 1.6386x; 1.3309x over previous
//
#include <hip/hip_runtime.h>
#include <stdint.h>

#define BB 4
#define LL 2048
#define DMM 256
#define HH 8
#define EE 32
#define NLL 3
#define ITR 16
#define UU 40
#define ROWS (BB*LL)          // 8192
#define NELEM (ROWS*DMM)      // 2097152

typedef __attribute__((ext_vector_type(8))) short short8;
typedef __attribute__((ext_vector_type(4))) float f32x4;
typedef unsigned long long u64;

// ---------------- bf16 bit helpers (RNE) ----------------
__device__ __forceinline__ float bfbits(unsigned short u) {
  return __uint_as_float(((uint32_t)u) << 16);
}
__device__ __forceinline__ unsigned short f2b(float f) {
  uint32_t u = __float_as_uint(f);
  uint32_t r = (u + 0x7FFFu + ((u >> 16) & 1u)) >> 16;
  return (unsigned short)r;
}

// ---------------- threefry2x32 (exact JAX semantics) ----------------
__host__ __device__ inline void threefry2x32(uint32_t k0, uint32_t k1,
                                             uint32_t x0, uint32_t x1,
                                             uint32_t* o0, uint32_t* o1) {
  uint32_t ks2 = k0 ^ k1 ^ 0x1BD11BDAu;
  x0 += k0; x1 += k1;
#define TFR(r) { x0 += x1; x1 = (x1 << (r)) | (x1 >> (32 - (r))); x1 ^= x0; }
  TFR(13) TFR(15) TFR(26) TFR(6)
  x0 += k1;  x1 += ks2 + 1u;
  TFR(17) TFR(29) TFR(16) TFR(24)
  x0 += ks2; x1 += k0 + 2u;
  TFR(13) TFR(15) TFR(26) TFR(6)
  x0 += k0;  x1 += k1 + 3u;
  TFR(17) TFR(29) TFR(16) TFR(24)
  x0 += k1;  x1 += ks2 + 4u;
  TFR(13) TFR(15) TFR(26) TFR(6)
  x0 += ks2; x1 += k0 + 5u;
#undef TFR
  *o0 = x0; *o1 = x1;
}

__device__ __forceinline__ float wave_sum(float v) {
#pragma unroll
  for (int off = 32; off > 0; off >>= 1) v += __shfl_xor(v, off);
  return v;
}

// ---------------- dtype probe: flag=1 if input is float32, 0 if bf16 ----------------
__global__ __launch_bounds__(256) void probe_dtype(const void* __restrict__ x,
                                                   int* __restrict__ flag) {
  __shared__ int cnt;
  if (threadIdx.x == 0) cnt = 0;
  __syncthreads();
  const unsigned short* u = (const unsigned short*)x;
  int bad = 0;
  for (int j = threadIdx.x; j < 2048; j += 256) {
    float v = bfbits(u[j]);
    float a = fabsf(v);
    bool ok = (v == 0.0f) || (a > 1e-4f && a < 100.0f);
    if (!ok) bad++;
  }
  atomicAdd(&cnt, bad);
  __syncthreads();
  if (threadIdx.x == 0) *flag = (cnt > 100) ? 1 : 0;
}

// ---------------- mega convert ----------------
struct CvtArgs {
  const void* src[23];
  float* dstF[23];
  unsigned short* dstB[23];
  int n[23];
  int blkStart[24];
};
__global__ __launch_bounds__(256) void mega_cvt(CvtArgs a, const int* __restrict__ flag) {
  int bid = blockIdx.x;
  int i = 0;
  while (i < 22 && bid >= a.blkStart[i + 1]) ++i;
  int e = (bid - a.blkStart[i]) * 256 + (int)threadIdx.x;
  if (e >= a.n[i]) return;
  float v; unsigned short rw;
  if (*flag) { v = ((const float*)a.src[i])[e]; rw = f2b(v); }
  else       { rw = ((const unsigned short*)a.src[i])[e]; v = bfbits(rw); }
  a.dstF[i][e] = v;
  if (a.dstB[i]) a.dstB[i][e] = rw;
}

// ---------------- conv weight repack ----------------
__global__ __launch_bounds__(256) void dcw_repack(const float* __restrict__ dcwF,
                                                  unsigned short* __restrict__ dcwT) {
  int gid = blockIdx.x * 256 + threadIdx.x;
  if (gid >= (NLL - 1) * 3 * 65536) return;
  int ly = gid / 196608;
  int r = gid - ly * 196608;
  int t = r >> 16;
  int r2 = r & 65535;
  int n = r2 >> 8, k = r2 & 255;
  dcwT[gid] = f2b(dcwF[ly * 196608 + n * 768 + k * 3 + t]);
}

// ---------------- idx generation ----------------
__global__ __launch_bounds__(256) void idx_kernel(uint32_t k20, uint32_t k21,
                                                  int* __restrict__ idx) {
  int j = blockIdx.x * 256 + threadIdx.x;
  if (j >= LL * UU) return;
  uint32_t o0, o1;
  const int half = (LL * UU) / 2;
  if (j < half) {
    threefry2x32(k20, k21, (uint32_t)j, (uint32_t)(j + half), &o0, &o1);
    idx[j] = (int)(o0 & (LL - 1));
  } else {
    threefry2x32(k20, k21, (uint32_t)(j - half), (uint32_t)j, &o0, &o1);
    idx[j] = (int)(o1 & (LL - 1));
  }
}

// ---------------- f32 GEMM, Q and K in one launch (z=0:Q, z=1:K) ----------------
#define GBM 64
#define GBN 64
#define GBK 16
__global__ __launch_bounds__(256) void gemm_qk(const float* __restrict__ A,
                                               const float* __restrict__ Wq,
                                               const float* __restrict__ Wk,
                                               const float* __restrict__ bq,
                                               const float* __restrict__ bk,
                                               float* __restrict__ Cq,
                                               float* __restrict__ Ck) {
  const float* W = blockIdx.z ? Wk : Wq;
  const float* bias = blockIdx.z ? bk : bq;
  float* C = blockIdx.z ? Ck : Cq;
  __shared__ float As[GBK][GBM + 4];
  __shared__ float Bs[GBK][GBN + 4];
  int bm = blockIdx.x * GBM;
  int bn = blockIdx.y * GBN;
  int tid = threadIdx.x;
  int kk = tid & 15, rr = tid >> 4;
  int tx = tid & 15, ty = tid >> 4;
  float acc[4][4] = {};
  for (int k0 = 0; k0 < DMM; k0 += GBK) {
#pragma unroll
    for (int p = 0; p < 4; ++p) {
      int row = bm + rr + 16 * p;
      As[kk][rr + 16 * p] = A[(size_t)row * DMM + k0 + kk];
      Bs[kk][rr + 16 * p] = W[(size_t)(bn + rr + 16 * p) * DMM + k0 + kk];
    }
    __syncthreads();
#pragma unroll
    for (int kq = 0; kq < GBK; ++kq) {
      float av[4], bv[4];
#pragma unroll
      for (int i = 0; i < 4; ++i) av[i] = As[kq][ty * 4 + i];
#pragma unroll
      for (int j = 0; j < 4; ++j) bv[j] = Bs[kq][tx * 4 + j];
#pragma unroll
      for (int i = 0; i < 4; ++i)
#pragma unroll
        for (int j = 0; j < 4; ++j) acc[i][j] = fmaf(av[i], bv[j], acc[i][j]);
    }
    __syncthreads();
  }
#pragma unroll
  for (int i = 0; i < 4; ++i) {
    int row = bm + ty * 4 + i;
    float* crow = C + (size_t)row * DMM + bn + tx * 4;
#pragma unroll
    for (int j = 0; j < 4; ++j) crow[j] = acc[i][j] + bias[bn + tx * 4 + j];
  }
}

// ---------------- bf16 MFMA GEMM (+3-tap conv mode) ----------------
__global__ __launch_bounds__(256) void gemm_mfma(const unsigned short* __restrict__ A,
                                                 const unsigned short* __restrict__ W,
                                                 const float* __restrict__ bias,
                                                 float* __restrict__ C, int ntaps) {
  __shared__ unsigned short As[128][40];
  __shared__ unsigned short Bs[64][40];
  int bm = blockIdx.x * 128, bn = blockIdx.y * 64;
  int tid = threadIdx.x;
  int wave = tid >> 6, lane = tid & 63;
  int wm = wave >> 1, wn = wave & 1;
  int l15 = lane & 15, quad = lane >> 4;
  f32x4 acc[4][2];
#pragma unroll
  for (int i = 0; i < 4; ++i)
#pragma unroll
    for (int j = 0; j < 2; ++j) acc[i][j] = (f32x4){0.f, 0.f, 0.f, 0.f};
  for (int tap = 0; tap < ntaps; ++tap) {
    int lshift = (ntaps == 3) ? (tap - 1) : 0;
    const unsigned short* Wt = W + (size_t)tap * 65536;
    for (int k0 = 0; k0 < 256; k0 += 32) {
      __syncthreads();
      for (int c = tid; c < 512; c += 256) {
        int row = c >> 2, seg = c & 3;
        int grow = bm + row;
        if (lshift != 0) {
          int bidx = grow >> 11, l = grow & 2047;
          grow = (bidx << 11) | ((l + lshift + 2048) & 2047);
        }
        *(uint4*)(&As[row][seg * 8]) =
            *(const uint4*)(A + (size_t)grow * 256 + k0 + seg * 8);
      }
      {
        int row = tid >> 2, seg = tid & 3;
        *(uint4*)(&Bs[row][seg * 8]) =
            *(const uint4*)(Wt + (size_t)(bn + row) * 256 + k0 + seg * 8);
      }
      __syncthreads();
      short8 af[4], bfr[2];
#pragma unroll
      for (int mt = 0; mt < 4; ++mt)
        af[mt] = *(const short8*)(&As[wm * 64 + mt * 16 + l15][quad * 8]);
#pragma unroll
      for (int nt = 0; nt < 2; ++nt)
        bfr[nt] = *(const short8*)(&Bs[wn * 32 + nt * 16 + l15][quad * 8]);
#pragma unroll
      for (int mt = 0; mt < 4; ++mt)
#pragma unroll
        for (int nt = 0; nt < 2; ++nt)
          acc[mt][nt] = __builtin_amdgcn_mfma_f32_16x16x32_bf16(af[mt], bfr[nt],
                                                                acc[mt][nt], 0, 0, 0);
    }
  }
#pragma unroll
  for (int nt = 0; nt < 2; ++nt) {
    int n = bn + wn * 32 + nt * 16 + l15;
    float bv = bias[n];
#pragma unroll
    for (int mt = 0; mt < 4; ++mt)
#pragma unroll
      for (int r = 0; r < 4; ++r) {
        int m = bm + wm * 64 + mt * 16 + quad * 4 + r;
        C[(size_t)m * 256 + n] = acc[mt][nt][r] + bv;
      }
  }
}

// ---------------- M scores ----------------
__global__ __launch_bounds__(256) void m_kernel(const float* __restrict__ Q,
                                                const float* __restrict__ K,
                                                const int* __restrict__ idx,
                                                float* __restrict__ M) {
  int gid = blockIdx.x * 256 + threadIdx.x;
  int l = gid & (LL - 1);
  int bh = gid >> 11;
  int h = bh & (HH - 1);
  int b = bh >> 3;
  const float4* q4 =
      reinterpret_cast<const float4*>(Q + ((size_t)(b * LL + l)) * DMM + h * EE);
  float4 qr[8];
#pragma unroll
  for (int i = 0; i < 8; ++i) qr[i] = q4[i];
  float mx = -1e30f, sm = 0.f;
  const int* ip = idx + l * UU;
  for (int u = 0; u < UU; ++u) {
    int j = ip[u];
    const float4* k4 =
        reinterpret_cast<const float4*>(K + ((size_t)(b * LL + j)) * DMM + h * EE);
    float s = 0.f;
#pragma unroll
    for (int i = 0; i < 8; ++i) {
      float4 kv = k4[i];
      s += qr[i].x * kv.x + qr[i].y * kv.y + qr[i].z * kv.z + qr[i].w * kv.w;
    }
    mx = fmaxf(mx, s);
    sm += s;
  }
  M[gid] = mx - sm * (1.0f / (float)LL);
}

// ---------------- top-k stage A: per-256-chunk bitonic, emit top-40 ----------------
__global__ __launch_bounds__(256) void cand_topk(const float* __restrict__ M,
                                                 u64* __restrict__ cand) {
  __shared__ u64 a[256];
  int bh = blockIdx.x >> 3, c = blockIdx.x & 7;
  int tid = threadIdx.x;
  int l = c * 256 + tid;
  float v = M[(size_t)bh * LL + l];
  uint32_t bits = __float_as_uint(v);
  uint32_t kv = (bits & 0x80000000u) ? ~bits : (bits | 0x80000000u);
  a[tid] = ((u64)kv << 32) | (uint32_t)(2047 - l);
  __syncthreads();
  for (int k = 2; k <= 256; k <<= 1)
    for (int j = k >> 1; j > 0; j >>= 1) {
      int ixj = tid ^ j;
      if (ixj > tid) {
        bool up = ((tid & k) == 0);  // ascending overall
        u64 x = a[tid], y = a[ixj];
        if ((x > y) == up) { a[tid] = y; a[ixj] = x; }
      }
      __syncthreads();
    }
  if (tid >= 216) cand[(size_t)blockIdx.x * 40 + (tid - 216)] = a[tid];
}

// ---------------- top-k stage B: merge 320 candidates, output sorted top-40 ----------------
__global__ __launch_bounds__(256) void merge_topk(const u64* __restrict__ cand,
                                                  int* __restrict__ top) {
  __shared__ u64 a[512];
  int bh = blockIdx.x;
  int tid = threadIdx.x;
  for (int t = tid; t < 512; t += 256)
    a[t] = (t < 320) ? cand[(size_t)bh * 320 + t] : 0ULL;
  __syncthreads();
  for (int k = 2; k <= 512; k <<= 1)
    for (int j = k >> 1; j > 0; j >>= 1) {
      for (int t = tid; t < 512; t += 256) {
        int ixj = t ^ j;
        if (ixj > t) {
          bool up = ((t & k) == 0);
          u64 x = a[t], y = a[ixj];
          if ((x > y) == up) { a[t] = y; a[ixj] = x; }
        }
      }
      __syncthreads();
    }
  if (tid < UU) {
    u64 key = a[511 - tid];  // descending; ties -> smaller index first
    top[bh * UU + tid] = 2047 - (int)(uint32_t)(key & 0xFFFFFFFFu);
  }
}

// ---------------- v mean over L ----------------
__global__ __launch_bounds__(256) void vmean_part(const float* __restrict__ V,
                                                  float* __restrict__ pv) {
  int blk = blockIdx.x;
  int b = blk >> 3, c = blk & 7;
  int d = threadIdx.x;
  float s = 0.f;
  int base = b * LL + c * 256;
  for (int r = 0; r < 256; ++r) s += V[(size_t)(base + r) * DMM + d];
  pv[(size_t)blk * DMM + d] = s;
}
__global__ __launch_bounds__(256) void vmean_fin(const float* __restrict__ pv,
                                                 float* __restrict__ vm) {
  int gid = blockIdx.x * 256 + threadIdx.x;
  int b = gid >> 8, d = gid & 255;
  float s = 0.f;
#pragma unroll
  for (int c = 0; c < 8; ++c) s += pv[(size_t)(b * 8 + c) * DMM + d];
  vm[gid] = s * (1.0f / (float)LL);
}

__global__ __launch_bounds__(256) void ctx_init2(const float* __restrict__ vm,
                                                 unsigned short* __restrict__ ctxbf) {
  int gid = blockIdx.x * 256 + threadIdx.x;
  int d = gid & 255;
  int b = gid >> 19;
  ctxbf[gid] = f2b(vm[b * DMM + d]);
}

// ---------------- split-K flash attention: partials ----------------
// grid (kc=8, bh=32); each block: 40 queries x 256 keys x 32 dims
__global__ __launch_bounds__(256) void attn_part(const float* __restrict__ Q,
                                                 const float* __restrict__ K,
                                                 const float* __restrict__ V,
                                                 const int* __restrict__ top,
                                                 float* __restrict__ pm,
                                                 float* __restrict__ pl,
                                                 float* __restrict__ po) {
  __shared__ float Qs[40][32];            // 5 KB
  __shared__ unsigned short ps[40][256];  // 20 KB
  __shared__ float Vs[256][36];           // 36.9 KB (bank-shift pad)
  __shared__ int qrows[40];
  int kc = blockIdx.x, bh = blockIdx.y;
  int h = bh & 7, b = bh >> 3;
  int tid = threadIdx.x;
  int wv = tid >> 6, lane = tid & 63;
  if (tid < 40) qrows[tid] = top[bh * UU + tid];
  __syncthreads();
  for (int t = tid; t < 40 * 32; t += 256) {
    int q = t >> 5, d = t & 31;
    Qs[q][d] = Q[((size_t)(b * LL + qrows[q])) * DMM + h * EE + d];
  }
  {
    int krow = b * LL + kc * 256 + tid;
#pragma unroll
    for (int seg = 0; seg < 8; ++seg)
      *(float4*)(&Vs[tid][seg * 4]) =
          *(const float4*)(V + (size_t)krow * DMM + h * EE + seg * 4);
  }
  __syncthreads();
  // scores: thread = one key
  {
    const float4* kp =
        (const float4*)(K + ((size_t)(b * LL + kc * 256 + tid)) * DMM + h * EE);
    float4 kr[8];
#pragma unroll
    for (int j = 0; j < 8; ++j) kr[j] = kp[j];
    const float scale = 0.17677669529663687f;  // 1/sqrt(32)
    for (int q = 0; q < 40; ++q) {
      const float4* qp = (const float4*)Qs[q];
      float s = 0.f;
#pragma unroll
      for (int j = 0; j < 8; ++j) {
        float4 qv = qp[j];
        s += qv.x * kr[j].x + qv.y * kr[j].y + qv.z * kr[j].z + qv.w * kr[j].w;
      }
      ps[q][tid] = f2b(s * scale);
    }
  }
  __syncthreads();
  // per-wave: 10 queries each — local softmax + PV partial
  int kg = lane >> 5, d = lane & 31;
  for (int qq = 0; qq < 10; ++qq) {
    int q = wv * 10 + qq;
    float mx = -1e30f;
#pragma unroll
    for (int e = 0; e < 4; ++e) mx = fmaxf(mx, bfbits(ps[q][lane + 64 * e]));
#pragma unroll
    for (int off = 32; off > 0; off >>= 1) mx = fmaxf(mx, __shfl_xor(mx, off));
    float sum = 0.f;
#pragma unroll
    for (int e = 0; e < 4; ++e) {
      int i = lane + 64 * e;
      float ev = expf(bfbits(ps[q][i]) - mx);
      sum += ev;
      ps[q][i] = f2b(ev);
    }
    sum = wave_sum(sum);
    float o = 0.f;
#pragma unroll 8
    for (int j = 0; j < 128; ++j) {
      int r = 2 * j + kg;
      o += bfbits(ps[q][r]) * Vs[r][d];
    }
    o += __shfl_xor(o, 32);
    size_t base = ((size_t)bh * UU + q) * 8 + kc;
    if (lane == 0) { pm[base] = mx; pl[base] = sum; }
    if (lane < 32) po[base * 32 + d] = o;
  }
}

// ---------------- merge partials -> ctx rows ----------------
__global__ __launch_bounds__(256) void attn_merge(const float* __restrict__ pm,
                                                  const float* __restrict__ pl,
                                                  const float* __restrict__ po,
                                                  const int* __restrict__ top,
                                                  unsigned short* __restrict__ ctxbf) {
  int bh = blockIdx.x;
  int h = bh & 7, b = bh >> 3;
  int tid = threadIdx.x;
  for (int qq = 0; qq < 5; ++qq) {
    int q = qq * 8 + (tid >> 5), d = tid & 31;
    size_t base = ((size_t)bh * UU + q) * 8;
    float M = -1e30f;
#pragma unroll
    for (int kc = 0; kc < 8; ++kc) M = fmaxf(M, pm[base + kc]);
    float L = 0.f, o = 0.f;
#pragma unroll
    for (int kc = 0; kc < 8; ++kc) {
      float sc = expf(pm[base + kc] - M);
      L += pl[base + kc] * sc;
      o += po[(base + kc) * 32 + d] * sc;
    }
    int qrow = top[bh * UU + q];
    ctxbf[((size_t)(b * LL + qrow)) * DMM + h * EE + d] = f2b(o / L);
  }
}

// ---------------- LayerNorm(x + t) ----------------
__global__ __launch_bounds__(256) void ln_res(const float* __restrict__ X,
                                              const float* __restrict__ T,
                                              const float* __restrict__ g,
                                              const float* __restrict__ bb,
                                              float* __restrict__ Out) {
  int wave = threadIdx.x >> 6, lane = threadIdx.x & 63;
  size_t row = (size_t)blockIdx.x * 4 + wave;
  const float* xr = X + row * DMM;
  const float* tr = T + row * DMM;
  float v[4];
#pragma unroll
  for (int i = 0; i < 4; ++i) v[i] = xr[lane + 64 * i] + tr[lane + 64 * i];
  float s = wave_sum(v[0] + v[1] + v[2] + v[3]);
  float m = s * (1.0f / (float)DMM);
  float sq = 0.f;
#pragma unroll
  for (int i = 0; i < 4; ++i) { float d = v[i] - m; sq += d * d; }
  sq = wave_sum(sq);
  float rstd = rsqrtf(sq * (1.0f / (float)DMM) + 1e-5f);
#pragma unroll
  for (int i = 0; i < 4; ++i) {
    int d = lane + 64 * i;
    Out[row * DMM + d] = (v[i] - m) * rstd * g[d] + bb[d];
  }
}

// ---------------- fused FFN + residual + LN (+bf16 copy) ----------------
__global__ __launch_bounds__(256) void ffn_ln(const float* __restrict__ X,
                                              const float* __restrict__ w1,
                                              const float* __restrict__ b1,
                                              const float* __restrict__ w2,
                                              const float* __restrict__ b2,
                                              const float* __restrict__ g,
                                              const float* __restrict__ bb,
                                              float* __restrict__ Out,
                                              unsigned short* __restrict__ OutB) {
  int wave = threadIdx.x >> 6, lane = threadIdx.x & 63;
  size_t row = (size_t)blockIdx.x * 4 + wave;
  __shared__ float xs[4][DMM];
  const float* xr = X + row * DMM;
  float xv[4];
#pragma unroll
  for (int i = 0; i < 4; ++i) {
    xv[i] = xr[lane + 64 * i];
    xs[wave][lane + 64 * i] = xv[i];
  }
  __syncthreads();
  int f = lane & 15, qtr = lane >> 4;
  const float* w1p = w1 + f * DMM + qtr * 64;
  const float* xq = &xs[wave][qtr * 64];
  float pacc = 0.f;
#pragma unroll 8
  for (int d = 0; d < 64; ++d) pacc += xq[d] * w1p[d];
  pacc += __shfl_xor(pacc, 16);
  pacc += __shfl_xor(pacc, 32);
  float y1 = fmaxf(pacc + b1[f], 0.0f);
  float y1v[16];
#pragma unroll
  for (int ff = 0; ff < 16; ++ff) y1v[ff] = __shfl(y1, ff);
  float v[4];
#pragma unroll
  for (int i = 0; i < 4; ++i) {
    int d = lane + 64 * i;
    const float* w2p = w2 + d * ITR;
    float a = b2[d];
#pragma unroll
    for (int ff = 0; ff < 16; ++ff) a += y1v[ff] * w2p[ff];
    v[i] = xv[i] + a;
  }
  float s = wave_sum(v[0] + v[1] + v[2] + v[3]);
  float m = s * (1.0f / (float)DMM);
  float sq = 0.f;
#pragma unroll
  for (int i = 0; i < 4; ++i) { float d = v[i] - m; sq += d * d; }
  sq = wave_sum(sq);
  float rstd = rsqrtf(sq * (1.0f / (float)DMM) + 1e-5f);
#pragma unroll
  for (int i = 0; i < 4; ++i) {
    int d = lane + 64 * i;
    float val = (v[i] - m) * rstd * g[d] + bb[d];
    Out[row * DMM + d] = val;
    OutB[row * DMM + d] = f2b(val);
  }
}

// ---------------- batchnorm stats ----------------
__global__ __launch_bounds__(256) void stat_part(const float* __restrict__ Y,
                                                 float* __restrict__ ps,
                                                 float* __restrict__ ps2) {
  int c = blockIdx.x;
  int d = threadIdx.x;
  float s = 0.f, s2 = 0.f;
  int base = c * 256;
  for (int r = 0; r < 256; ++r) {
    float v = Y[(size_t)(base + r) * DMM + d];
    s += v;
    s2 += v * v;
  }
  ps[(size_t)c * DMM + d] = s;
  ps2[(size_t)c * DMM + d] = s2;
}
__global__ __launch_bounds__(256) void stat_fin(const float* __restrict__ ps,
                                                const float* __restrict__ ps2,
                                                float* __restrict__ mean,
                                                float* __restrict__ rstd) {
  int d = threadIdx.x;
  float s = 0.f, s2 = 0.f;
  for (int c = 0; c < 32; ++c) {
    s += ps[(size_t)c * DMM + d];
    s2 += ps2[(size_t)c * DMM + d];
  }
  float m = s * (1.0f / (float)ROWS);
  float var = s2 * (1.0f / (float)ROWS) - m * m;
  mean[d] = m;
  rstd[d] = rsqrtf(var + 1e-5f);
}

__global__ __launch_bounds__(256) void bn_elu(const float* __restrict__ Y,
                                              const float* __restrict__ mean,
                                              const float* __restrict__ rstd,
                                              const float* __restrict__ g,
                                              const float* __restrict__ bb,
                                              float* __restrict__ X,
                                              unsigned short* __restrict__ XB) {
  int gid = blockIdx.x * 256 + threadIdx.x;
  int d = gid & 255;
  float v = (Y[gid] - mean[d]) * rstd[d] * g[d] + bb[d];
  float r = v > 0.f ? v : expm1f(v);
  X[gid] = r;
  XB[gid] = f2b(r);
}

// ---------------- final LN -> out ----------------
__global__ __launch_bounds__(256) void ln_final(const float* __restrict__ X,
                                                const float* __restrict__ g,
                                                const float* __restrict__ bb,
                                                void* __restrict__ Out,
                                                const int* __restrict__ flag) {
  int wave = threadIdx.x >> 6, lane = threadIdx.x & 63;
  size_t row = (size_t)blockIdx.x * 4 + wave;
  const float* xr = X + row * DMM;
  float v[4];
#pragma unroll
  for (int i = 0; i < 4; ++i) v[i] = xr[lane + 64 * i];
  float s = wave_sum(v[0] + v[1] + v[2] + v[3]);
  float m = s * (1.0f / (float)DMM);
  float sq = 0.f;
#pragma unroll
  for (int i = 0; i < 4; ++i) { float d = v[i] - m; sq += d * d; }
  sq = wave_sum(sq);
  float rstd = rsqrtf(sq * (1.0f / (float)DMM) + 1e-5f);
  int isf32 = *flag;
#pragma unroll
  for (int i = 0; i < 4; ++i) {
    int d = lane + 64 * i;
    float val = (v[i] - m) * rstd * g[d] + bb[d];
    if (isf32) ((float*)Out)[row * DMM + d] = val;
    else       ((unsigned short*)Out)[row * DMM + d] = f2b(val);
  }
}

extern "C" void kernel_launch(void* const* d_in, const int* in_sizes, int n_in,
                              void* d_out, int out_size, void* d_ws, size_t ws_size,
                              hipStream_t stream) {
  (void)in_sizes; (void)n_in; (void)out_size; (void)ws_size;

  // ---- workspace layout ----
  float* xbuf = (float*)d_ws;
  float* kb   = xbuf + NELEM;
  float* vb   = kb + NELEM;
  float* qb   = vb + NELEM;   // aliases tmp
  float* tmp  = qb;
  float* Mbuf = qb + NELEM;
  float* vmp  = Mbuf + BB * HH * LL;
  float* vmean= vmp + BB * 8 * DMM;
  float* stp  = vmean + BB * DMM;
  float* stp2 = stp + 32 * DMM;
  float* smean= stp2 + 32 * DMM;
  float* srstd= smean + DMM;
  float* wp   = srstd + DMM;
  const int wsz[23] = {
      NELEM,
      NLL * DMM * DMM, NLL * DMM,
      NLL * DMM * DMM, NLL * DMM,
      NLL * DMM * DMM, NLL * DMM,
      NLL * DMM * DMM, NLL * DMM,
      NLL * ITR * DMM, NLL * ITR,
      NLL * DMM * ITR, NLL * DMM,
      NLL * DMM, NLL * DMM,
      NLL * DMM, NLL * DMM,
      (NLL - 1) * DMM * DMM * 3, (NLL - 1) * DMM,
      (NLL - 1) * DMM, (NLL - 1) * DMM,
      DMM, DMM
  };
  float* fptr[23];
  fptr[0] = xbuf;
  for (int i = 1; i < 23; ++i) { fptr[i] = wp; wp += wsz[i]; }
  float* pm = wp;                        // 32*40*8
  float* pl = pm + 32 * UU * 8;
  float* po = pl + 32 * UU * 8;          // 32*40*8*32
  unsigned short* xbf   = (unsigned short*)(po + 32 * UU * 8 * 32);
  unsigned short* ctxbf = xbf + NELEM;
  unsigned short* wvbf  = ctxbf + NELEM;
  unsigned short* wobf  = wvbf + NLL * DMM * DMM;
  unsigned short* dcwT  = wobf + NLL * DMM * DMM;
  u64* cand = (u64*)(dcwT + (NLL - 1) * 3 * DMM * DMM);  // 32*320
  int* idxb = (int*)(cand + 32 * 320);
  int* topb = idxb + LL * UU;
  int* flag = topb + BB * HH * UU;

  // ---- probe + convert ----
  probe_dtype<<<1, 256, 0, stream>>>(d_in[0], flag);
  CvtArgs ca;
  int totalBlk = 0;
  for (int i = 0; i < 23; ++i) {
    ca.src[i] = d_in[i];
    ca.dstF[i] = fptr[i];
    ca.dstB[i] = nullptr;
    ca.n[i] = wsz[i];
    ca.blkStart[i] = totalBlk;
    totalBlk += (wsz[i] + 255) / 256;
  }
  ca.blkStart[23] = totalBlk;
  ca.dstB[0] = xbf;
  ca.dstB[5] = wvbf;
  ca.dstB[7] = wobf;
  mega_cvt<<<totalBlk, 256, 0, stream>>>(ca, flag);
  dcw_repack<<<((NLL - 1) * 3 * 65536 + 255) / 256, 256, 0, stream>>>(fptr[17], dcwT);

  dim3 gqk(ROWS / GBM, DMM / GBN, 2);
  dim3 gm(ROWS / 128, DMM / 64);

  for (int i = 0; i < NLL; ++i) {
    gemm_qk<<<gqk, 256, 0, stream>>>(xbuf, fptr[1] + (size_t)i * DMM * DMM,
                                     fptr[3] + (size_t)i * DMM * DMM,
                                     fptr[2] + i * DMM, fptr[4] + i * DMM, qb, kb);
    gemm_mfma<<<gm, 256, 0, stream>>>(xbf, wvbf + (size_t)i * DMM * DMM,
                                      fptr[6] + i * DMM, vb, 1);

    uint32_t ki0, ki1, a0, a1, b0, b1;
    threefry2x32(0u, 42u, 0u, (uint32_t)i, &ki0, &ki1);
    threefry2x32(ki0, ki1, 0u, 2u, &a0, &a1);
    threefry2x32(ki0, ki1, 1u, 3u, &b0, &b1);
    (void)a0; (void)b0;
    idx_kernel<<<(LL * UU) / 256, 256, 0, stream>>>(a1, b1, idxb);

    m_kernel<<<(BB * HH * LL) / 256, 256, 0, stream>>>(qb, kb, idxb, Mbuf);
    cand_topk<<<BB * HH * 8, 256, 0, stream>>>(Mbuf, cand);
    merge_topk<<<BB * HH, 256, 0, stream>>>(cand, topb);
    vmean_part<<<BB * 8, 256, 0, stream>>>(vb, vmp);
    vmean_fin<<<(BB * DMM) / 256, 256, 0, stream>>>(vmp, vmean);
    ctx_init2<<<NELEM / 256, 256, 0, stream>>>(vmean, ctxbf);
    attn_part<<<dim3(8, BB * HH), 256, 0, stream>>>(qb, kb, vb, topb, pm, pl, po);
    attn_merge<<<BB * HH, 256, 0, stream>>>(pm, pl, po, topb, ctxbf);

    gemm_mfma<<<gm, 256, 0, stream>>>(ctxbf, wobf + (size_t)i * DMM * DMM,
                                      fptr[8] + i * DMM, tmp, 1);
    ln_res<<<ROWS / 4, 256, 0, stream>>>(xbuf, tmp, fptr[13] + i * DMM,
                                         fptr[14] + i * DMM, xbuf);
    ffn_ln<<<ROWS / 4, 256, 0, stream>>>(xbuf, fptr[9] + (size_t)i * ITR * DMM,
                                         fptr[10] + i * ITR,
                                         fptr[11] + (size_t)i * DMM * ITR,
                                         fptr[12] + i * DMM, fptr[15] + i * DMM,
                                         fptr[16] + i * DMM, xbuf, xbf);

    if (i < NLL - 1) {
      gemm_mfma<<<gm, 256, 0, stream>>>(xbf, dcwT + (size_t)i * 3 * DMM * DMM,
                                        fptr[18] + i * DMM, tmp, 3);
      stat_part<<<32, 256, 0, stream>>>(tmp, stp, stp2);
      stat_fin<<<1, 256, 0, stream>>>(stp, stp2, smean, srstd);
      bn_elu<<<NELEM / 256, 256, 0, stream>>>(tmp, smean, srstd, fptr[19] + i * DMM,
                                              fptr[20] + i * DMM, xbuf, xbf);
    }
  }

  ln_final<<<ROWS / 4, 256, 0, stream>>>(xbuf, fptr[21], fptr[22], d_out, flag);
}

// Round 5
// 810.759 us; speedup vs baseline: 1.7852x; 1.0895x over previous
//
#include <hip/hip_runtime.h>
#include <stdint.h>

#define BB 4
#define LL 2048
#define DMM 256
#define HH 8
#define EE 32
#define NLL 3
#define ITR 16
#define UU 40
#define ROWS (BB*LL)          // 8192
#define NELEM (ROWS*DMM)      // 2097152

typedef __attribute__((ext_vector_type(8))) short short8;
typedef __attribute__((ext_vector_type(4))) float f32x4;
typedef unsigned long long u64;

// ---------------- bf16 bit helpers (RNE) ----------------
__device__ __forceinline__ float bfbits(unsigned short u) {
  return __uint_as_float(((uint32_t)u) << 16);
}
__device__ __forceinline__ unsigned short f2b(float f) {
  uint32_t u = __float_as_uint(f);
  uint32_t r = (u + 0x7FFFu + ((u >> 16) & 1u)) >> 16;
  return (unsigned short)r;
}

// ---------------- threefry2x32 (exact JAX semantics) ----------------
__host__ __device__ inline void threefry2x32(uint32_t k0, uint32_t k1,
                                             uint32_t x0, uint32_t x1,
                                             uint32_t* o0, uint32_t* o1) {
  uint32_t ks2 = k0 ^ k1 ^ 0x1BD11BDAu;
  x0 += k0; x1 += k1;
#define TFR(r) { x0 += x1; x1 = (x1 << (r)) | (x1 >> (32 - (r))); x1 ^= x0; }
  TFR(13) TFR(15) TFR(26) TFR(6)
  x0 += k1;  x1 += ks2 + 1u;
  TFR(17) TFR(29) TFR(16) TFR(24)
  x0 += ks2; x1 += k0 + 2u;
  TFR(13) TFR(15) TFR(26) TFR(6)
  x0 += k0;  x1 += k1 + 3u;
  TFR(17) TFR(29) TFR(16) TFR(24)
  x0 += k1;  x1 += ks2 + 4u;
  TFR(13) TFR(15) TFR(26) TFR(6)
  x0 += ks2; x1 += k0 + 5u;
#undef TFR
  *o0 = x0; *o1 = x1;
}

__device__ __forceinline__ float wave_sum(float v) {
#pragma unroll
  for (int off = 32; off > 0; off >>= 1) v += __shfl_xor(v, off);
  return v;
}

// ---------------- dtype probe ----------------
__global__ __launch_bounds__(256) void probe_dtype(const void* __restrict__ x,
                                                   int* __restrict__ flag) {
  __shared__ int cnt;
  if (threadIdx.x == 0) cnt = 0;
  __syncthreads();
  const unsigned short* u = (const unsigned short*)x;
  int bad = 0;
  for (int j = threadIdx.x; j < 2048; j += 256) {
    float v = bfbits(u[j]);
    float a = fabsf(v);
    bool ok = (v == 0.0f) || (a > 1e-4f && a < 100.0f);
    if (!ok) bad++;
  }
  atomicAdd(&cnt, bad);
  __syncthreads();
  if (threadIdx.x == 0) *flag = (cnt > 100) ? 1 : 0;
}

// ---------------- mega convert ----------------
struct CvtArgs {
  const void* src[23];
  float* dstF[23];
  unsigned short* dstB[23];
  int n[23];
  int blkStart[24];
};
__global__ __launch_bounds__(256) void mega_cvt(CvtArgs a, const int* __restrict__ flag) {
  int bid = blockIdx.x;
  int i = 0;
  while (i < 22 && bid >= a.blkStart[i + 1]) ++i;
  int e = (bid - a.blkStart[i]) * 256 + (int)threadIdx.x;
  if (e >= a.n[i]) return;
  float v; unsigned short rw;
  if (*flag) { v = ((const float*)a.src[i])[e]; rw = f2b(v); }
  else       { rw = ((const unsigned short*)a.src[i])[e]; v = bfbits(rw); }
  a.dstF[i][e] = v;
  if (a.dstB[i]) a.dstB[i][e] = rw;
}

// ---------------- conv weight repack ----------------
__global__ __launch_bounds__(256) void dcw_repack(const float* __restrict__ dcwF,
                                                  unsigned short* __restrict__ dcwT) {
  int gid = blockIdx.x * 256 + threadIdx.x;
  if (gid >= (NLL - 1) * 3 * 65536) return;
  int ly = gid / 196608;
  int r = gid - ly * 196608;
  int t = r >> 16;
  int r2 = r & 65535;
  int n = r2 >> 8, k = r2 & 255;
  dcwT[gid] = f2b(dcwF[ly * 196608 + n * 768 + k * 3 + t]);
}

// ---------------- f32 GEMM for Q,K -> head-major layout [bh][l][e] ----------------
#define QBM 128
#define QBN 64
#define QBK 16
__global__ __launch_bounds__(256) void gemm_qk(const float* __restrict__ A,
                                               const float* __restrict__ Wq,
                                               const float* __restrict__ Wk,
                                               const float* __restrict__ bq,
                                               const float* __restrict__ bk,
                                               float* __restrict__ Qh,
                                               float* __restrict__ Kh) {
  const float* W = blockIdx.z ? Wk : Wq;
  const float* bias = blockIdx.z ? bk : bq;
  float* Ch = blockIdx.z ? Kh : Qh;
  __shared__ float As[QBK][QBM + 4];
  __shared__ float Bs[QBK][QBN + 4];
  int bm = blockIdx.x * QBM;
  int bn = blockIdx.y * QBN;
  int tid = threadIdx.x;
  int kk = tid & 15, rr = tid >> 4;
  int tx = tid & 15, ty = tid >> 4;
  float acc[8][4] = {};
  for (int k0 = 0; k0 < DMM; k0 += QBK) {
#pragma unroll
    for (int p = 0; p < 8; ++p)
      As[kk][rr + 16 * p] = A[(size_t)(bm + rr + 16 * p) * DMM + k0 + kk];
#pragma unroll
    for (int p = 0; p < 4; ++p)
      Bs[kk][rr + 16 * p] = W[(size_t)(bn + rr + 16 * p) * DMM + k0 + kk];
    __syncthreads();
#pragma unroll
    for (int kq = 0; kq < QBK; ++kq) {
      float4 a0 = *(const float4*)(&As[kq][ty * 8]);
      float4 a1 = *(const float4*)(&As[kq][ty * 8 + 4]);
      float4 b0 = *(const float4*)(&Bs[kq][tx * 4]);
      float av[8] = {a0.x, a0.y, a0.z, a0.w, a1.x, a1.y, a1.z, a1.w};
      float bv[4] = {b0.x, b0.y, b0.z, b0.w};
#pragma unroll
      for (int i = 0; i < 8; ++i)
#pragma unroll
        for (int j = 0; j < 4; ++j) acc[i][j] = fmaf(av[i], bv[j], acc[i][j]);
    }
    __syncthreads();
  }
  int n = bn + tx * 4;
  int h = n >> 5, e = n & 31;
  float4 bv4 = *(const float4*)(bias + n);
#pragma unroll
  for (int i = 0; i < 8; ++i) {
    int row = bm + ty * 8 + i;
    int b = row >> 11, l = row & 2047;
    float4 o;
    o.x = acc[i][0] + bv4.x; o.y = acc[i][1] + bv4.y;
    o.z = acc[i][2] + bv4.z; o.w = acc[i][3] + bv4.w;
    *(float4*)(Ch + (((size_t)(b * HH + h)) * LL + l) * EE + e) = o;
  }
}

// ---------------- bf16 MFMA GEMM (+3-tap conv mode) ----------------
__global__ __launch_bounds__(256) void gemm_mfma(const unsigned short* __restrict__ A,
                                                 const unsigned short* __restrict__ W,
                                                 const float* __restrict__ bias,
                                                 float* __restrict__ C, int ntaps) {
  __shared__ unsigned short As[128][40];
  __shared__ unsigned short Bs[64][40];
  int bm = blockIdx.x * 128, bn = blockIdx.y * 64;
  int tid = threadIdx.x;
  int wave = tid >> 6, lane = tid & 63;
  int wm = wave >> 1, wn = wave & 1;
  int l15 = lane & 15, quad = lane >> 4;
  f32x4 acc[4][2];
#pragma unroll
  for (int i = 0; i < 4; ++i)
#pragma unroll
    for (int j = 0; j < 2; ++j) acc[i][j] = (f32x4){0.f, 0.f, 0.f, 0.f};
  for (int tap = 0; tap < ntaps; ++tap) {
    int lshift = (ntaps == 3) ? (tap - 1) : 0;
    const unsigned short* Wt = W + (size_t)tap * 65536;
    for (int k0 = 0; k0 < 256; k0 += 32) {
      __syncthreads();
      for (int c = tid; c < 512; c += 256) {
        int row = c >> 2, seg = c & 3;
        int grow = bm + row;
        if (lshift != 0) {
          int bidx = grow >> 11, l = grow & 2047;
          grow = (bidx << 11) | ((l + lshift + 2048) & 2047);
        }
        *(uint4*)(&As[row][seg * 8]) =
            *(const uint4*)(A + (size_t)grow * 256 + k0 + seg * 8);
      }
      {
        int row = tid >> 2, seg = tid & 3;
        *(uint4*)(&Bs[row][seg * 8]) =
            *(const uint4*)(Wt + (size_t)(bn + row) * 256 + k0 + seg * 8);
      }
      __syncthreads();
      short8 af[4], bfr[2];
#pragma unroll
      for (int mt = 0; mt < 4; ++mt)
        af[mt] = *(const short8*)(&As[wm * 64 + mt * 16 + l15][quad * 8]);
#pragma unroll
      for (int nt = 0; nt < 2; ++nt)
        bfr[nt] = *(const short8*)(&Bs[wn * 32 + nt * 16 + l15][quad * 8]);
#pragma unroll
      for (int mt = 0; mt < 4; ++mt)
#pragma unroll
        for (int nt = 0; nt < 2; ++nt)
          acc[mt][nt] = __builtin_amdgcn_mfma_f32_16x16x32_bf16(af[mt], bfr[nt],
                                                                acc[mt][nt], 0, 0, 0);
    }
  }
#pragma unroll
  for (int nt = 0; nt < 2; ++nt) {
    int n = bn + wn * 32 + nt * 16 + l15;
    float bv = bias[n];
#pragma unroll
    for (int mt = 0; mt < 4; ++mt)
#pragma unroll
      for (int r = 0; r < 4; ++r) {
        int m = bm + wm * 64 + mt * 16 + quad * 4 + r;
        C[(size_t)m * 256 + n] = acc[mt][nt][r] + bv;
      }
  }
}

// ---------------- M scores: 4 threads per l, inline threefry, head-major Q/K ----------------
// grid: 32 bh * 32 lchunks = 1024 blocks
__global__ __launch_bounds__(256) void m_kernel2(const float* __restrict__ Qh,
                                                 const float* __restrict__ Kh,
                                                 uint32_t k20, uint32_t k21,
                                                 float* __restrict__ M) {
  __shared__ float Qs[64][36];
  int bh = blockIdx.x >> 5, lc = blockIdx.x & 31;
  int l0 = lc * 64;
  int tid = threadIdx.x;
  const float* Qb = Qh + ((size_t)bh * LL + l0) * EE;
  for (int t = tid; t < 64 * 32; t += 256) {
    int li = t >> 5, e = t & 31;
    Qs[li][e] = Qb[li * EE + e];
  }
  __syncthreads();
  int li = tid >> 2, ug = tid & 3;
  int l = l0 + li;
  float4 qr[8];
#pragma unroll
  for (int j = 0; j < 8; ++j) qr[j] = *(const float4*)(&Qs[li][j * 4]);
  const float* Kb = Kh + (size_t)bh * LL * EE;
  float mx = -1e30f, sm = 0.f;
#pragma unroll
  for (int i = 0; i < 10; ++i) {
    int jj = l * UU + ug * 10 + i;
    uint32_t o0, o1, kidx;
    const int half = (LL * UU) / 2;  // 40960
    if (jj < half) {
      threefry2x32(k20, k21, (uint32_t)jj, (uint32_t)(jj + half), &o0, &o1);
      kidx = o0 & (LL - 1);
    } else {
      threefry2x32(k20, k21, (uint32_t)(jj - half), (uint32_t)jj, &o0, &o1);
      kidx = o1 & (LL - 1);
    }
    const float4* kp = (const float4*)(Kb + (size_t)kidx * EE);
    float s = 0.f;
#pragma unroll
    for (int j = 0; j < 8; ++j) {
      float4 kv = kp[j];
      s += qr[j].x * kv.x + qr[j].y * kv.y + qr[j].z * kv.z + qr[j].w * kv.w;
    }
    mx = fmaxf(mx, s);
    sm += s;
  }
  mx = fmaxf(mx, __shfl_xor(mx, 1));
  mx = fmaxf(mx, __shfl_xor(mx, 2));
  sm += __shfl_xor(sm, 1);
  sm += __shfl_xor(sm, 2);
  if (ug == 0) M[(size_t)bh * LL + l] = mx - sm * (1.0f / (float)LL);
}

// ---------------- top-k stage A ----------------
__global__ __launch_bounds__(256) void cand_topk(const float* __restrict__ M,
                                                 u64* __restrict__ cand) {
  __shared__ u64 a[256];
  int bh = blockIdx.x >> 3, c = blockIdx.x & 7;
  int tid = threadIdx.x;
  int l = c * 256 + tid;
  float v = M[(size_t)bh * LL + l];
  uint32_t bits = __float_as_uint(v);
  uint32_t kv = (bits & 0x80000000u) ? ~bits : (bits | 0x80000000u);
  a[tid] = ((u64)kv << 32) | (uint32_t)(2047 - l);
  __syncthreads();
  for (int k = 2; k <= 256; k <<= 1)
    for (int j = k >> 1; j > 0; j >>= 1) {
      int ixj = tid ^ j;
      if (ixj > tid) {
        bool up = ((tid & k) == 0);
        u64 x = a[tid], y = a[ixj];
        if ((x > y) == up) { a[tid] = y; a[ixj] = x; }
      }
      __syncthreads();
    }
  if (tid >= 216) cand[(size_t)blockIdx.x * 40 + (tid - 216)] = a[tid];
}

// ---------------- top-k stage B ----------------
__global__ __launch_bounds__(256) void merge_topk(const u64* __restrict__ cand,
                                                  int* __restrict__ top) {
  __shared__ u64 a[512];
  int bh = blockIdx.x;
  int tid = threadIdx.x;
  for (int t = tid; t < 512; t += 256)
    a[t] = (t < 320) ? cand[(size_t)bh * 320 + t] : 0ULL;
  __syncthreads();
  for (int k = 2; k <= 512; k <<= 1)
    for (int j = k >> 1; j > 0; j >>= 1) {
      for (int t = tid; t < 512; t += 256) {
        int ixj = t ^ j;
        if (ixj > t) {
          bool up = ((t & k) == 0);
          u64 x = a[t], y = a[ixj];
          if ((x > y) == up) { a[t] = y; a[ixj] = x; }
        }
      }
      __syncthreads();
    }
  if (tid < UU) {
    u64 key = a[511 - tid];
    top[bh * UU + tid] = 2047 - (int)(uint32_t)(key & 0xFFFFFFFFu);
  }
}

// ---------------- v mean over L ----------------
__global__ __launch_bounds__(256) void vmean_part(const float* __restrict__ V,
                                                  float* __restrict__ pv) {
  int blk = blockIdx.x;
  int b = blk >> 3, c = blk & 7;
  int d = threadIdx.x;
  float s = 0.f;
  int base = b * LL + c * 256;
  for (int r = 0; r < 256; ++r) s += V[(size_t)(base + r) * DMM + d];
  pv[(size_t)blk * DMM + d] = s;
}
__global__ __launch_bounds__(256) void vmean_fin(const float* __restrict__ pv,
                                                 float* __restrict__ vm) {
  int gid = blockIdx.x * 256 + threadIdx.x;
  int b = gid >> 8, d = gid & 255;
  float s = 0.f;
#pragma unroll
  for (int c = 0; c < 8; ++c) s += pv[(size_t)(b * 8 + c) * DMM + d];
  vm[gid] = s * (1.0f / (float)LL);
}

__global__ __launch_bounds__(256) void ctx_init2(const float* __restrict__ vm,
                                                 unsigned short* __restrict__ ctxbf) {
  int gid = blockIdx.x * 256 + threadIdx.x;
  int d = gid & 255;
  int b = gid >> 19;
  ctxbf[gid] = f2b(vm[b * DMM + d]);
}

// ---------------- split-K flash attention: partials (head-major Q/K) ----------------
__global__ __launch_bounds__(256) void attn_part(const float* __restrict__ Qh,
                                                 const float* __restrict__ Kh,
                                                 const float* __restrict__ V,
                                                 const int* __restrict__ top,
                                                 float* __restrict__ pm,
                                                 float* __restrict__ pl,
                                                 float* __restrict__ po) {
  __shared__ float Qs[40][32];
  __shared__ unsigned short ps[40][256];
  __shared__ float Vs[256][36];
  __shared__ int qrows[40];
  int kc = blockIdx.x, bh = blockIdx.y;
  int h = bh & 7, b = bh >> 3;
  int tid = threadIdx.x;
  int wv = tid >> 6, lane = tid & 63;
  if (tid < 40) qrows[tid] = top[bh * UU + tid];
  __syncthreads();
  for (int t = tid; t < 40 * 32; t += 256) {
    int q = t >> 5, d = t & 31;
    Qs[q][d] = Qh[((size_t)bh * LL + qrows[q]) * EE + d];
  }
  {
    int krow = b * LL + kc * 256 + tid;
#pragma unroll
    for (int seg = 0; seg < 8; ++seg)
      *(float4*)(&Vs[tid][seg * 4]) =
          *(const float4*)(V + (size_t)krow * DMM + h * EE + seg * 4);
  }
  __syncthreads();
  {
    const float4* kp = (const float4*)(Kh + ((size_t)bh * LL + kc * 256 + tid) * EE);
    float4 kr[8];
#pragma unroll
    for (int j = 0; j < 8; ++j) kr[j] = kp[j];
    const float scale = 0.17677669529663687f;
    for (int q = 0; q < 40; ++q) {
      const float4* qp = (const float4*)Qs[q];
      float s = 0.f;
#pragma unroll
      for (int j = 0; j < 8; ++j) {
        float4 qv = qp[j];
        s += qv.x * kr[j].x + qv.y * kr[j].y + qv.z * kr[j].z + qv.w * kr[j].w;
      }
      ps[q][tid] = f2b(s * scale);
    }
  }
  __syncthreads();
  int kg = lane >> 5, d = lane & 31;
  for (int qq = 0; qq < 10; ++qq) {
    int q = wv * 10 + qq;
    float mx = -1e30f;
#pragma unroll
    for (int e = 0; e < 4; ++e) mx = fmaxf(mx, bfbits(ps[q][lane + 64 * e]));
#pragma unroll
    for (int off = 32; off > 0; off >>= 1) mx = fmaxf(mx, __shfl_xor(mx, off));
    float sum = 0.f;
#pragma unroll
    for (int e = 0; e < 4; ++e) {
      int i = lane + 64 * e;
      float ev = expf(bfbits(ps[q][i]) - mx);
      sum += ev;
      ps[q][i] = f2b(ev);
    }
    sum = wave_sum(sum);
    float o = 0.f;
#pragma unroll 8
    for (int j = 0; j < 128; ++j) {
      int r = 2 * j + kg;
      o += bfbits(ps[q][r]) * Vs[r][d];
    }
    o += __shfl_xor(o, 32);
    size_t base = ((size_t)bh * UU + q) * 8 + kc;
    if (lane == 0) { pm[base] = mx; pl[base] = sum; }
    if (lane < 32) po[base * 32 + d] = o;
  }
}

// ---------------- merge partials -> ctx rows ----------------
__global__ __launch_bounds__(256) void attn_merge(const float* __restrict__ pm,
                                                  const float* __restrict__ pl,
                                                  const float* __restrict__ po,
                                                  const int* __restrict__ top,
                                                  unsigned short* __restrict__ ctxbf) {
  int bh = blockIdx.x;
  int h = bh & 7, b = bh >> 3;
  int tid = threadIdx.x;
  for (int qq = 0; qq < 5; ++qq) {
    int q = qq * 8 + (tid >> 5), d = tid & 31;
    size_t base = ((size_t)bh * UU + q) * 8;
    float M = -1e30f;
#pragma unroll
    for (int kc = 0; kc < 8; ++kc) M = fmaxf(M, pm[base + kc]);
    float L = 0.f, o = 0.f;
#pragma unroll
    for (int kc = 0; kc < 8; ++kc) {
      float sc = expf(pm[base + kc] - M);
      L += pl[base + kc] * sc;
      o += po[(base + kc) * 32 + d] * sc;
    }
    int qrow = top[bh * UU + q];
    ctxbf[((size_t)(b * LL + qrow)) * DMM + h * EE + d] = f2b(o / L);
  }
}

// ---------------- fused LN1(x+t) + FFN + LN2 (+ optional final LN -> d_out) ----------------
__global__ __launch_bounds__(256) void enc_tail(const float* __restrict__ X,
                                                const float* __restrict__ T,
                                                const float* __restrict__ g1,
                                                const float* __restrict__ b1ln,
                                                const float* __restrict__ w1,
                                                const float* __restrict__ b1,
                                                const float* __restrict__ w2,
                                                const float* __restrict__ b2,
                                                const float* __restrict__ g2,
                                                const float* __restrict__ b2ln,
                                                float* __restrict__ Out,
                                                unsigned short* __restrict__ OutB,
                                                const float* __restrict__ fing,
                                                const float* __restrict__ finb,
                                                void* __restrict__ finOut,
                                                const int* __restrict__ flag) {
  int wave = threadIdx.x >> 6, lane = threadIdx.x & 63;
  size_t row = (size_t)blockIdx.x * 4 + wave;
  __shared__ float xs[4][DMM];
  const float* xr = X + row * DMM;
  const float* tr = T + row * DMM;
  // LN1(x + t)
  float v[4];
#pragma unroll
  for (int i = 0; i < 4; ++i) v[i] = xr[lane + 64 * i] + tr[lane + 64 * i];
  float s = wave_sum(v[0] + v[1] + v[2] + v[3]);
  float m = s * (1.0f / (float)DMM);
  float sq = 0.f;
#pragma unroll
  for (int i = 0; i < 4; ++i) { float d = v[i] - m; sq += d * d; }
  sq = wave_sum(sq);
  float rstd = rsqrtf(sq * (1.0f / (float)DMM) + 1e-5f);
  float xv[4];
#pragma unroll
  for (int i = 0; i < 4; ++i) {
    int d = lane + 64 * i;
    xv[i] = (v[i] - m) * rstd * g1[d] + b1ln[d];
    xs[wave][d] = xv[i];
  }
  __syncthreads();
  // FFN (INTER=16)
  int f = lane & 15, qtr = lane >> 4;
  const float* w1p = w1 + f * DMM + qtr * 64;
  const float* xq = &xs[wave][qtr * 64];
  float pacc = 0.f;
#pragma unroll 8
  for (int d = 0; d < 64; ++d) pacc += xq[d] * w1p[d];
  pacc += __shfl_xor(pacc, 16);
  pacc += __shfl_xor(pacc, 32);
  float y1 = fmaxf(pacc + b1[f], 0.0f);
  float y1v[16];
#pragma unroll
  for (int ff = 0; ff < 16; ++ff) y1v[ff] = __shfl(y1, ff);
#pragma unroll
  for (int i = 0; i < 4; ++i) {
    int d = lane + 64 * i;
    const float* w2p = w2 + d * ITR;
    float a = b2[d];
#pragma unroll
    for (int ff = 0; ff < 16; ++ff) a += y1v[ff] * w2p[ff];
    v[i] = xv[i] + a;
  }
  // LN2
  s = wave_sum(v[0] + v[1] + v[2] + v[3]);
  m = s * (1.0f / (float)DMM);
  sq = 0.f;
#pragma unroll
  for (int i = 0; i < 4; ++i) { float d = v[i] - m; sq += d * d; }
  sq = wave_sum(sq);
  rstd = rsqrtf(sq * (1.0f / (float)DMM) + 1e-5f);
  float vv[4];
#pragma unroll
  for (int i = 0; i < 4; ++i) {
    int d = lane + 64 * i;
    float val = (v[i] - m) * rstd * g2[d] + b2ln[d];
    vv[i] = val;
    Out[row * DMM + d] = val;
    if (OutB) OutB[row * DMM + d] = f2b(val);
  }
  if (finOut) {
    s = wave_sum(vv[0] + vv[1] + vv[2] + vv[3]);
    m = s * (1.0f / (float)DMM);
    sq = 0.f;
#pragma unroll
    for (int i = 0; i < 4; ++i) { float d = vv[i] - m; sq += d * d; }
    sq = wave_sum(sq);
    rstd = rsqrtf(sq * (1.0f / (float)DMM) + 1e-5f);
    int isf32 = *flag;
#pragma unroll
    for (int i = 0; i < 4; ++i) {
      int d = lane + 64 * i;
      float val = (vv[i] - m) * rstd * fing[d] + finb[d];
      if (isf32) ((float*)finOut)[row * DMM + d] = val;
      else       ((unsigned short*)finOut)[row * DMM + d] = f2b(val);
    }
  }
}

// ---------------- batchnorm stats ----------------
__global__ __launch_bounds__(256) void stat_part(const float* __restrict__ Y,
                                                 float* __restrict__ ps,
                                                 float* __restrict__ ps2) {
  int c = blockIdx.x;
  int d = threadIdx.x;
  float s = 0.f, s2 = 0.f;
  int base = c * 256;
  for (int r = 0; r < 256; ++r) {
    float v = Y[(size_t)(base + r) * DMM + d];
    s += v;
    s2 += v * v;
  }
  ps[(size_t)c * DMM + d] = s;
  ps2[(size_t)c * DMM + d] = s2;
}
__global__ __launch_bounds__(256) void stat_fin(const float* __restrict__ ps,
                                                const float* __restrict__ ps2,
                                                float* __restrict__ mean,
                                                float* __restrict__ rstd) {
  int d = threadIdx.x;
  float s = 0.f, s2 = 0.f;
  for (int c = 0; c < 32; ++c) {
    s += ps[(size_t)c * DMM + d];
    s2 += ps2[(size_t)c * DMM + d];
  }
  float m = s * (1.0f / (float)ROWS);
  float var = s2 * (1.0f / (float)ROWS) - m * m;
  mean[d] = m;
  rstd[d] = rsqrtf(var + 1e-5f);
}

__global__ __launch_bounds__(256) void bn_elu(const float* __restrict__ Y,
                                              const float* __restrict__ mean,
                                              const float* __restrict__ rstd,
                                              const float* __restrict__ g,
                                              const float* __restrict__ bb,
                                              float* __restrict__ X,
                                              unsigned short* __restrict__ XB) {
  int gid = blockIdx.x * 256 + threadIdx.x;
  int d = gid & 255;
  float v = (Y[gid] - mean[d]) * rstd[d] * g[d] + bb[d];
  float r = v > 0.f ? v : expm1f(v);
  X[gid] = r;
  XB[gid] = f2b(r);
}

extern "C" void kernel_launch(void* const* d_in, const int* in_sizes, int n_in,
                              void* d_out, int out_size, void* d_ws, size_t ws_size,
                              hipStream_t stream) {
  (void)in_sizes; (void)n_in; (void)out_size; (void)ws_size;

  // ---- workspace layout ----
  float* xbuf = (float*)d_ws;
  float* Kh   = xbuf + NELEM;
  float* vb   = Kh + NELEM;
  float* Qh   = vb + NELEM;   // aliases tmp (Q dead after attn_part)
  float* tmp  = Qh;
  float* Mbuf = Qh + NELEM;
  float* vmp  = Mbuf + BB * HH * LL;
  float* vmean= vmp + BB * 8 * DMM;
  float* stp  = vmean + BB * DMM;
  float* stp2 = stp + 32 * DMM;
  float* smean= stp2 + 32 * DMM;
  float* srstd= smean + DMM;
  float* wp   = srstd + DMM;
  const int wsz[23] = {
      NELEM,
      NLL * DMM * DMM, NLL * DMM,
      NLL * DMM * DMM, NLL * DMM,
      NLL * DMM * DMM, NLL * DMM,
      NLL * DMM * DMM, NLL * DMM,
      NLL * ITR * DMM, NLL * ITR,
      NLL * DMM * ITR, NLL * DMM,
      NLL * DMM, NLL * DMM,
      NLL * DMM, NLL * DMM,
      (NLL - 1) * DMM * DMM * 3, (NLL - 1) * DMM,
      (NLL - 1) * DMM, (NLL - 1) * DMM,
      DMM, DMM
  };
  float* fptr[23];
  fptr[0] = xbuf;
  for (int i = 1; i < 23; ++i) { fptr[i] = wp; wp += wsz[i]; }
  float* pm = wp;
  float* pl = pm + 32 * UU * 8;
  float* po = pl + 32 * UU * 8;
  unsigned short* xbf   = (unsigned short*)(po + 32 * UU * 8 * 32);
  unsigned short* ctxbf = xbf + NELEM;
  unsigned short* wvbf  = ctxbf + NELEM;
  unsigned short* wobf  = wvbf + NLL * DMM * DMM;
  unsigned short* dcwT  = wobf + NLL * DMM * DMM;
  u64* cand = (u64*)(dcwT + (NLL - 1) * 3 * DMM * DMM);
  int* topb = (int*)(cand + 32 * 320);
  int* flag = topb + BB * HH * UU;

  // ---- probe + convert ----
  probe_dtype<<<1, 256, 0, stream>>>(d_in[0], flag);
  CvtArgs ca;
  int totalBlk = 0;
  for (int i = 0; i < 23; ++i) {
    ca.src[i] = d_in[i];
    ca.dstF[i] = fptr[i];
    ca.dstB[i] = nullptr;
    ca.n[i] = wsz[i];
    ca.blkStart[i] = totalBlk;
    totalBlk += (wsz[i] + 255) / 256;
  }
  ca.blkStart[23] = totalBlk;
  ca.dstB[0] = xbf;
  ca.dstB[5] = wvbf;
  ca.dstB[7] = wobf;
  mega_cvt<<<totalBlk, 256, 0, stream>>>(ca, flag);
  dcw_repack<<<((NLL - 1) * 3 * 65536 + 255) / 256, 256, 0, stream>>>(fptr[17], dcwT);

  dim3 gqk(ROWS / QBM, DMM / QBN, 2);
  dim3 gm(ROWS / 128, DMM / 64);

  for (int i = 0; i < NLL; ++i) {
    gemm_qk<<<gqk, 256, 0, stream>>>(xbuf, fptr[1] + (size_t)i * DMM * DMM,
                                     fptr[3] + (size_t)i * DMM * DMM,
                                     fptr[2] + i * DMM, fptr[4] + i * DMM, Qh, Kh);
    gemm_mfma<<<gm, 256, 0, stream>>>(xbf, wvbf + (size_t)i * DMM * DMM,
                                      fptr[6] + i * DMM, vb, 1);

    uint32_t ki0, ki1, a0, a1, b0, b1;
    threefry2x32(0u, 42u, 0u, (uint32_t)i, &ki0, &ki1);
    threefry2x32(ki0, ki1, 0u, 2u, &a0, &a1);
    threefry2x32(ki0, ki1, 1u, 3u, &b0, &b1);
    (void)a0; (void)b0;

    m_kernel2<<<32 * 32, 256, 0, stream>>>(Qh, Kh, a1, b1, Mbuf);
    cand_topk<<<BB * HH * 8, 256, 0, stream>>>(Mbuf, cand);
    merge_topk<<<BB * HH, 256, 0, stream>>>(cand, topb);
    vmean_part<<<BB * 8, 256, 0, stream>>>(vb, vmp);
    vmean_fin<<<(BB * DMM) / 256, 256, 0, stream>>>(vmp, vmean);
    ctx_init2<<<NELEM / 256, 256, 0, stream>>>(vmean, ctxbf);
    attn_part<<<dim3(8, BB * HH), 256, 0, stream>>>(Qh, Kh, vb, topb, pm, pl, po);
    attn_merge<<<BB * HH, 256, 0, stream>>>(pm, pl, po, topb, ctxbf);

    gemm_mfma<<<gm, 256, 0, stream>>>(ctxbf, wobf + (size_t)i * DMM * DMM,
                                      fptr[8] + i * DMM, tmp, 1);
    bool last = (i == NLL - 1);
    enc_tail<<<ROWS / 4, 256, 0, stream>>>(
        xbuf, tmp, fptr[13] + i * DMM, fptr[14] + i * DMM,
        fptr[9] + (size_t)i * ITR * DMM, fptr[10] + i * ITR,
        fptr[11] + (size_t)i * DMM * ITR, fptr[12] + i * DMM,
        fptr[15] + i * DMM, fptr[16] + i * DMM, xbuf, xbf,
        fptr[21], fptr[22], last ? d_out : nullptr, flag);

    if (!last) {
      gemm_mfma<<<gm, 256, 0, stream>>>(xbf, dcwT + (size_t)i * 3 * DMM * DMM,
                                        fptr[18] + i * DMM, tmp, 3);
      stat_part<<<32, 256, 0, stream>>>(tmp, stp, stp2);
      stat_fin<<<1, 256, 0, stream>>>(stp, stp2, smean, srstd);
      bn_elu<<<NELEM / 256, 256, 0, stream>>>(tmp, smean, srstd, fptr[19] + i * DMM,
                                              fptr[20] + i * DMM, xbuf, xbf);
    }
  }
}

// Round 6
// 774.045 us; speedup vs baseline: 1.8699x; 1.0474x over previous
//
#include <hip/hip_runtime.h>
#include <stdint.h>

#define BB 4
#define LL 2048
#define DMM 256
#define HH 8
#define EE 32
#define NLL 3
#define ITR 16
#define UU 40
#define ROWS (BB*LL)          // 8192
#define NELEM (ROWS*DMM)      // 2097152

typedef __attribute__((ext_vector_type(8))) short short8;
typedef __attribute__((ext_vector_type(4))) float f32x4;
typedef unsigned long long u64;

// ---------------- bf16 bit helpers (RNE) ----------------
__device__ __forceinline__ float bfbits(unsigned short u) {
  return __uint_as_float(((uint32_t)u) << 16);
}
__device__ __forceinline__ unsigned short f2b(float f) {
  uint32_t u = __float_as_uint(f);
  uint32_t r = (u + 0x7FFFu + ((u >> 16) & 1u)) >> 16;
  return (unsigned short)r;
}

// ---------------- threefry2x32 (exact JAX semantics) ----------------
__host__ __device__ inline void threefry2x32(uint32_t k0, uint32_t k1,
                                             uint32_t x0, uint32_t x1,
                                             uint32_t* o0, uint32_t* o1) {
  uint32_t ks2 = k0 ^ k1 ^ 0x1BD11BDAu;
  x0 += k0; x1 += k1;
#define TFR(r) { x0 += x1; x1 = (x1 << (r)) | (x1 >> (32 - (r))); x1 ^= x0; }
  TFR(13) TFR(15) TFR(26) TFR(6)
  x0 += k1;  x1 += ks2 + 1u;
  TFR(17) TFR(29) TFR(16) TFR(24)
  x0 += ks2; x1 += k0 + 2u;
  TFR(13) TFR(15) TFR(26) TFR(6)
  x0 += k0;  x1 += k1 + 3u;
  TFR(17) TFR(29) TFR(16) TFR(24)
  x0 += k1;  x1 += ks2 + 4u;
  TFR(13) TFR(15) TFR(26) TFR(6)
  x0 += ks2; x1 += k0 + 5u;
#undef TFR
  *o0 = x0; *o1 = x1;
}

__device__ __forceinline__ float wave_sum(float v) {
#pragma unroll
  for (int off = 32; off > 0; off >>= 1) v += __shfl_xor(v, off);
  return v;
}

// ---------------- dtype probe ----------------
__global__ __launch_bounds__(256) void probe_dtype(const void* __restrict__ x,
                                                   int* __restrict__ flag) {
  __shared__ int cnt;
  if (threadIdx.x == 0) cnt = 0;
  __syncthreads();
  const unsigned short* u = (const unsigned short*)x;
  int bad = 0;
  for (int j = threadIdx.x; j < 2048; j += 256) {
    float v = bfbits(u[j]);
    float a = fabsf(v);
    bool ok = (v == 0.0f) || (a > 1e-4f && a < 100.0f);
    if (!ok) bad++;
  }
  atomicAdd(&cnt, bad);
  __syncthreads();
  if (threadIdx.x == 0) *flag = (cnt > 100) ? 1 : 0;
}

// ---------------- mega convert ----------------
struct CvtArgs {
  const void* src[23];
  float* dstF[23];
  unsigned short* dstB[23];
  int n[23];
  int blkStart[24];
};
__global__ __launch_bounds__(256) void mega_cvt(CvtArgs a, const int* __restrict__ flag) {
  int bid = blockIdx.x;
  int i = 0;
  while (i < 22 && bid >= a.blkStart[i + 1]) ++i;
  int e = (bid - a.blkStart[i]) * 256 + (int)threadIdx.x;
  if (e >= a.n[i]) return;
  float v; unsigned short rw;
  if (*flag) { v = ((const float*)a.src[i])[e]; rw = f2b(v); }
  else       { rw = ((const unsigned short*)a.src[i])[e]; v = bfbits(rw); }
  a.dstF[i][e] = v;
  if (a.dstB[i]) a.dstB[i][e] = rw;
}

// ---------------- conv weight repack ----------------
__global__ __launch_bounds__(256) void dcw_repack(const float* __restrict__ dcwF,
                                                  unsigned short* __restrict__ dcwT) {
  int gid = blockIdx.x * 256 + threadIdx.x;
  if (gid >= (NLL - 1) * 3 * 65536) return;
  int ly = gid / 196608;
  int r = gid - ly * 196608;
  int t = r >> 16;
  int r2 = r & 65535;
  int n = r2 >> 8, k = r2 & 255;
  dcwT[gid] = f2b(dcwF[ly * 196608 + n * 768 + k * 3 + t]);
}

// ---------------- idx generation ----------------
__global__ __launch_bounds__(256) void idx_kernel(uint32_t k20, uint32_t k21,
                                                  int* __restrict__ idx) {
  int j = blockIdx.x * 256 + threadIdx.x;
  if (j >= LL * UU) return;
  uint32_t o0, o1;
  const int half = (LL * UU) / 2;
  if (j < half) {
    threefry2x32(k20, k21, (uint32_t)j, (uint32_t)(j + half), &o0, &o1);
    idx[j] = (int)(o0 & (LL - 1));
  } else {
    threefry2x32(k20, k21, (uint32_t)(j - half), (uint32_t)j, &o0, &o1);
    idx[j] = (int)(o1 & (LL - 1));
  }
}

// ---------------- f32 GEMM for Q,K (row-major out), 128x128 tile, 8x8 micro ----------------
#define QBM 128
#define QBN 128
#define QBK 16
__global__ __launch_bounds__(256) void gemm_qk(const float* __restrict__ A,
                                               const float* __restrict__ Wq,
                                               const float* __restrict__ Wk,
                                               const float* __restrict__ bq,
                                               const float* __restrict__ bk,
                                               float* __restrict__ Cq,
                                               float* __restrict__ Ck) {
  const float* W = blockIdx.z ? Wk : Wq;
  const float* bias = blockIdx.z ? bk : bq;
  float* C = blockIdx.z ? Ck : Cq;
  __shared__ float As[QBK][QBM + 4];
  __shared__ float Bs[QBK][QBN + 4];
  int bm = blockIdx.x * QBM;
  int bn = blockIdx.y * QBN;
  int tid = threadIdx.x;
  int kk = tid & 15, rr = tid >> 4;
  int tx = tid & 15, ty = tid >> 4;
  float acc[8][8] = {};
  for (int k0 = 0; k0 < DMM; k0 += QBK) {
#pragma unroll
    for (int p = 0; p < 8; ++p) {
      As[kk][rr + 16 * p] = A[(size_t)(bm + rr + 16 * p) * DMM + k0 + kk];
      Bs[kk][rr + 16 * p] = W[(size_t)(bn + rr + 16 * p) * DMM + k0 + kk];
    }
    __syncthreads();
#pragma unroll
    for (int kq = 0; kq < QBK; ++kq) {
      float4 a0 = *(const float4*)(&As[kq][ty * 8]);
      float4 a1 = *(const float4*)(&As[kq][ty * 8 + 4]);
      float4 b0 = *(const float4*)(&Bs[kq][tx * 8]);
      float4 b1 = *(const float4*)(&Bs[kq][tx * 8 + 4]);
      float av[8] = {a0.x, a0.y, a0.z, a0.w, a1.x, a1.y, a1.z, a1.w};
      float bv[8] = {b0.x, b0.y, b0.z, b0.w, b1.x, b1.y, b1.z, b1.w};
#pragma unroll
      for (int i = 0; i < 8; ++i)
#pragma unroll
        for (int j = 0; j < 8; ++j) acc[i][j] = fmaf(av[i], bv[j], acc[i][j]);
    }
    __syncthreads();
  }
  int n = bn + tx * 8;
  float4 bv0 = *(const float4*)(bias + n);
  float4 bv1 = *(const float4*)(bias + n + 4);
#pragma unroll
  for (int i = 0; i < 8; ++i) {
    int row = bm + ty * 8 + i;
    float4 o0, o1;
    o0.x = acc[i][0] + bv0.x; o0.y = acc[i][1] + bv0.y;
    o0.z = acc[i][2] + bv0.z; o0.w = acc[i][3] + bv0.w;
    o1.x = acc[i][4] + bv1.x; o1.y = acc[i][5] + bv1.y;
    o1.z = acc[i][6] + bv1.z; o1.w = acc[i][7] + bv1.w;
    *(float4*)(C + (size_t)row * DMM + n) = o0;
    *(float4*)(C + (size_t)row * DMM + n + 4) = o1;
  }
}

// ---------------- bf16 MFMA GEMM (+3-tap conv mode) ----------------
__global__ __launch_bounds__(256) void gemm_mfma(const unsigned short* __restrict__ A,
                                                 const unsigned short* __restrict__ W,
                                                 const float* __restrict__ bias,
                                                 float* __restrict__ C, int ntaps) {
  __shared__ unsigned short As[128][40];
  __shared__ unsigned short Bs[64][40];
  int bm = blockIdx.x * 128, bn = blockIdx.y * 64;
  int tid = threadIdx.x;
  int wave = tid >> 6, lane = tid & 63;
  int wm = wave >> 1, wn = wave & 1;
  int l15 = lane & 15, quad = lane >> 4;
  f32x4 acc[4][2];
#pragma unroll
  for (int i = 0; i < 4; ++i)
#pragma unroll
    for (int j = 0; j < 2; ++j) acc[i][j] = (f32x4){0.f, 0.f, 0.f, 0.f};
  for (int tap = 0; tap < ntaps; ++tap) {
    int lshift = (ntaps == 3) ? (tap - 1) : 0;
    const unsigned short* Wt = W + (size_t)tap * 65536;
    for (int k0 = 0; k0 < 256; k0 += 32) {
      __syncthreads();
      for (int c = tid; c < 512; c += 256) {
        int row = c >> 2, seg = c & 3;
        int grow = bm + row;
        if (lshift != 0) {
          int bidx = grow >> 11, l = grow & 2047;
          grow = (bidx << 11) | ((l + lshift + 2048) & 2047);
        }
        *(uint4*)(&As[row][seg * 8]) =
            *(const uint4*)(A + (size_t)grow * 256 + k0 + seg * 8);
      }
      {
        int row = tid >> 2, seg = tid & 3;
        *(uint4*)(&Bs[row][seg * 8]) =
            *(const uint4*)(Wt + (size_t)(bn + row) * 256 + k0 + seg * 8);
      }
      __syncthreads();
      short8 af[4], bfr[2];
#pragma unroll
      for (int mt = 0; mt < 4; ++mt)
        af[mt] = *(const short8*)(&As[wm * 64 + mt * 16 + l15][quad * 8]);
#pragma unroll
      for (int nt = 0; nt < 2; ++nt)
        bfr[nt] = *(const short8*)(&Bs[wn * 32 + nt * 16 + l15][quad * 8]);
#pragma unroll
      for (int mt = 0; mt < 4; ++mt)
#pragma unroll
        for (int nt = 0; nt < 2; ++nt)
          acc[mt][nt] = __builtin_amdgcn_mfma_f32_16x16x32_bf16(af[mt], bfr[nt],
                                                                acc[mt][nt], 0, 0, 0);
    }
  }
#pragma unroll
  for (int nt = 0; nt < 2; ++nt) {
    int n = bn + wn * 32 + nt * 16 + l15;
    float bv = bias[n];
#pragma unroll
    for (int mt = 0; mt < 4; ++mt)
#pragma unroll
      for (int r = 0; r < 4; ++r) {
        int m = bm + wm * 64 + mt * 16 + quad * 4 + r;
        C[(size_t)m * 256 + n] = acc[mt][nt][r] + bv;
      }
  }
}

// ---------------- M scores: wave per (b,l), all 8 heads at once ----------------
// grid: b*512 + lchunk (4 l per block); K-row gathers are wave-coalesced 1KB loads
__global__ __launch_bounds__(256) void m_kernel3(const float* __restrict__ Q,
                                                 const float* __restrict__ K,
                                                 const int* __restrict__ idx,
                                                 float* __restrict__ M) {
  int blk = blockIdx.x;
  int b = blk >> 9, lc = blk & 511;
  int wave = threadIdx.x >> 6, lane = threadIdx.x & 63;
  int l = lc * 4 + wave;
  float4 q4 = *(const float4*)(Q + ((size_t)(b * LL + l)) * DMM + lane * 4);
  const float* Kb = K + (size_t)b * LL * DMM;
  const int* ip = idx + l * UU;
  float mx = -1e30f, sm = 0.f;
#pragma unroll 4
  for (int u = 0; u < UU; ++u) {
    int kidx = ip[u];
    float4 k4 = *(const float4*)(Kb + (size_t)kidx * DMM + lane * 4);
    float s = q4.x * k4.x + q4.y * k4.y + q4.z * k4.z + q4.w * k4.w;
    s += __shfl_xor(s, 1);
    s += __shfl_xor(s, 2);
    s += __shfl_xor(s, 4);
    mx = fmaxf(mx, s);
    sm += s;
  }
  if ((lane & 7) == 0) {
    int h = lane >> 3;
    M[((size_t)(b * HH + h)) * LL + l] = mx - sm * (1.0f / (float)LL);
  }
}

// ---------------- top-k stage A ----------------
__global__ __launch_bounds__(256) void cand_topk(const float* __restrict__ M,
                                                 u64* __restrict__ cand) {
  __shared__ u64 a[256];
  int bh = blockIdx.x >> 3, c = blockIdx.x & 7;
  int tid = threadIdx.x;
  int l = c * 256 + tid;
  float v = M[(size_t)bh * LL + l];
  uint32_t bits = __float_as_uint(v);
  uint32_t kv = (bits & 0x80000000u) ? ~bits : (bits | 0x80000000u);
  a[tid] = ((u64)kv << 32) | (uint32_t)(2047 - l);
  __syncthreads();
  for (int k = 2; k <= 256; k <<= 1)
    for (int j = k >> 1; j > 0; j >>= 1) {
      int ixj = tid ^ j;
      if (ixj > tid) {
        bool up = ((tid & k) == 0);
        u64 x = a[tid], y = a[ixj];
        if ((x > y) == up) { a[tid] = y; a[ixj] = x; }
      }
      __syncthreads();
    }
  if (tid >= 216) cand[(size_t)blockIdx.x * 40 + (tid - 216)] = a[tid];
}

// ---------------- top-k stage B ----------------
__global__ __launch_bounds__(256) void merge_topk(const u64* __restrict__ cand,
                                                  int* __restrict__ top) {
  __shared__ u64 a[512];
  int bh = blockIdx.x;
  int tid = threadIdx.x;
  for (int t = tid; t < 512; t += 256)
    a[t] = (t < 320) ? cand[(size_t)bh * 320 + t] : 0ULL;
  __syncthreads();
  for (int k = 2; k <= 512; k <<= 1)
    for (int j = k >> 1; j > 0; j >>= 1) {
      for (int t = tid; t < 512; t += 256) {
        int ixj = t ^ j;
        if (ixj > t) {
          bool up = ((t & k) == 0);
          u64 x = a[t], y = a[ixj];
          if ((x > y) == up) { a[t] = y; a[ixj] = x; }
        }
      }
      __syncthreads();
    }
  if (tid < UU) {
    u64 key = a[511 - tid];
    top[bh * UU + tid] = 2047 - (int)(uint32_t)(key & 0xFFFFFFFFu);
  }
}

// ---------------- v mean over L (256 blocks) ----------------
__global__ __launch_bounds__(256) void vmean_part(const float* __restrict__ V,
                                                  float* __restrict__ pv) {
  int blk = blockIdx.x;                  // b*64 + c
  int b = blk >> 6, c = blk & 63;
  int d = threadIdx.x;
  float s = 0.f;
  int base = b * LL + c * 32;
  for (int r = 0; r < 32; ++r) s += V[(size_t)(base + r) * DMM + d];
  pv[(size_t)blk * DMM + d] = s;
}
__global__ __launch_bounds__(256) void vmean_fin(const float* __restrict__ pv,
                                                 float* __restrict__ vm) {
  int gid = blockIdx.x * 256 + threadIdx.x;  // B*DM
  int b = gid >> 8, d = gid & 255;
  float s = 0.f;
  for (int c = 0; c < 64; ++c) s += pv[(size_t)(b * 64 + c) * DMM + d];
  vm[gid] = s * (1.0f / (float)LL);
}

__global__ __launch_bounds__(256) void ctx_init2(const float* __restrict__ vm,
                                                 unsigned short* __restrict__ ctxbf) {
  int gid = blockIdx.x * 256 + threadIdx.x;
  int d = gid & 255;
  int b = gid >> 19;
  ctxbf[gid] = f2b(vm[b * DMM + d]);
}

// ---------------- split-K flash attention: partials (row-major Q/K/V) ----------------
__global__ __launch_bounds__(256) void attn_part(const float* __restrict__ Q,
                                                 const float* __restrict__ K,
                                                 const float* __restrict__ V,
                                                 const int* __restrict__ top,
                                                 float* __restrict__ pm,
                                                 float* __restrict__ pl,
                                                 float* __restrict__ po) {
  __shared__ float Qs[40][32];
  __shared__ unsigned short ps[40][256];
  __shared__ float Vs[256][36];
  __shared__ int qrows[40];
  int kc = blockIdx.x, bh = blockIdx.y;
  int h = bh & 7, b = bh >> 3;
  int tid = threadIdx.x;
  int wv = tid >> 6, lane = tid & 63;
  if (tid < 40) qrows[tid] = top[bh * UU + tid];
  __syncthreads();
  for (int t = tid; t < 40 * 32; t += 256) {
    int q = t >> 5, d = t & 31;
    Qs[q][d] = Q[((size_t)(b * LL + qrows[q])) * DMM + h * EE + d];
  }
  {
    int krow = b * LL + kc * 256 + tid;
#pragma unroll
    for (int seg = 0; seg < 8; ++seg)
      *(float4*)(&Vs[tid][seg * 4]) =
          *(const float4*)(V + (size_t)krow * DMM + h * EE + seg * 4);
  }
  __syncthreads();
  {
    const float4* kp =
        (const float4*)(K + ((size_t)(b * LL + kc * 256 + tid)) * DMM + h * EE);
    float4 kr[8];
#pragma unroll
    for (int j = 0; j < 8; ++j) kr[j] = kp[j];
    const float scale = 0.17677669529663687f;
    for (int q = 0; q < 40; ++q) {
      const float4* qp = (const float4*)Qs[q];
      float s = 0.f;
#pragma unroll
      for (int j = 0; j < 8; ++j) {
        float4 qv = qp[j];
        s += qv.x * kr[j].x + qv.y * kr[j].y + qv.z * kr[j].z + qv.w * kr[j].w;
      }
      ps[q][tid] = f2b(s * scale);
    }
  }
  __syncthreads();
  int kg = lane >> 5, d = lane & 31;
  for (int qq = 0; qq < 10; ++qq) {
    int q = wv * 10 + qq;
    float mx = -1e30f;
#pragma unroll
    for (int e = 0; e < 4; ++e) mx = fmaxf(mx, bfbits(ps[q][lane + 64 * e]));
#pragma unroll
    for (int off = 32; off > 0; off >>= 1) mx = fmaxf(mx, __shfl_xor(mx, off));
    float sum = 0.f;
#pragma unroll
    for (int e = 0; e < 4; ++e) {
      int i = lane + 64 * e;
      float ev = expf(bfbits(ps[q][i]) - mx);
      sum += ev;
      ps[q][i] = f2b(ev);
    }
    sum = wave_sum(sum);
    float o = 0.f;
#pragma unroll 8
    for (int j = 0; j < 128; ++j) {
      int r = 2 * j + kg;
      o += bfbits(ps[q][r]) * Vs[r][d];
    }
    o += __shfl_xor(o, 32);
    size_t base = ((size_t)bh * UU + q) * 8 + kc;
    if (lane == 0) { pm[base] = mx; pl[base] = sum; }
    if (lane < 32) po[base * 32 + d] = o;
  }
}

// ---------------- merge partials -> ctx rows ----------------
__global__ __launch_bounds__(256) void attn_merge(const float* __restrict__ pm,
                                                  const float* __restrict__ pl,
                                                  const float* __restrict__ po,
                                                  const int* __restrict__ top,
                                                  unsigned short* __restrict__ ctxbf) {
  int bh = blockIdx.x;
  int h = bh & 7, b = bh >> 3;
  int tid = threadIdx.x;
  for (int qq = 0; qq < 5; ++qq) {
    int q = qq * 8 + (tid >> 5), d = tid & 31;
    size_t base = ((size_t)bh * UU + q) * 8;
    float M = -1e30f;
#pragma unroll
    for (int kc = 0; kc < 8; ++kc) M = fmaxf(M, pm[base + kc]);
    float L = 0.f, o = 0.f;
#pragma unroll
    for (int kc = 0; kc < 8; ++kc) {
      float sc = expf(pm[base + kc] - M);
      L += pl[base + kc] * sc;
      o += po[(base + kc) * 32 + d] * sc;
    }
    int qrow = top[bh * UU + q];
    ctxbf[((size_t)(b * LL + qrow)) * DMM + h * EE + d] = f2b(o / L);
  }
}

// ---------------- fused LN1(x+t) + FFN + LN2 (+ optional final LN -> d_out) ----------------
__global__ __launch_bounds__(256) void enc_tail(const float* __restrict__ X,
                                                const float* __restrict__ T,
                                                const float* __restrict__ g1,
                                                const float* __restrict__ b1ln,
                                                const float* __restrict__ w1,
                                                const float* __restrict__ b1,
                                                const float* __restrict__ w2,
                                                const float* __restrict__ b2,
                                                const float* __restrict__ g2,
                                                const float* __restrict__ b2ln,
                                                float* __restrict__ Out,
                                                unsigned short* __restrict__ OutB,
                                                const float* __restrict__ fing,
                                                const float* __restrict__ finb,
                                                void* __restrict__ finOut,
                                                const int* __restrict__ flag) {
  int wave = threadIdx.x >> 6, lane = threadIdx.x & 63;
  size_t row = (size_t)blockIdx.x * 4 + wave;
  __shared__ float xs[4][DMM];
  const float* xr = X + row * DMM;
  const float* tr = T + row * DMM;
  float v[4];
#pragma unroll
  for (int i = 0; i < 4; ++i) v[i] = xr[lane + 64 * i] + tr[lane + 64 * i];
  float s = wave_sum(v[0] + v[1] + v[2] + v[3]);
  float m = s * (1.0f / (float)DMM);
  float sq = 0.f;
#pragma unroll
  for (int i = 0; i < 4; ++i) { float d = v[i] - m; sq += d * d; }
  sq = wave_sum(sq);
  float rstd = rsqrtf(sq * (1.0f / (float)DMM) + 1e-5f);
  float xv[4];
#pragma unroll
  for (int i = 0; i < 4; ++i) {
    int d = lane + 64 * i;
    xv[i] = (v[i] - m) * rstd * g1[d] + b1ln[d];
    xs[wave][d] = xv[i];
  }
  __syncthreads();
  int f = lane & 15, qtr = lane >> 4;
  const float* w1p = w1 + f * DMM + qtr * 64;
  const float* xq = &xs[wave][qtr * 64];
  float pacc = 0.f;
#pragma unroll 8
  for (int d = 0; d < 64; ++d) pacc += xq[d] * w1p[d];
  pacc += __shfl_xor(pacc, 16);
  pacc += __shfl_xor(pacc, 32);
  float y1 = fmaxf(pacc + b1[f], 0.0f);
  float y1v[16];
#pragma unroll
  for (int ff = 0; ff < 16; ++ff) y1v[ff] = __shfl(y1, ff);
#pragma unroll
  for (int i = 0; i < 4; ++i) {
    int d = lane + 64 * i;
    const float* w2p = w2 + d * ITR;
    float a = b2[d];
#pragma unroll
    for (int ff = 0; ff < 16; ++ff) a += y1v[ff] * w2p[ff];
    v[i] = xv[i] + a;
  }
  s = wave_sum(v[0] + v[1] + v[2] + v[3]);
  m = s * (1.0f / (float)DMM);
  sq = 0.f;
#pragma unroll
  for (int i = 0; i < 4; ++i) { float d = v[i] - m; sq += d * d; }
  sq = wave_sum(sq);
  rstd = rsqrtf(sq * (1.0f / (float)DMM) + 1e-5f);
  float vv[4];
#pragma unroll
  for (int i = 0; i < 4; ++i) {
    int d = lane + 64 * i;
    float val = (v[i] - m) * rstd * g2[d] + b2ln[d];
    vv[i] = val;
    Out[row * DMM + d] = val;
    if (OutB) OutB[row * DMM + d] = f2b(val);
  }
  if (finOut) {
    s = wave_sum(vv[0] + vv[1] + vv[2] + vv[3]);
    m = s * (1.0f / (float)DMM);
    sq = 0.f;
#pragma unroll
    for (int i = 0; i < 4; ++i) { float d = vv[i] - m; sq += d * d; }
    sq = wave_sum(sq);
    rstd = rsqrtf(sq * (1.0f / (float)DMM) + 1e-5f);
    int isf32 = *flag;
#pragma unroll
    for (int i = 0; i < 4; ++i) {
      int d = lane + 64 * i;
      float val = (vv[i] - m) * rstd * fing[d] + finb[d];
      if (isf32) ((float*)finOut)[row * DMM + d] = val;
      else       ((unsigned short*)finOut)[row * DMM + d] = f2b(val);
    }
  }
}

// ---------------- batchnorm stats ----------------
__global__ __launch_bounds__(256) void stat_part(const float* __restrict__ Y,
                                                 float* __restrict__ ps,
                                                 float* __restrict__ ps2) {
  int c = blockIdx.x;
  int d = threadIdx.x;
  float s = 0.f, s2 = 0.f;
  int base = c * 256;
  for (int r = 0; r < 256; ++r) {
    float v = Y[(size_t)(base + r) * DMM + d];
    s += v;
    s2 += v * v;
  }
  ps[(size_t)c * DMM + d] = s;
  ps2[(size_t)c * DMM + d] = s2;
}
__global__ __launch_bounds__(256) void stat_fin(const float* __restrict__ ps,
                                                const float* __restrict__ ps2,
                                                float* __restrict__ mean,
                                                float* __restrict__ rstd) {
  int d = threadIdx.x;
  float s = 0.f, s2 = 0.f;
  for (int c = 0; c < 32; ++c) {
    s += ps[(size_t)c * DMM + d];
    s2 += ps2[(size_t)c * DMM + d];
  }
  float m = s * (1.0f / (float)ROWS);
  float var = s2 * (1.0f / (float)ROWS) - m * m;
  mean[d] = m;
  rstd[d] = rsqrtf(var + 1e-5f);
}

__global__ __launch_bounds__(256) void bn_elu(const float* __restrict__ Y,
                                              const float* __restrict__ mean,
                                              const float* __restrict__ rstd,
                                              const float* __restrict__ g,
                                              const float* __restrict__ bb,
                                              float* __restrict__ X,
                                              unsigned short* __restrict__ XB) {
  int gid = blockIdx.x * 256 + threadIdx.x;
  int d = gid & 255;
  float v = (Y[gid] - mean[d]) * rstd[d] * g[d] + bb[d];
  float r = v > 0.f ? v : expm1f(v);
  X[gid] = r;
  XB[gid] = f2b(r);
}

extern "C" void kernel_launch(void* const* d_in, const int* in_sizes, int n_in,
                              void* d_out, int out_size, void* d_ws, size_t ws_size,
                              hipStream_t stream) {
  (void)in_sizes; (void)n_in; (void)out_size; (void)ws_size;

  // ---- workspace layout ----
  float* xbuf = (float*)d_ws;
  float* kb   = xbuf + NELEM;
  float* vb   = kb + NELEM;
  float* qb   = vb + NELEM;   // aliases tmp (Q dead after attn_part)
  float* tmp  = qb;
  float* Mbuf = qb + NELEM;
  float* vmp  = Mbuf + BB * HH * LL;          // 256*DM
  float* vmean= vmp + 256 * DMM;
  float* stp  = vmean + BB * DMM;
  float* stp2 = stp + 32 * DMM;
  float* smean= stp2 + 32 * DMM;
  float* srstd= smean + DMM;
  float* wp   = srstd + DMM;
  const int wsz[23] = {
      NELEM,
      NLL * DMM * DMM, NLL * DMM,
      NLL * DMM * DMM, NLL * DMM,
      NLL * DMM * DMM, NLL * DMM,
      NLL * DMM * DMM, NLL * DMM,
      NLL * ITR * DMM, NLL * ITR,
      NLL * DMM * ITR, NLL * DMM,
      NLL * DMM, NLL * DMM,
      NLL * DMM, NLL * DMM,
      (NLL - 1) * DMM * DMM * 3, (NLL - 1) * DMM,
      (NLL - 1) * DMM, (NLL - 1) * DMM,
      DMM, DMM
  };
  float* fptr[23];
  fptr[0] = xbuf;
  for (int i = 1; i < 23; ++i) { fptr[i] = wp; wp += wsz[i]; }
  float* pm = wp;
  float* pl = pm + 32 * UU * 8;
  float* po = pl + 32 * UU * 8;
  unsigned short* xbf   = (unsigned short*)(po + 32 * UU * 8 * 32);
  unsigned short* ctxbf = xbf + NELEM;
  unsigned short* wvbf  = ctxbf + NELEM;
  unsigned short* wobf  = wvbf + NLL * DMM * DMM;
  unsigned short* dcwT  = wobf + NLL * DMM * DMM;
  u64* cand = (u64*)(dcwT + (NLL - 1) * 3 * DMM * DMM);
  int* idxb = (int*)(cand + 32 * 320);
  int* topb = idxb + LL * UU;
  int* flag = topb + BB * HH * UU;

  // ---- probe + convert ----
  probe_dtype<<<1, 256, 0, stream>>>(d_in[0], flag);
  CvtArgs ca;
  int totalBlk = 0;
  for (int i = 0; i < 23; ++i) {
    ca.src[i] = d_in[i];
    ca.dstF[i] = fptr[i];
    ca.dstB[i] = nullptr;
    ca.n[i] = wsz[i];
    ca.blkStart[i] = totalBlk;
    totalBlk += (wsz[i] + 255) / 256;
  }
  ca.blkStart[23] = totalBlk;
  ca.dstB[0] = xbf;
  ca.dstB[5] = wvbf;
  ca.dstB[7] = wobf;
  mega_cvt<<<totalBlk, 256, 0, stream>>>(ca, flag);
  dcw_repack<<<((NLL - 1) * 3 * 65536 + 255) / 256, 256, 0, stream>>>(fptr[17], dcwT);

  dim3 gqk(ROWS / QBM, DMM / QBN, 2);
  dim3 gm(ROWS / 128, DMM / 64);

  for (int i = 0; i < NLL; ++i) {
    gemm_qk<<<gqk, 256, 0, stream>>>(xbuf, fptr[1] + (size_t)i * DMM * DMM,
                                     fptr[3] + (size_t)i * DMM * DMM,
                                     fptr[2] + i * DMM, fptr[4] + i * DMM, qb, kb);
    gemm_mfma<<<gm, 256, 0, stream>>>(xbf, wvbf + (size_t)i * DMM * DMM,
                                      fptr[6] + i * DMM, vb, 1);

    uint32_t ki0, ki1, a0, a1, b0, b1;
    threefry2x32(0u, 42u, 0u, (uint32_t)i, &ki0, &ki1);
    threefry2x32(ki0, ki1, 0u, 2u, &a0, &a1);
    threefry2x32(ki0, ki1, 1u, 3u, &b0, &b1);
    (void)a0; (void)b0;
    idx_kernel<<<(LL * UU) / 256, 256, 0, stream>>>(a1, b1, idxb);

    m_kernel3<<<BB * 512, 256, 0, stream>>>(qb, kb, idxb, Mbuf);
    cand_topk<<<BB * HH * 8, 256, 0, stream>>>(Mbuf, cand);
    merge_topk<<<BB * HH, 256, 0, stream>>>(cand, topb);
    vmean_part<<<BB * 64, 256, 0, stream>>>(vb, vmp);
    vmean_fin<<<(BB * DMM) / 256, 256, 0, stream>>>(vmp, vmean);
    ctx_init2<<<NELEM / 256, 256, 0, stream>>>(vmean, ctxbf);
    attn_part<<<dim3(8, BB * HH), 256, 0, stream>>>(qb, kb, vb, topb, pm, pl, po);
    attn_merge<<<BB * HH, 256, 0, stream>>>(pm, pl, po, topb, ctxbf);

    gemm_mfma<<<gm, 256, 0, stream>>>(ctxbf, wobf + (size_t)i * DMM * DMM,
                                      fptr[8] + i * DMM, tmp, 1);
    bool last = (i == NLL - 1);
    enc_tail<<<ROWS / 4, 256, 0, stream>>>(
        xbuf, tmp, fptr[13] + i * DMM, fptr[14] + i * DMM,
        fptr[9] + (size_t)i * ITR * DMM, fptr[10] + i * ITR,
        fptr[11] + (size_t)i * DMM * ITR, fptr[12] + i * DMM,
        fptr[15] + i * DMM, fptr[16] + i * DMM, xbuf, xbf,
        fptr[21], fptr[22], last ? d_out : nullptr, flag);

    if (!last) {
      gemm_mfma<<<gm, 256, 0, stream>>>(xbf, dcwT + (size_t)i * 3 * DMM * DMM,
                                        fptr[18] + i * DMM, tmp, 3);
      stat_part<<<32, 256, 0, stream>>>(tmp, stp, stp2);
      stat_fin<<<1, 256, 0, stream>>>(stp, stp2, smean, srstd);
      bn_elu<<<NELEM / 256, 256, 0, stream>>>(tmp, smean, srstd, fptr[19] + i * DMM,
                                              fptr[20] + i * DMM, xbuf, xbf);
    }
  }
}

// Round 7
// 638.798 us; speedup vs baseline: 2.2658x; 1.2117x over previous
//
#include <hip/hip_runtime.h>
#include <stdint.h>

#define BB 4
#define LL 2048
#define DMM 256
#define HH 8
#define EE 32
#define NLL 3
#define ITR 16
#define UU 40
#define ROWS (BB*LL)          // 8192
#define NELEM (ROWS*DMM)      // 2097152

typedef __attribute__((ext_vector_type(8))) short short8;
typedef __attribute__((ext_vector_type(4))) float f32x4;
typedef unsigned long long u64;

// ---------------- bf16 bit helpers (RNE) ----------------
__device__ __forceinline__ float bfbits(unsigned short u) {
  return __uint_as_float(((uint32_t)u) << 16);
}
__device__ __forceinline__ unsigned short f2b(float f) {
  uint32_t u = __float_as_uint(f);
  uint32_t r = (u + 0x7FFFu + ((u >> 16) & 1u)) >> 16;
  return (unsigned short)r;
}

// ---------------- threefry2x32 (exact JAX semantics) ----------------
__host__ __device__ inline void threefry2x32(uint32_t k0, uint32_t k1,
                                             uint32_t x0, uint32_t x1,
                                             uint32_t* o0, uint32_t* o1) {
  uint32_t ks2 = k0 ^ k1 ^ 0x1BD11BDAu;
  x0 += k0; x1 += k1;
#define TFR(r) { x0 += x1; x1 = (x1 << (r)) | (x1 >> (32 - (r))); x1 ^= x0; }
  TFR(13) TFR(15) TFR(26) TFR(6)
  x0 += k1;  x1 += ks2 + 1u;
  TFR(17) TFR(29) TFR(16) TFR(24)
  x0 += ks2; x1 += k0 + 2u;
  TFR(13) TFR(15) TFR(26) TFR(6)
  x0 += k0;  x1 += k1 + 3u;
  TFR(17) TFR(29) TFR(16) TFR(24)
  x0 += k1;  x1 += ks2 + 4u;
  TFR(13) TFR(15) TFR(26) TFR(6)
  x0 += ks2; x1 += k0 + 5u;
#undef TFR
  *o0 = x0; *o1 = x1;
}

__device__ __forceinline__ float wave_sum(float v) {
#pragma unroll
  for (int off = 32; off > 0; off >>= 1) v += __shfl_xor(v, off);
  return v;
}

// ---------------- dtype probe ----------------
__global__ __launch_bounds__(256) void probe_dtype(const void* __restrict__ x,
                                                   int* __restrict__ flag) {
  __shared__ int cnt;
  if (threadIdx.x == 0) cnt = 0;
  __syncthreads();
  const unsigned short* u = (const unsigned short*)x;
  int bad = 0;
  for (int j = threadIdx.x; j < 2048; j += 256) {
    float v = bfbits(u[j]);
    float a = fabsf(v);
    bool ok = (v == 0.0f) || (a > 1e-4f && a < 100.0f);
    if (!ok) bad++;
  }
  atomicAdd(&cnt, bad);
  __syncthreads();
  if (threadIdx.x == 0) *flag = (cnt > 100) ? 1 : 0;
}

// ---------------- mega convert (+hi/lo bf16 splits) ----------------
struct CvtArgs {
  const void* src[23];
  float* dstF[23];
  unsigned short* dstB[23];
  unsigned short* dstL[23];
  int n[23];
  int blkStart[24];
};
__global__ __launch_bounds__(256) void mega_cvt(CvtArgs a, const int* __restrict__ flag) {
  int bid = blockIdx.x;
  int i = 0;
  while (i < 22 && bid >= a.blkStart[i + 1]) ++i;
  int e = (bid - a.blkStart[i]) * 256 + (int)threadIdx.x;
  if (e >= a.n[i]) return;
  float v; unsigned short rw;
  if (*flag) { v = ((const float*)a.src[i])[e]; rw = f2b(v); }
  else       { rw = ((const unsigned short*)a.src[i])[e]; v = bfbits(rw); }
  a.dstF[i][e] = v;
  if (a.dstB[i]) a.dstB[i][e] = rw;
  if (a.dstL[i]) a.dstL[i][e] = f2b(v - bfbits(rw));
}

// ---------------- conv weight repack ----------------
__global__ __launch_bounds__(256) void dcw_repack(const float* __restrict__ dcwF,
                                                  unsigned short* __restrict__ dcwT) {
  int gid = blockIdx.x * 256 + threadIdx.x;
  if (gid >= (NLL - 1) * 3 * 65536) return;
  int ly = gid / 196608;
  int r = gid - ly * 196608;
  int t = r >> 16;
  int r2 = r & 65535;
  int n = r2 >> 8, k = r2 & 255;
  dcwT[gid] = f2b(dcwF[ly * 196608 + n * 768 + k * 3 + t]);
}

// ---------------- idx generation ----------------
__global__ __launch_bounds__(256) void idx_kernel(uint32_t k20, uint32_t k21,
                                                  int* __restrict__ idx) {
  int j = blockIdx.x * 256 + threadIdx.x;
  if (j >= LL * UU) return;
  uint32_t o0, o1;
  const int half = (LL * UU) / 2;
  if (j < half) {
    threefry2x32(k20, k21, (uint32_t)j, (uint32_t)(j + half), &o0, &o1);
    idx[j] = (int)(o0 & (LL - 1));
  } else {
    threefry2x32(k20, k21, (uint32_t)(j - half), (uint32_t)j, &o0, &o1);
    idx[j] = (int)(o1 & (LL - 1));
  }
}

// ---------------- QKV MFMA GEMM: hi/lo 2-pass, z=0:Q 1:K 2:V ----------------
// C[z][8192,256] = (A_hi + A_lo) @ W[z]^T + bias[z], f32 out.
struct QKVArgs {
  const unsigned short* W[3];
  const float* bias[3];
  float* C[3];
};
__global__ __launch_bounds__(256) void gemm_qkv(const unsigned short* __restrict__ Ahi,
                                                const unsigned short* __restrict__ Alo,
                                                QKVArgs qa) {
  __shared__ unsigned short AsH[128][40];
  __shared__ unsigned short AsL[128][40];
  __shared__ unsigned short Bs[64][40];
  const unsigned short* W = qa.W[blockIdx.z];
  const float* bias = qa.bias[blockIdx.z];
  float* C = qa.C[blockIdx.z];
  int bm = blockIdx.x * 128, bn = blockIdx.y * 64;
  int tid = threadIdx.x;
  int wave = tid >> 6, lane = tid & 63;
  int wm = wave >> 1, wn = wave & 1;
  int l15 = lane & 15, quad = lane >> 4;
  f32x4 acc[4][2];
#pragma unroll
  for (int i = 0; i < 4; ++i)
#pragma unroll
    for (int j = 0; j < 2; ++j) acc[i][j] = (f32x4){0.f, 0.f, 0.f, 0.f};
  for (int k0 = 0; k0 < 256; k0 += 32) {
    __syncthreads();
    for (int c = tid; c < 512; c += 256) {
      int row = c >> 2, seg = c & 3;
      size_t off = (size_t)(bm + row) * 256 + k0 + seg * 8;
      *(uint4*)(&AsH[row][seg * 8]) = *(const uint4*)(Ahi + off);
      *(uint4*)(&AsL[row][seg * 8]) = *(const uint4*)(Alo + off);
    }
    {
      int row = tid >> 2, seg = tid & 3;
      *(uint4*)(&Bs[row][seg * 8]) =
          *(const uint4*)(W + (size_t)(bn + row) * 256 + k0 + seg * 8);
    }
    __syncthreads();
    short8 ah[4], al[4], bfr[2];
#pragma unroll
    for (int mt = 0; mt < 4; ++mt) {
      ah[mt] = *(const short8*)(&AsH[wm * 64 + mt * 16 + l15][quad * 8]);
      al[mt] = *(const short8*)(&AsL[wm * 64 + mt * 16 + l15][quad * 8]);
    }
#pragma unroll
    for (int nt = 0; nt < 2; ++nt)
      bfr[nt] = *(const short8*)(&Bs[wn * 32 + nt * 16 + l15][quad * 8]);
#pragma unroll
    for (int mt = 0; mt < 4; ++mt)
#pragma unroll
      for (int nt = 0; nt < 2; ++nt) {
        acc[mt][nt] = __builtin_amdgcn_mfma_f32_16x16x32_bf16(ah[mt], bfr[nt],
                                                              acc[mt][nt], 0, 0, 0);
        acc[mt][nt] = __builtin_amdgcn_mfma_f32_16x16x32_bf16(al[mt], bfr[nt],
                                                              acc[mt][nt], 0, 0, 0);
      }
  }
#pragma unroll
  for (int nt = 0; nt < 2; ++nt) {
    int n = bn + wn * 32 + nt * 16 + l15;
    float bv = bias[n];
#pragma unroll
    for (int mt = 0; mt < 4; ++mt)
#pragma unroll
      for (int r = 0; r < 4; ++r) {
        int m = bm + wm * 64 + mt * 16 + quad * 4 + r;
        C[(size_t)m * 256 + n] = acc[mt][nt][r] + bv;
      }
  }
}

// ---------------- bf16 MFMA GEMM 64x64 tile (O-proj + 3-tap conv) ----------------
__global__ __launch_bounds__(256) void gemm_mfma64(const unsigned short* __restrict__ A,
                                                   const unsigned short* __restrict__ W,
                                                   const float* __restrict__ bias,
                                                   float* __restrict__ C, int ntaps) {
  __shared__ unsigned short As[64][40];
  __shared__ unsigned short Bs[64][40];
  int bm = blockIdx.x * 64, bn = blockIdx.y * 64;
  int tid = threadIdx.x;
  int wave = tid >> 6, lane = tid & 63;
  int wm = wave >> 1, wn = wave & 1;
  int l15 = lane & 15, quad = lane >> 4;
  f32x4 acc[2][2];
#pragma unroll
  for (int i = 0; i < 2; ++i)
#pragma unroll
    for (int j = 0; j < 2; ++j) acc[i][j] = (f32x4){0.f, 0.f, 0.f, 0.f};
  for (int tap = 0; tap < ntaps; ++tap) {
    int lshift = (ntaps == 3) ? (tap - 1) : 0;
    const unsigned short* Wt = W + (size_t)tap * 65536;
    for (int k0 = 0; k0 < 256; k0 += 32) {
      __syncthreads();
      {
        int row = tid >> 2, seg = tid & 3;
        int grow = bm + row;
        if (lshift != 0) {
          int bidx = grow >> 11, l = grow & 2047;
          grow = (bidx << 11) | ((l + lshift + 2048) & 2047);
        }
        *(uint4*)(&As[row][seg * 8]) =
            *(const uint4*)(A + (size_t)grow * 256 + k0 + seg * 8);
        *(uint4*)(&Bs[row][seg * 8]) =
            *(const uint4*)(Wt + (size_t)(bn + row) * 256 + k0 + seg * 8);
      }
      __syncthreads();
      short8 af[2], bfr[2];
#pragma unroll
      for (int mt = 0; mt < 2; ++mt)
        af[mt] = *(const short8*)(&As[wm * 32 + mt * 16 + l15][quad * 8]);
#pragma unroll
      for (int nt = 0; nt < 2; ++nt)
        bfr[nt] = *(const short8*)(&Bs[wn * 32 + nt * 16 + l15][quad * 8]);
#pragma unroll
      for (int mt = 0; mt < 2; ++mt)
#pragma unroll
        for (int nt = 0; nt < 2; ++nt)
          acc[mt][nt] = __builtin_amdgcn_mfma_f32_16x16x32_bf16(af[mt], bfr[nt],
                                                                acc[mt][nt], 0, 0, 0);
    }
  }
#pragma unroll
  for (int nt = 0; nt < 2; ++nt) {
    int n = bn + wn * 32 + nt * 16 + l15;
    float bv = bias[n];
#pragma unroll
    for (int mt = 0; mt < 2; ++mt)
#pragma unroll
      for (int r = 0; r < 4; ++r) {
        int m = bm + wm * 32 + mt * 16 + quad * 4 + r;
        C[(size_t)m * 256 + n] = acc[mt][nt][r] + bv;
      }
  }
}

// ---------------- M scores: wave per (b,l), all 8 heads at once ----------------
__global__ __launch_bounds__(256) void m_kernel3(const float* __restrict__ Q,
                                                 const float* __restrict__ K,
                                                 const int* __restrict__ idx,
                                                 float* __restrict__ M) {
  int blk = blockIdx.x;
  int b = blk >> 9, lc = blk & 511;
  int wave = threadIdx.x >> 6, lane = threadIdx.x & 63;
  int l = lc * 4 + wave;
  float4 q4 = *(const float4*)(Q + ((size_t)(b * LL + l)) * DMM + lane * 4);
  const float* Kb = K + (size_t)b * LL * DMM;
  const int* ip = idx + l * UU;
  float mx = -1e30f, sm = 0.f;
#pragma unroll 4
  for (int u = 0; u < UU; ++u) {
    int kidx = ip[u];
    float4 k4 = *(const float4*)(Kb + (size_t)kidx * DMM + lane * 4);
    float s = q4.x * k4.x + q4.y * k4.y + q4.z * k4.z + q4.w * k4.w;
    s += __shfl_xor(s, 1);
    s += __shfl_xor(s, 2);
    s += __shfl_xor(s, 4);
    mx = fmaxf(mx, s);
    sm += s;
  }
  if ((lane & 7) == 0) {
    int h = lane >> 3;
    M[((size_t)(b * HH + h)) * LL + l] = mx - sm * (1.0f / (float)LL);
  }
}

// ---------------- top-k stage A ----------------
__global__ __launch_bounds__(256) void cand_topk(const float* __restrict__ M,
                                                 u64* __restrict__ cand) {
  __shared__ u64 a[256];
  int bh = blockIdx.x >> 3, c = blockIdx.x & 7;
  int tid = threadIdx.x;
  int l = c * 256 + tid;
  float v = M[(size_t)bh * LL + l];
  uint32_t bits = __float_as_uint(v);
  uint32_t kv = (bits & 0x80000000u) ? ~bits : (bits | 0x80000000u);
  a[tid] = ((u64)kv << 32) | (uint32_t)(2047 - l);
  __syncthreads();
  for (int k = 2; k <= 256; k <<= 1)
    for (int j = k >> 1; j > 0; j >>= 1) {
      int ixj = tid ^ j;
      if (ixj > tid) {
        bool up = ((tid & k) == 0);
        u64 x = a[tid], y = a[ixj];
        if ((x > y) == up) { a[tid] = y; a[ixj] = x; }
      }
      __syncthreads();
    }
  if (tid >= 216) cand[(size_t)blockIdx.x * 40 + (tid - 216)] = a[tid];
}

// ---------------- top-k stage B ----------------
__global__ __launch_bounds__(256) void merge_topk(const u64* __restrict__ cand,
                                                  int* __restrict__ top) {
  __shared__ u64 a[512];
  int bh = blockIdx.x;
  int tid = threadIdx.x;
  for (int t = tid; t < 512; t += 256)
    a[t] = (t < 320) ? cand[(size_t)bh * 320 + t] : 0ULL;
  __syncthreads();
  for (int k = 2; k <= 512; k <<= 1)
    for (int j = k >> 1; j > 0; j >>= 1) {
      for (int t = tid; t < 512; t += 256) {
        int ixj = t ^ j;
        if (ixj > t) {
          bool up = ((t & k) == 0);
          u64 x = a[t], y = a[ixj];
          if ((x > y) == up) { a[t] = y; a[ixj] = x; }
        }
      }
      __syncthreads();
    }
  if (tid < UU) {
    u64 key = a[511 - tid];
    top[bh * UU + tid] = 2047 - (int)(uint32_t)(key & 0xFFFFFFFFu);
  }
}

// ---------------- v mean over L ----------------
__global__ __launch_bounds__(256) void vmean_part(const float* __restrict__ V,
                                                  float* __restrict__ pv) {
  int blk = blockIdx.x;
  int b = blk >> 6, c = blk & 63;
  int d = threadIdx.x;
  float s = 0.f;
  int base = b * LL + c * 32;
  for (int r = 0; r < 32; ++r) s += V[(size_t)(base + r) * DMM + d];
  pv[(size_t)blk * DMM + d] = s;
}
__global__ __launch_bounds__(256) void vmean_fin(const float* __restrict__ pv,
                                                 float* __restrict__ vm) {
  int gid = blockIdx.x * 256 + threadIdx.x;
  int b = gid >> 8, d = gid & 255;
  float s = 0.f;
  for (int c = 0; c < 64; ++c) s += pv[(size_t)(b * 64 + c) * DMM + d];
  vm[gid] = s * (1.0f / (float)LL);
}

__global__ __launch_bounds__(256) void ctx_init2(const float* __restrict__ vm,
                                                 unsigned short* __restrict__ ctxbf) {
  int gid = blockIdx.x * 256 + threadIdx.x;
  int d = gid & 255;
  int b = gid >> 19;
  ctxbf[gid] = f2b(vm[b * DMM + d]);
}

// ---------------- split-K flash attention: partials ----------------
__global__ __launch_bounds__(256) void attn_part(const float* __restrict__ Q,
                                                 const float* __restrict__ K,
                                                 const float* __restrict__ V,
                                                 const int* __restrict__ top,
                                                 float* __restrict__ pm,
                                                 float* __restrict__ pl,
                                                 float* __restrict__ po) {
  __shared__ float Qs[40][32];
  __shared__ unsigned short ps[40][256];
  __shared__ float Vs[256][36];
  __shared__ int qrows[40];
  int kc = blockIdx.x, bh = blockIdx.y;
  int h = bh & 7, b = bh >> 3;
  int tid = threadIdx.x;
  int wv = tid >> 6, lane = tid & 63;
  if (tid < 40) qrows[tid] = top[bh * UU + tid];
  __syncthreads();
  for (int t = tid; t < 40 * 32; t += 256) {
    int q = t >> 5, d = t & 31;
    Qs[q][d] = Q[((size_t)(b * LL + qrows[q])) * DMM + h * EE + d];
  }
  {
    int krow = b * LL + kc * 256 + tid;
#pragma unroll
    for (int seg = 0; seg < 8; ++seg)
      *(float4*)(&Vs[tid][seg * 4]) =
          *(const float4*)(V + (size_t)krow * DMM + h * EE + seg * 4);
  }
  __syncthreads();
  {
    const float4* kp =
        (const float4*)(K + ((size_t)(b * LL + kc * 256 + tid)) * DMM + h * EE);
    float4 kr[8];
#pragma unroll
    for (int j = 0; j < 8; ++j) kr[j] = kp[j];
    const float scale = 0.17677669529663687f;
    for (int q = 0; q < 40; ++q) {
      const float4* qp = (const float4*)Qs[q];
      float s = 0.f;
#pragma unroll
      for (int j = 0; j < 8; ++j) {
        float4 qv = qp[j];
        s += qv.x * kr[j].x + qv.y * kr[j].y + qv.z * kr[j].z + qv.w * kr[j].w;
      }
      ps[q][tid] = f2b(s * scale);
    }
  }
  __syncthreads();
  int kg = lane >> 5, d = lane & 31;
  for (int qq = 0; qq < 10; ++qq) {
    int q = wv * 10 + qq;
    float mx = -1e30f;
#pragma unroll
    for (int e = 0; e < 4; ++e) mx = fmaxf(mx, bfbits(ps[q][lane + 64 * e]));
#pragma unroll
    for (int off = 32; off > 0; off >>= 1) mx = fmaxf(mx, __shfl_xor(mx, off));
    float sum = 0.f;
#pragma unroll
    for (int e = 0; e < 4; ++e) {
      int i = lane + 64 * e;
      float ev = expf(bfbits(ps[q][i]) - mx);
      sum += ev;
      ps[q][i] = f2b(ev);
    }
    sum = wave_sum(sum);
    float o = 0.f;
#pragma unroll 8
    for (int j = 0; j < 128; ++j) {
      int r = 2 * j + kg;
      o += bfbits(ps[q][r]) * Vs[r][d];
    }
    o += __shfl_xor(o, 32);
    size_t base = ((size_t)bh * UU + q) * 8 + kc;
    if (lane == 0) { pm[base] = mx; pl[base] = sum; }
    if (lane < 32) po[base * 32 + d] = o;
  }
}

// ---------------- merge partials -> ctx rows ----------------
__global__ __launch_bounds__(256) void attn_merge(const float* __restrict__ pm,
                                                  const float* __restrict__ pl,
                                                  const float* __restrict__ po,
                                                  const int* __restrict__ top,
                                                  unsigned short* __restrict__ ctxbf) {
  int bh = blockIdx.x;
  int h = bh & 7, b = bh >> 3;
  int tid = threadIdx.x;
  for (int qq = 0; qq < 5; ++qq) {
    int q = qq * 8 + (tid >> 5), d = tid & 31;
    size_t base = ((size_t)bh * UU + q) * 8;
    float M = -1e30f;
#pragma unroll
    for (int kc = 0; kc < 8; ++kc) M = fmaxf(M, pm[base + kc]);
    float L = 0.f, o = 0.f;
#pragma unroll
    for (int kc = 0; kc < 8; ++kc) {
      float sc = expf(pm[base + kc] - M);
      L += pl[base + kc] * sc;
      o += po[(base + kc) * 32 + d] * sc;
    }
    int qrow = top[bh * UU + q];
    ctxbf[((size_t)(b * LL + qrow)) * DMM + h * EE + d] = f2b(o / L);
  }
}

// ---------------- fused LN1(x+t) + FFN + LN2 (+ optional final LN) ----------------
__global__ __launch_bounds__(256) void enc_tail(const float* __restrict__ X,
                                                const float* __restrict__ T,
                                                const float* __restrict__ g1,
                                                const float* __restrict__ b1ln,
                                                const float* __restrict__ w1,
                                                const float* __restrict__ b1,
                                                const float* __restrict__ w2,
                                                const float* __restrict__ b2,
                                                const float* __restrict__ g2,
                                                const float* __restrict__ b2ln,
                                                float* __restrict__ Out,
                                                unsigned short* __restrict__ OutB,
                                                unsigned short* __restrict__ OutL,
                                                const float* __restrict__ fing,
                                                const float* __restrict__ finb,
                                                void* __restrict__ finOut,
                                                const int* __restrict__ flag) {
  int wave = threadIdx.x >> 6, lane = threadIdx.x & 63;
  size_t row = (size_t)blockIdx.x * 4 + wave;
  __shared__ float xs[4][DMM];
  const float* xr = X + row * DMM;
  const float* tr = T + row * DMM;
  float v[4];
#pragma unroll
  for (int i = 0; i < 4; ++i) v[i] = xr[lane + 64 * i] + tr[lane + 64 * i];
  float s = wave_sum(v[0] + v[1] + v[2] + v[3]);
  float m = s * (1.0f / (float)DMM);
  float sq = 0.f;
#pragma unroll
  for (int i = 0; i < 4; ++i) { float d = v[i] - m; sq += d * d; }
  sq = wave_sum(sq);
  float rstd = rsqrtf(sq * (1.0f / (float)DMM) + 1e-5f);
  float xv[4];
#pragma unroll
  for (int i = 0; i < 4; ++i) {
    int d = lane + 64 * i;
    xv[i] = (v[i] - m) * rstd * g1[d] + b1ln[d];
    xs[wave][d] = xv[i];
  }
  __syncthreads();
  int f = lane & 15, qtr = lane >> 4;
  const float* w1p = w1 + f * DMM + qtr * 64;
  const float* xq = &xs[wave][qtr * 64];
  float pacc = 0.f;
#pragma unroll 8
  for (int d = 0; d < 64; ++d) pacc += xq[d] * w1p[d];
  pacc += __shfl_xor(pacc, 16);
  pacc += __shfl_xor(pacc, 32);
  float y1 = fmaxf(pacc + b1[f], 0.0f);
  float y1v[16];
#pragma unroll
  for (int ff = 0; ff < 16; ++ff) y1v[ff] = __shfl(y1, ff);
#pragma unroll
  for (int i = 0; i < 4; ++i) {
    int d = lane + 64 * i;
    const float* w2p = w2 + d * ITR;
    float a = b2[d];
#pragma unroll
    for (int ff = 0; ff < 16; ++ff) a += y1v[ff] * w2p[ff];
    v[i] = xv[i] + a;
  }
  s = wave_sum(v[0] + v[1] + v[2] + v[3]);
  m = s * (1.0f / (float)DMM);
  sq = 0.f;
#pragma unroll
  for (int i = 0; i < 4; ++i) { float d = v[i] - m; sq += d * d; }
  sq = wave_sum(sq);
  rstd = rsqrtf(sq * (1.0f / (float)DMM) + 1e-5f);
  float vv[4];
#pragma unroll
  for (int i = 0; i < 4; ++i) {
    int d = lane + 64 * i;
    float val = (v[i] - m) * rstd * g2[d] + b2ln[d];
    vv[i] = val;
    Out[row * DMM + d] = val;
    unsigned short hi = f2b(val);
    OutB[row * DMM + d] = hi;
    OutL[row * DMM + d] = f2b(val - bfbits(hi));
  }
  if (finOut) {
    s = wave_sum(vv[0] + vv[1] + vv[2] + vv[3]);
    m = s * (1.0f / (float)DMM);
    sq = 0.f;
#pragma unroll
    for (int i = 0; i < 4; ++i) { float d = vv[i] - m; sq += d * d; }
    sq = wave_sum(sq);
    rstd = rsqrtf(sq * (1.0f / (float)DMM) + 1e-5f);
    int isf32 = *flag;
#pragma unroll
    for (int i = 0; i < 4; ++i) {
      int d = lane + 64 * i;
      float val = (vv[i] - m) * rstd * fing[d] + finb[d];
      if (isf32) ((float*)finOut)[row * DMM + d] = val;
      else       ((unsigned short*)finOut)[row * DMM + d] = f2b(val);
    }
  }
}

// ---------------- batchnorm stats ----------------
__global__ __launch_bounds__(256) void stat_part(const float* __restrict__ Y,
                                                 float* __restrict__ ps,
                                                 float* __restrict__ ps2) {
  int c = blockIdx.x;
  int d = threadIdx.x;
  float s = 0.f, s2 = 0.f;
  int base = c * 256;
  for (int r = 0; r < 256; ++r) {
    float v = Y[(size_t)(base + r) * DMM + d];
    s += v;
    s2 += v * v;
  }
  ps[(size_t)c * DMM + d] = s;
  ps2[(size_t)c * DMM + d] = s2;
}
__global__ __launch_bounds__(256) void stat_fin(const float* __restrict__ ps,
                                                const float* __restrict__ ps2,
                                                float* __restrict__ mean,
                                                float* __restrict__ rstd) {
  int d = threadIdx.x;
  float s = 0.f, s2 = 0.f;
  for (int c = 0; c < 32; ++c) {
    s += ps[(size_t)c * DMM + d];
    s2 += ps2[(size_t)c * DMM + d];
  }
  float m = s * (1.0f / (float)ROWS);
  float var = s2 * (1.0f / (float)ROWS) - m * m;
  mean[d] = m;
  rstd[d] = rsqrtf(var + 1e-5f);
}

__global__ __launch_bounds__(256) void bn_elu(const float* __restrict__ Y,
                                              const float* __restrict__ mean,
                                              const float* __restrict__ rstd,
                                              const float* __restrict__ g,
                                              const float* __restrict__ bb,
                                              float* __restrict__ X,
                                              unsigned short* __restrict__ XB,
                                              unsigned short* __restrict__ XL) {
  int gid = blockIdx.x * 256 + threadIdx.x;
  int d = gid & 255;
  float v = (Y[gid] - mean[d]) * rstd[d] * g[d] + bb[d];
  float r = v > 0.f ? v : expm1f(v);
  X[gid] = r;
  unsigned short hi = f2b(r);
  XB[gid] = hi;
  XL[gid] = f2b(r - bfbits(hi));
}

extern "C" void kernel_launch(void* const* d_in, const int* in_sizes, int n_in,
                              void* d_out, int out_size, void* d_ws, size_t ws_size,
                              hipStream_t stream) {
  (void)in_sizes; (void)n_in; (void)out_size; (void)ws_size;

  // ---- workspace layout ----
  float* xbuf = (float*)d_ws;
  float* kb   = xbuf + NELEM;
  float* vb   = kb + NELEM;
  float* qb   = vb + NELEM;   // aliases tmp (Q dead after attn_part)
  float* tmp  = qb;
  float* Mbuf = qb + NELEM;
  float* vmp  = Mbuf + BB * HH * LL;
  float* vmean= vmp + 256 * DMM;
  float* stp  = vmean + BB * DMM;
  float* stp2 = stp + 32 * DMM;
  float* smean= stp2 + 32 * DMM;
  float* srstd= smean + DMM;
  float* wp   = srstd + DMM;
  const int wsz[23] = {
      NELEM,
      NLL * DMM * DMM, NLL * DMM,
      NLL * DMM * DMM, NLL * DMM,
      NLL * DMM * DMM, NLL * DMM,
      NLL * DMM * DMM, NLL * DMM,
      NLL * ITR * DMM, NLL * ITR,
      NLL * DMM * ITR, NLL * DMM,
      NLL * DMM, NLL * DMM,
      NLL * DMM, NLL * DMM,
      (NLL - 1) * DMM * DMM * 3, (NLL - 1) * DMM,
      (NLL - 1) * DMM, (NLL - 1) * DMM,
      DMM, DMM
  };
  float* fptr[23];
  fptr[0] = xbuf;
  for (int i = 1; i < 23; ++i) { fptr[i] = wp; wp += wsz[i]; }
  float* pm = wp;
  float* pl = pm + 32 * UU * 8;
  float* po = pl + 32 * UU * 8;
  unsigned short* xbf   = (unsigned short*)(po + 32 * UU * 8 * 32);
  unsigned short* xlo   = xbf + NELEM;
  unsigned short* ctxbf = xlo + NELEM;
  unsigned short* wqbf  = ctxbf + NELEM;
  unsigned short* wkbf  = wqbf + NLL * DMM * DMM;
  unsigned short* wvbf  = wkbf + NLL * DMM * DMM;
  unsigned short* wobf  = wvbf + NLL * DMM * DMM;
  unsigned short* dcwT  = wobf + NLL * DMM * DMM;
  u64* cand = (u64*)(dcwT + (NLL - 1) * 3 * DMM * DMM);
  int* idxb = (int*)(cand + 32 * 320);
  int* topb = idxb + LL * UU;
  int* flag = topb + BB * HH * UU;

  // ---- probe + convert ----
  probe_dtype<<<1, 256, 0, stream>>>(d_in[0], flag);
  CvtArgs ca;
  int totalBlk = 0;
  for (int i = 0; i < 23; ++i) {
    ca.src[i] = d_in[i];
    ca.dstF[i] = fptr[i];
    ca.dstB[i] = nullptr;
    ca.dstL[i] = nullptr;
    ca.n[i] = wsz[i];
    ca.blkStart[i] = totalBlk;
    totalBlk += (wsz[i] + 255) / 256;
  }
  ca.blkStart[23] = totalBlk;
  ca.dstB[0] = xbf;  ca.dstL[0] = xlo;
  ca.dstB[1] = wqbf;
  ca.dstB[3] = wkbf;
  ca.dstB[5] = wvbf;
  ca.dstB[7] = wobf;
  mega_cvt<<<totalBlk, 256, 0, stream>>>(ca, flag);
  dcw_repack<<<((NLL - 1) * 3 * 65536 + 255) / 256, 256, 0, stream>>>(fptr[17], dcwT);

  dim3 gqkv(ROWS / 128, DMM / 64, 3);
  dim3 g64(ROWS / 64, DMM / 64);

  for (int i = 0; i < NLL; ++i) {
    QKVArgs qa;
    qa.W[0] = wqbf + (size_t)i * DMM * DMM;
    qa.W[1] = wkbf + (size_t)i * DMM * DMM;
    qa.W[2] = wvbf + (size_t)i * DMM * DMM;
    qa.bias[0] = fptr[2] + i * DMM;
    qa.bias[1] = fptr[4] + i * DMM;
    qa.bias[2] = fptr[6] + i * DMM;
    qa.C[0] = qb; qa.C[1] = kb; qa.C[2] = vb;
    gemm_qkv<<<gqkv, 256, 0, stream>>>(xbf, xlo, qa);

    uint32_t ki0, ki1, a0, a1, b0, b1;
    threefry2x32(0u, 42u, 0u, (uint32_t)i, &ki0, &ki1);
    threefry2x32(ki0, ki1, 0u, 2u, &a0, &a1);
    threefry2x32(ki0, ki1, 1u, 3u, &b0, &b1);
    (void)a0; (void)b0;
    idx_kernel<<<(LL * UU) / 256, 256, 0, stream>>>(a1, b1, idxb);

    m_kernel3<<<BB * 512, 256, 0, stream>>>(qb, kb, idxb, Mbuf);
    cand_topk<<<BB * HH * 8, 256, 0, stream>>>(Mbuf, cand);
    merge_topk<<<BB * HH, 256, 0, stream>>>(cand, topb);
    vmean_part<<<BB * 64, 256, 0, stream>>>(vb, vmp);
    vmean_fin<<<(BB * DMM) / 256, 256, 0, stream>>>(vmp, vmean);
    ctx_init2<<<NELEM / 256, 256, 0, stream>>>(vmean, ctxbf);
    attn_part<<<dim3(8, BB * HH), 256, 0, stream>>>(qb, kb, vb, topb, pm, pl, po);
    attn_merge<<<BB * HH, 256, 0, stream>>>(pm, pl, po, topb, ctxbf);

    gemm_mfma64<<<g64, 256, 0, stream>>>(ctxbf, wobf + (size_t)i * DMM * DMM,
                                         fptr[8] + i * DMM, tmp, 1);
    bool last = (i == NLL - 1);
    enc_tail<<<ROWS / 4, 256, 0, stream>>>(
        xbuf, tmp, fptr[13] + i * DMM, fptr[14] + i * DMM,
        fptr[9] + (size_t)i * ITR * DMM, fptr[10] + i * ITR,
        fptr[11] + (size_t)i * DMM * ITR, fptr[12] + i * DMM,
        fptr[15] + i * DMM, fptr[16] + i * DMM, xbuf, xbf, xlo,
        fptr[21], fptr[22], last ? d_out : nullptr, flag);

    if (!last) {
      gemm_mfma64<<<g64, 256, 0, stream>>>(xbf, dcwT + (size_t)i * 3 * DMM * DMM,
                                           fptr[18] + i * DMM, tmp, 3);
      stat_part<<<32, 256, 0, stream>>>(tmp, stp, stp2);
      stat_fin<<<1, 256, 0, stream>>>(stp, stp2, smean, srstd);
      bn_elu<<<NELEM / 256, 256, 0, stream>>>(tmp, smean, srstd, fptr[19] + i * DMM,
                                              fptr[20] + i * DMM, xbuf, xbf, xlo);
    }
  }
}

// Round 8
// 587.912 us; speedup vs baseline: 2.4619x; 1.0866x over previous
//
#include <hip/hip_runtime.h>
#include <stdint.h>

#define BB 4
#define LL 2048
#define DMM 256
#define HH 8
#define EE 32
#define NLL 3
#define ITR 16
#define UU 40
#define ROWS (BB*LL)          // 8192
#define NELEM (ROWS*DMM)      // 2097152

typedef __attribute__((ext_vector_type(8))) short short8;
typedef __attribute__((ext_vector_type(4))) float f32x4;
typedef unsigned long long u64;

// ---------------- bf16 bit helpers (RNE) ----------------
__device__ __forceinline__ float bfbits(unsigned short u) {
  return __uint_as_float(((uint32_t)u) << 16);
}
__device__ __forceinline__ unsigned short f2b(float f) {
  uint32_t u = __float_as_uint(f);
  uint32_t r = (u + 0x7FFFu + ((u >> 16) & 1u)) >> 16;
  return (unsigned short)r;
}

// ---------------- threefry2x32 (exact JAX semantics) ----------------
__host__ __device__ inline void threefry2x32(uint32_t k0, uint32_t k1,
                                             uint32_t x0, uint32_t x1,
                                             uint32_t* o0, uint32_t* o1) {
  uint32_t ks2 = k0 ^ k1 ^ 0x1BD11BDAu;
  x0 += k0; x1 += k1;
#define TFR(r) { x0 += x1; x1 = (x1 << (r)) | (x1 >> (32 - (r))); x1 ^= x0; }
  TFR(13) TFR(15) TFR(26) TFR(6)
  x0 += k1;  x1 += ks2 + 1u;
  TFR(17) TFR(29) TFR(16) TFR(24)
  x0 += ks2; x1 += k0 + 2u;
  TFR(13) TFR(15) TFR(26) TFR(6)
  x0 += k0;  x1 += k1 + 3u;
  TFR(17) TFR(29) TFR(16) TFR(24)
  x0 += k1;  x1 += ks2 + 4u;
  TFR(13) TFR(15) TFR(26) TFR(6)
  x0 += ks2; x1 += k0 + 5u;
#undef TFR
  *o0 = x0; *o1 = x1;
}

__device__ __forceinline__ float wave_sum(float v) {
#pragma unroll
  for (int off = 32; off > 0; off >>= 1) v += __shfl_xor(v, off);
  return v;
}

// ---------------- dtype probe ----------------
__global__ __launch_bounds__(256) void probe_dtype(const void* __restrict__ x,
                                                   int* __restrict__ flag) {
  __shared__ int cnt;
  if (threadIdx.x == 0) cnt = 0;
  __syncthreads();
  const unsigned short* u = (const unsigned short*)x;
  int bad = 0;
  for (int j = threadIdx.x; j < 2048; j += 256) {
    float v = bfbits(u[j]);
    float a = fabsf(v);
    bool ok = (v == 0.0f) || (a > 1e-4f && a < 100.0f);
    if (!ok) bad++;
  }
  atomicAdd(&cnt, bad);
  __syncthreads();
  if (threadIdx.x == 0) *flag = (cnt > 100) ? 1 : 0;
}

// ---------------- mega convert (+hi/lo splits, +dcw repack, +vmp zero) ----------------
struct CvtArgs {
  const void* src[23];
  float* dstF[23];
  unsigned short* dstB[23];
  unsigned short* dstL[23];
  int n[23];
  int blkStart[24];
  unsigned short* dcwT;
  float* vmpZ;     // zero 1024 floats
};
__global__ __launch_bounds__(256) void mega_cvt(CvtArgs a, const int* __restrict__ flag) {
  int bid = blockIdx.x;
  if (bid == a.blkStart[23]) {  // tail block: zero vmp
    for (int t = threadIdx.x; t < BB * DMM; t += 256) a.vmpZ[t] = 0.f;
    return;
  }
  int i = 0;
  while (i < 22 && bid >= a.blkStart[i + 1]) ++i;
  int e = (bid - a.blkStart[i]) * 256 + (int)threadIdx.x;
  if (e >= a.n[i]) return;
  float v; unsigned short rw;
  if (*flag) { v = ((const float*)a.src[i])[e]; rw = f2b(v); }
  else       { rw = ((const unsigned short*)a.src[i])[e]; v = bfbits(rw); }
  a.dstF[i][e] = v;
  if (a.dstB[i]) a.dstB[i][e] = rw;
  if (a.dstL[i]) a.dstL[i][e] = f2b(v - bfbits(rw));
  if (i == 17) {  // dcw: [ly][n][k][t] -> [ly][t][n][k] bf16
    int ly = e / 196608;
    int r = e - ly * 196608;
    int n = r / 768;
    int rem = r - n * 768;
    int k = rem / 3, t = rem - k * 3;
    a.dcwT[ly * 196608 + t * 65536 + n * 256 + k] = rw;
  }
}

// ---------------- QKV MFMA GEMM: z=0:Q 1:K (hi/lo 2-pass) 2:V (1-pass + vmean atomics) ----
struct QKVArgs {
  const unsigned short* W[3];
  const float* bias[3];
  float* C[3];
  float* vmp;   // [B][DMM] atomic column sums of V
};
__global__ __launch_bounds__(256) void gemm_qkv(const unsigned short* __restrict__ Ahi,
                                                const unsigned short* __restrict__ Alo,
                                                QKVArgs qa) {
  __shared__ unsigned short AsH[128][40];
  __shared__ unsigned short AsL[128][40];
  __shared__ unsigned short Bs[64][40];
  int z = blockIdx.z;
  const unsigned short* W = qa.W[z];
  const float* bias = qa.bias[z];
  float* C = qa.C[z];
  bool twoPass = (z < 2);
  int bm = blockIdx.x * 128, bn = blockIdx.y * 64;
  int tid = threadIdx.x;
  int wave = tid >> 6, lane = tid & 63;
  int wm = wave >> 1, wn = wave & 1;
  int l15 = lane & 15, quad = lane >> 4;
  f32x4 acc[4][2];
#pragma unroll
  for (int i = 0; i < 4; ++i)
#pragma unroll
    for (int j = 0; j < 2; ++j) acc[i][j] = (f32x4){0.f, 0.f, 0.f, 0.f};
  for (int k0 = 0; k0 < 256; k0 += 32) {
    __syncthreads();
    for (int c = tid; c < 512; c += 256) {
      int row = c >> 2, seg = c & 3;
      size_t off = (size_t)(bm + row) * 256 + k0 + seg * 8;
      *(uint4*)(&AsH[row][seg * 8]) = *(const uint4*)(Ahi + off);
      if (twoPass) *(uint4*)(&AsL[row][seg * 8]) = *(const uint4*)(Alo + off);
    }
    {
      int row = tid >> 2, seg = tid & 3;
      *(uint4*)(&Bs[row][seg * 8]) =
          *(const uint4*)(W + (size_t)(bn + row) * 256 + k0 + seg * 8);
    }
    __syncthreads();
    short8 ah[4], bfr[2];
#pragma unroll
    for (int mt = 0; mt < 4; ++mt)
      ah[mt] = *(const short8*)(&AsH[wm * 64 + mt * 16 + l15][quad * 8]);
#pragma unroll
    for (int nt = 0; nt < 2; ++nt)
      bfr[nt] = *(const short8*)(&Bs[wn * 32 + nt * 16 + l15][quad * 8]);
#pragma unroll
    for (int mt = 0; mt < 4; ++mt)
#pragma unroll
      for (int nt = 0; nt < 2; ++nt)
        acc[mt][nt] = __builtin_amdgcn_mfma_f32_16x16x32_bf16(ah[mt], bfr[nt],
                                                              acc[mt][nt], 0, 0, 0);
    if (twoPass) {
      short8 al[4];
#pragma unroll
      for (int mt = 0; mt < 4; ++mt)
        al[mt] = *(const short8*)(&AsL[wm * 64 + mt * 16 + l15][quad * 8]);
#pragma unroll
      for (int mt = 0; mt < 4; ++mt)
#pragma unroll
        for (int nt = 0; nt < 2; ++nt)
          acc[mt][nt] = __builtin_amdgcn_mfma_f32_16x16x32_bf16(al[mt], bfr[nt],
                                                                acc[mt][nt], 0, 0, 0);
    }
  }
#pragma unroll
  for (int nt = 0; nt < 2; ++nt) {
    int n = bn + wn * 32 + nt * 16 + l15;
    float bv = bias[n];
    float csum = 0.f;
#pragma unroll
    for (int mt = 0; mt < 4; ++mt)
#pragma unroll
      for (int r = 0; r < 4; ++r) {
        int m = bm + wm * 64 + mt * 16 + quad * 4 + r;
        float val = acc[mt][nt][r] + bv;
        C[(size_t)m * 256 + n] = val;
        csum += val;
      }
    if (z == 2) {  // vmean column partials
      csum += __shfl_xor(csum, 16);
      csum += __shfl_xor(csum, 32);
      if (quad == 0) {
        int b = bm >> 11;
        atomicAdd(&qa.vmp[b * DMM + n], csum);
      }
    }
  }
}

// ---------------- bf16 MFMA GEMM 64x64 (O-proj; conv w/ fused BN stats) ----------------
__global__ __launch_bounds__(256) void gemm_mfma64(const unsigned short* __restrict__ A,
                                                   const unsigned short* __restrict__ W,
                                                   const float* __restrict__ bias,
                                                   float* __restrict__ C, int ntaps,
                                                   float* __restrict__ stp,
                                                   float* __restrict__ stp2) {
  __shared__ unsigned short As[64][40];
  __shared__ unsigned short Bs[64][40];
  int bm = blockIdx.x * 64, bn = blockIdx.y * 64;
  int tid = threadIdx.x;
  int wave = tid >> 6, lane = tid & 63;
  int wm = wave >> 1, wn = wave & 1;
  int l15 = lane & 15, quad = lane >> 4;
  f32x4 acc[2][2];
#pragma unroll
  for (int i = 0; i < 2; ++i)
#pragma unroll
    for (int j = 0; j < 2; ++j) acc[i][j] = (f32x4){0.f, 0.f, 0.f, 0.f};
  for (int tap = 0; tap < ntaps; ++tap) {
    int lshift = (ntaps == 3) ? (tap - 1) : 0;
    const unsigned short* Wt = W + (size_t)tap * 65536;
    for (int k0 = 0; k0 < 256; k0 += 32) {
      __syncthreads();
      {
        int row = tid >> 2, seg = tid & 3;
        int grow = bm + row;
        if (lshift != 0) {
          int bidx = grow >> 11, l = grow & 2047;
          grow = (bidx << 11) | ((l + lshift + 2048) & 2047);
        }
        *(uint4*)(&As[row][seg * 8]) =
            *(const uint4*)(A + (size_t)grow * 256 + k0 + seg * 8);
        *(uint4*)(&Bs[row][seg * 8]) =
            *(const uint4*)(Wt + (size_t)(bn + row) * 256 + k0 + seg * 8);
      }
      __syncthreads();
      short8 af[2], bfr[2];
#pragma unroll
      for (int mt = 0; mt < 2; ++mt)
        af[mt] = *(const short8*)(&As[wm * 32 + mt * 16 + l15][quad * 8]);
#pragma unroll
      for (int nt = 0; nt < 2; ++nt)
        bfr[nt] = *(const short8*)(&Bs[wn * 32 + nt * 16 + l15][quad * 8]);
#pragma unroll
      for (int mt = 0; mt < 2; ++mt)
#pragma unroll
        for (int nt = 0; nt < 2; ++nt)
          acc[mt][nt] = __builtin_amdgcn_mfma_f32_16x16x32_bf16(af[mt], bfr[nt],
                                                                acc[mt][nt], 0, 0, 0);
    }
  }
#pragma unroll
  for (int nt = 0; nt < 2; ++nt) {
    int n = bn + wn * 32 + nt * 16 + l15;
    float bv = bias[n];
    float s = 0.f, s2 = 0.f;
#pragma unroll
    for (int mt = 0; mt < 2; ++mt)
#pragma unroll
      for (int r = 0; r < 4; ++r) {
        int m = bm + wm * 32 + mt * 16 + quad * 4 + r;
        float val = acc[mt][nt][r] + bv;
        C[(size_t)m * 256 + n] = val;
        s += val;
        s2 += val * val;
      }
    if (stp) {  // fused batchnorm stats (conv path)
      s  += __shfl_xor(s, 16);   s  += __shfl_xor(s, 32);
      s2 += __shfl_xor(s2, 16);  s2 += __shfl_xor(s2, 32);
      if (quad == 0) {
        atomicAdd(&stp[n], s);
        atomicAdd(&stp2[n], s2);
      }
    }
  }
}

// ---------------- M scores: wave per (b,l), inline threefry ----------------
__global__ __launch_bounds__(256) void m_kernel3(const float* __restrict__ Q,
                                                 const float* __restrict__ K,
                                                 uint32_t k20, uint32_t k21,
                                                 float* __restrict__ M) {
  int blk = blockIdx.x;
  int b = blk >> 9, lc = blk & 511;
  int wave = threadIdx.x >> 6, lane = threadIdx.x & 63;
  int l = lc * 4 + wave;
  // lanes 0..39: sample index via threefry
  int myidx = 0;
  if (lane < UU) {
    int j = l * UU + lane;
    uint32_t o0, o1;
    const int half = (LL * UU) / 2;  // 40960
    if (j < half) {
      threefry2x32(k20, k21, (uint32_t)j, (uint32_t)(j + half), &o0, &o1);
      myidx = (int)(o0 & (LL - 1));
    } else {
      threefry2x32(k20, k21, (uint32_t)(j - half), (uint32_t)j, &o0, &o1);
      myidx = (int)(o1 & (LL - 1));
    }
  }
  float4 q4 = *(const float4*)(Q + ((size_t)(b * LL + l)) * DMM + lane * 4);
  const float* Kb = K + (size_t)b * LL * DMM;
  float mx = -1e30f, sm = 0.f;
#pragma unroll 4
  for (int u = 0; u < UU; ++u) {
    int kidx = __shfl(myidx, u);
    float4 k4 = *(const float4*)(Kb + (size_t)kidx * DMM + lane * 4);
    float s = q4.x * k4.x + q4.y * k4.y + q4.z * k4.z + q4.w * k4.w;
    s += __shfl_xor(s, 1);
    s += __shfl_xor(s, 2);
    s += __shfl_xor(s, 4);
    mx = fmaxf(mx, s);
    sm += s;
  }
  if ((lane & 7) == 0) {
    int h = lane >> 3;
    M[((size_t)(b * HH + h)) * LL + l] = mx - sm * (1.0f / (float)LL);
  }
}

// ---------------- top-k stage A ----------------
__global__ __launch_bounds__(256) void cand_topk(const float* __restrict__ M,
                                                 u64* __restrict__ cand) {
  __shared__ u64 a[256];
  int bh = blockIdx.x >> 3, c = blockIdx.x & 7;
  int tid = threadIdx.x;
  int l = c * 256 + tid;
  float v = M[(size_t)bh * LL + l];
  uint32_t bits = __float_as_uint(v);
  uint32_t kv = (bits & 0x80000000u) ? ~bits : (bits | 0x80000000u);
  a[tid] = ((u64)kv << 32) | (uint32_t)(2047 - l);
  __syncthreads();
  for (int k = 2; k <= 256; k <<= 1)
    for (int j = k >> 1; j > 0; j >>= 1) {
      int ixj = tid ^ j;
      if (ixj > tid) {
        bool up = ((tid & k) == 0);
        u64 x = a[tid], y = a[ixj];
        if ((x > y) == up) { a[tid] = y; a[ixj] = x; }
      }
      __syncthreads();
    }
  if (tid >= 216) cand[(size_t)blockIdx.x * 40 + (tid - 216)] = a[tid];
}

// ---------------- top-k stage B (+selection map) ----------------
__global__ __launch_bounds__(256) void merge_topk(const u64* __restrict__ cand,
                                                  int* __restrict__ top,
                                                  unsigned char* __restrict__ mapb) {
  __shared__ u64 a[512];
  int bh = blockIdx.x;
  int tid = threadIdx.x;
  for (int t = tid; t < 2048; t += 256) mapb[bh * 2048 + t] = 0;
  for (int t = tid; t < 512; t += 256)
    a[t] = (t < 320) ? cand[(size_t)bh * 320 + t] : 0ULL;
  __syncthreads();
  for (int k = 2; k <= 512; k <<= 1)
    for (int j = k >> 1; j > 0; j >>= 1) {
      for (int t = tid; t < 512; t += 256) {
        int ixj = t ^ j;
        if (ixj > t) {
          bool up = ((t & k) == 0);
          u64 x = a[t], y = a[ixj];
          if ((x > y) == up) { a[t] = y; a[ixj] = x; }
        }
      }
      __syncthreads();
    }
  if (tid < UU) {
    u64 key = a[511 - tid];
    int l = 2047 - (int)(uint32_t)(key & 0xFFFFFFFFu);
    top[bh * UU + tid] = l;
    mapb[bh * 2048 + l] = (unsigned char)(tid + 1);
  }
}

// ---------------- split-K flash attention: partials ----------------
__global__ __launch_bounds__(256) void attn_part(const float* __restrict__ Q,
                                                 const float* __restrict__ K,
                                                 const float* __restrict__ V,
                                                 const int* __restrict__ top,
                                                 float* __restrict__ pm,
                                                 float* __restrict__ pl,
                                                 float* __restrict__ po) {
  __shared__ float Qs[40][32];
  __shared__ unsigned short ps[40][256];
  __shared__ float Vs[256][36];
  __shared__ int qrows[40];
  int kc = blockIdx.x, bh = blockIdx.y;
  int h = bh & 7, b = bh >> 3;
  int tid = threadIdx.x;
  int wv = tid >> 6, lane = tid & 63;
  if (tid < 40) qrows[tid] = top[bh * UU + tid];
  __syncthreads();
  for (int t = tid; t < 40 * 32; t += 256) {
    int q = t >> 5, d = t & 31;
    Qs[q][d] = Q[((size_t)(b * LL + qrows[q])) * DMM + h * EE + d];
  }
  {
    int krow = b * LL + kc * 256 + tid;
#pragma unroll
    for (int seg = 0; seg < 8; ++seg)
      *(float4*)(&Vs[tid][seg * 4]) =
          *(const float4*)(V + (size_t)krow * DMM + h * EE + seg * 4);
  }
  __syncthreads();
  {
    const float4* kp =
        (const float4*)(K + ((size_t)(b * LL + kc * 256 + tid)) * DMM + h * EE);
    float4 kr[8];
#pragma unroll
    for (int j = 0; j < 8; ++j) kr[j] = kp[j];
    const float scale = 0.17677669529663687f;
    for (int q = 0; q < 40; ++q) {
      const float4* qp = (const float4*)Qs[q];
      float s = 0.f;
#pragma unroll
      for (int j = 0; j < 8; ++j) {
        float4 qv = qp[j];
        s += qv.x * kr[j].x + qv.y * kr[j].y + qv.z * kr[j].z + qv.w * kr[j].w;
      }
      ps[q][tid] = f2b(s * scale);
    }
  }
  __syncthreads();
  int kg = lane >> 5, d = lane & 31;
  for (int qq = 0; qq < 10; ++qq) {
    int q = wv * 10 + qq;
    float mx = -1e30f;
#pragma unroll
    for (int e = 0; e < 4; ++e) mx = fmaxf(mx, bfbits(ps[q][lane + 64 * e]));
#pragma unroll
    for (int off = 32; off > 0; off >>= 1) mx = fmaxf(mx, __shfl_xor(mx, off));
    float sum = 0.f;
#pragma unroll
    for (int e = 0; e < 4; ++e) {
      int i = lane + 64 * e;
      float ev = expf(bfbits(ps[q][i]) - mx);
      sum += ev;
      ps[q][i] = f2b(ev);
    }
    sum = wave_sum(sum);
    float o = 0.f;
#pragma unroll 8
    for (int j = 0; j < 128; ++j) {
      int r = 2 * j + kg;
      o += bfbits(ps[q][r]) * Vs[r][d];
    }
    o += __shfl_xor(o, 32);
    size_t base = ((size_t)bh * UU + q) * 8 + kc;
    if (lane == 0) { pm[base] = mx; pl[base] = sum; }
    if (lane < 32) po[base * 32 + d] = o;
  }
}

// ---------------- ctx fill: vmean broadcast + merged attention rows ----------------
// grid ROWS/8 blocks; thread: lr=t>>5 (row in block), dl=t&31 (dim in head)
__global__ __launch_bounds__(256) void ctx_fill(const float* __restrict__ vmp,
                                                const unsigned char* __restrict__ mapb,
                                                const float* __restrict__ pm,
                                                const float* __restrict__ pl,
                                                const float* __restrict__ po,
                                                unsigned short* __restrict__ ctxbf) {
  int tid = threadIdx.x;
  int lr = tid >> 5, dl = tid & 31;
  int row = blockIdx.x * 8 + lr;
  int b = row >> 11, l = row & 2047;
  const float invL = 1.0f / (float)LL;
#pragma unroll
  for (int h = 0; h < HH; ++h) {
    int bh = b * HH + h;
    int q = (int)mapb[bh * 2048 + l];
    float val;
    if (q) {
      size_t base = ((size_t)bh * UU + (q - 1)) * 8;
      float Mx = -1e30f;
#pragma unroll
      for (int kc = 0; kc < 8; ++kc) Mx = fmaxf(Mx, pm[base + kc]);
      float L = 0.f, o = 0.f;
#pragma unroll
      for (int kc = 0; kc < 8; ++kc) {
        float sc = expf(pm[base + kc] - Mx);
        L += pl[base + kc] * sc;
        o += po[(base + kc) * 32 + dl] * sc;
      }
      val = o / L;
    } else {
      val = vmp[b * DMM + h * EE + dl] * invL;
    }
    ctxbf[(size_t)row * DMM + h * EE + dl] = f2b(val);
  }
}

// ---------------- fused LN1(x+t) + FFN + LN2 (+final LN, +stat zero) ----------------
__global__ __launch_bounds__(256) void enc_tail(const float* __restrict__ X,
                                                const float* __restrict__ T,
                                                const float* __restrict__ g1,
                                                const float* __restrict__ b1ln,
                                                const float* __restrict__ w1,
                                                const float* __restrict__ b1,
                                                const float* __restrict__ w2,
                                                const float* __restrict__ b2,
                                                const float* __restrict__ g2,
                                                const float* __restrict__ b2ln,
                                                float* __restrict__ Out,
                                                unsigned short* __restrict__ OutB,
                                                unsigned short* __restrict__ OutL,
                                                const float* __restrict__ fing,
                                                const float* __restrict__ finb,
                                                void* __restrict__ finOut,
                                                const int* __restrict__ flag,
                                                float* __restrict__ stpZ,
                                                float* __restrict__ stp2Z) {
  if (blockIdx.x == 0) {  // zero BN stat accumulators for this layer's conv
    stpZ[threadIdx.x] = 0.f;
    stp2Z[threadIdx.x] = 0.f;
  }
  int wave = threadIdx.x >> 6, lane = threadIdx.x & 63;
  size_t row = (size_t)blockIdx.x * 4 + wave;
  __shared__ float xs[4][DMM];
  const float* xr = X + row * DMM;
  const float* tr = T + row * DMM;
  float v[4];
#pragma unroll
  for (int i = 0; i < 4; ++i) v[i] = xr[lane + 64 * i] + tr[lane + 64 * i];
  float s = wave_sum(v[0] + v[1] + v[2] + v[3]);
  float m = s * (1.0f / (float)DMM);
  float sq = 0.f;
#pragma unroll
  for (int i = 0; i < 4; ++i) { float d = v[i] - m; sq += d * d; }
  sq = wave_sum(sq);
  float rstd = rsqrtf(sq * (1.0f / (float)DMM) + 1e-5f);
  float xv[4];
#pragma unroll
  for (int i = 0; i < 4; ++i) {
    int d = lane + 64 * i;
    xv[i] = (v[i] - m) * rstd * g1[d] + b1ln[d];
    xs[wave][d] = xv[i];
  }
  __syncthreads();
  int f = lane & 15, qtr = lane >> 4;
  const float* w1p = w1 + f * DMM + qtr * 64;
  const float* xq = &xs[wave][qtr * 64];
  float pacc = 0.f;
#pragma unroll 8
  for (int d = 0; d < 64; ++d) pacc += xq[d] * w1p[d];
  pacc += __shfl_xor(pacc, 16);
  pacc += __shfl_xor(pacc, 32);
  float y1 = fmaxf(pacc + b1[f], 0.0f);
  float y1v[16];
#pragma unroll
  for (int ff = 0; ff < 16; ++ff) y1v[ff] = __shfl(y1, ff);
#pragma unroll
  for (int i = 0; i < 4; ++i) {
    int d = lane + 64 * i;
    const float* w2p = w2 + d * ITR;
    float a = b2[d];
#pragma unroll
    for (int ff = 0; ff < 16; ++ff) a += y1v[ff] * w2p[ff];
    v[i] = xv[i] + a;
  }
  s = wave_sum(v[0] + v[1] + v[2] + v[3]);
  m = s * (1.0f / (float)DMM);
  sq = 0.f;
#pragma unroll
  for (int i = 0; i < 4; ++i) { float d = v[i] - m; sq += d * d; }
  sq = wave_sum(sq);
  rstd = rsqrtf(sq * (1.0f / (float)DMM) + 1e-5f);
  float vv[4];
#pragma unroll
  for (int i = 0; i < 4; ++i) {
    int d = lane + 64 * i;
    float val = (v[i] - m) * rstd * g2[d] + b2ln[d];
    vv[i] = val;
    Out[row * DMM + d] = val;
    unsigned short hi = f2b(val);
    OutB[row * DMM + d] = hi;
    OutL[row * DMM + d] = f2b(val - bfbits(hi));
  }
  if (finOut) {
    s = wave_sum(vv[0] + vv[1] + vv[2] + vv[3]);
    m = s * (1.0f / (float)DMM);
    sq = 0.f;
#pragma unroll
    for (int i = 0; i < 4; ++i) { float d = vv[i] - m; sq += d * d; }
    sq = wave_sum(sq);
    rstd = rsqrtf(sq * (1.0f / (float)DMM) + 1e-5f);
    int isf32 = *flag;
#pragma unroll
    for (int i = 0; i < 4; ++i) {
      int d = lane + 64 * i;
      float val = (vv[i] - m) * rstd * fing[d] + finb[d];
      if (isf32) ((float*)finOut)[row * DMM + d] = val;
      else       ((unsigned short*)finOut)[row * DMM + d] = f2b(val);
    }
  }
}

// ---------------- bn+elu from atomic stats (+vmp zero for next layer) ----------------
__global__ __launch_bounds__(256) void bn_elu(const float* __restrict__ Y,
                                              const float* __restrict__ stp,
                                              const float* __restrict__ stp2,
                                              const float* __restrict__ g,
                                              const float* __restrict__ bb,
                                              float* __restrict__ X,
                                              unsigned short* __restrict__ XB,
                                              unsigned short* __restrict__ XL,
                                              float* __restrict__ vmpZ) {
  int gid = blockIdx.x * 256 + threadIdx.x;
  if (gid < BB * DMM) vmpZ[gid] = 0.f;
  int d = gid & 255;
  float mean = stp[d] * (1.0f / (float)ROWS);
  float var = stp2[d] * (1.0f / (float)ROWS) - mean * mean;
  float rstd = rsqrtf(var + 1e-5f);
  float v = (Y[gid] - mean) * rstd * g[d] + bb[d];
  float r = v > 0.f ? v : expm1f(v);
  X[gid] = r;
  unsigned short hi = f2b(r);
  XB[gid] = hi;
  XL[gid] = f2b(r - bfbits(hi));
}

extern "C" void kernel_launch(void* const* d_in, const int* in_sizes, int n_in,
                              void* d_out, int out_size, void* d_ws, size_t ws_size,
                              hipStream_t stream) {
  (void)in_sizes; (void)n_in; (void)out_size; (void)ws_size;

  // ---- workspace layout ----
  float* xbuf = (float*)d_ws;
  float* kb   = xbuf + NELEM;
  float* vb   = kb + NELEM;
  float* qb   = vb + NELEM;   // aliases tmp (Q dead after attn_part)
  float* tmp  = qb;
  float* Mbuf = qb + NELEM;
  float* vmp  = Mbuf + BB * HH * LL;   // B*DMM atomic sums
  float* stp  = vmp + BB * DMM;        // DMM
  float* stp2 = stp + DMM;             // DMM
  float* wp   = stp2 + DMM;
  const int wsz[23] = {
      NELEM,
      NLL * DMM * DMM, NLL * DMM,
      NLL * DMM * DMM, NLL * DMM,
      NLL * DMM * DMM, NLL * DMM,
      NLL * DMM * DMM, NLL * DMM,
      NLL * ITR * DMM, NLL * ITR,
      NLL * DMM * ITR, NLL * DMM,
      NLL * DMM, NLL * DMM,
      NLL * DMM, NLL * DMM,
      (NLL - 1) * DMM * DMM * 3, (NLL - 1) * DMM,
      (NLL - 1) * DMM, (NLL - 1) * DMM,
      DMM, DMM
  };
  float* fptr[23];
  fptr[0] = xbuf;
  for (int i = 1; i < 23; ++i) { fptr[i] = wp; wp += wsz[i]; }
  float* pm = wp;
  float* pl = pm + 32 * UU * 8;
  float* po = pl + 32 * UU * 8;
  unsigned short* xbf   = (unsigned short*)(po + 32 * UU * 8 * 32);
  unsigned short* xlo   = xbf + NELEM;
  unsigned short* ctxbf = xlo + NELEM;
  unsigned short* wqbf  = ctxbf + NELEM;
  unsigned short* wkbf  = wqbf + NLL * DMM * DMM;
  unsigned short* wvbf  = wkbf + NLL * DMM * DMM;
  unsigned short* wobf  = wvbf + NLL * DMM * DMM;
  unsigned short* dcwT  = wobf + NLL * DMM * DMM;
  u64* cand = (u64*)(dcwT + (NLL - 1) * 3 * DMM * DMM);
  int* topb = (int*)(cand + 32 * 320);
  int* flag = topb + BB * HH * UU;
  unsigned char* mapb = (unsigned char*)(flag + 1);  // 32*2048

  // ---- probe + convert (+dcw repack, +vmp zero) ----
  probe_dtype<<<1, 256, 0, stream>>>(d_in[0], flag);
  CvtArgs ca;
  int totalBlk = 0;
  for (int i = 0; i < 23; ++i) {
    ca.src[i] = d_in[i];
    ca.dstF[i] = fptr[i];
    ca.dstB[i] = nullptr;
    ca.dstL[i] = nullptr;
    ca.n[i] = wsz[i];
    ca.blkStart[i] = totalBlk;
    totalBlk += (wsz[i] + 255) / 256;
  }
  ca.blkStart[23] = totalBlk;
  ca.dstB[0] = xbf;  ca.dstL[0] = xlo;
  ca.dstB[1] = wqbf;
  ca.dstB[3] = wkbf;
  ca.dstB[5] = wvbf;
  ca.dstB[7] = wobf;
  ca.dcwT = dcwT;
  ca.vmpZ = vmp;
  mega_cvt<<<totalBlk + 1, 256, 0, stream>>>(ca, flag);

  dim3 gqkv(ROWS / 128, DMM / 64, 3);
  dim3 g64(ROWS / 64, DMM / 64);

  for (int i = 0; i < NLL; ++i) {
    QKVArgs qa;
    qa.W[0] = wqbf + (size_t)i * DMM * DMM;
    qa.W[1] = wkbf + (size_t)i * DMM * DMM;
    qa.W[2] = wvbf + (size_t)i * DMM * DMM;
    qa.bias[0] = fptr[2] + i * DMM;
    qa.bias[1] = fptr[4] + i * DMM;
    qa.bias[2] = fptr[6] + i * DMM;
    qa.C[0] = qb; qa.C[1] = kb; qa.C[2] = vb;
    qa.vmp = vmp;
    gemm_qkv<<<gqkv, 256, 0, stream>>>(xbf, xlo, qa);

    uint32_t ki0, ki1, a0, a1, b0, b1;
    threefry2x32(0u, 42u, 0u, (uint32_t)i, &ki0, &ki1);
    threefry2x32(ki0, ki1, 0u, 2u, &a0, &a1);
    threefry2x32(ki0, ki1, 1u, 3u, &b0, &b1);
    (void)a0; (void)b0;

    m_kernel3<<<BB * 512, 256, 0, stream>>>(qb, kb, a1, b1, Mbuf);
    cand_topk<<<BB * HH * 8, 256, 0, stream>>>(Mbuf, cand);
    merge_topk<<<BB * HH, 256, 0, stream>>>(cand, topb, mapb);
    attn_part<<<dim3(8, BB * HH), 256, 0, stream>>>(qb, kb, vb, topb, pm, pl, po);
    ctx_fill<<<ROWS / 8, 256, 0, stream>>>(vmp, mapb, pm, pl, po, ctxbf);

    gemm_mfma64<<<g64, 256, 0, stream>>>(ctxbf, wobf + (size_t)i * DMM * DMM,
                                         fptr[8] + i * DMM, tmp, 1, nullptr, nullptr);
    bool last = (i == NLL - 1);
    enc_tail<<<ROWS / 4, 256, 0, stream>>>(
        xbuf, tmp, fptr[13] + i * DMM, fptr[14] + i * DMM,
        fptr[9] + (size_t)i * ITR * DMM, fptr[10] + i * ITR,
        fptr[11] + (size_t)i * DMM * ITR, fptr[12] + i * DMM,
        fptr[15] + i * DMM, fptr[16] + i * DMM, xbuf, xbf, xlo,
        fptr[21], fptr[22], last ? d_out : nullptr, flag, stp, stp2);

    if (!last) {
      gemm_mfma64<<<g64, 256, 0, stream>>>(xbf, dcwT + (size_t)i * 3 * DMM * DMM,
                                           fptr[18] + i * DMM, tmp, 3, stp, stp2);
      bn_elu<<<NELEM / 256, 256, 0, stream>>>(tmp, stp, stp2, fptr[19] + i * DMM,
                                              fptr[20] + i * DMM, xbuf, xbf, xlo, vmp);
    }
  }
}